// Round 7
// baseline (700.796 us; speedup 1.0000x reference)
//
#include <hip/hip_runtime.h>
#include <hip/hip_bf16.h>
#include <type_traits>

// ---------------------------------------------------------------------------
// Round 7: tile-shape consolidation. QKV 128x96 (512 blk), W1 128x128
// (512 blk), W2/Wo 128x64 (256 blk). Fast trig in embed. Flash attn kept.
// ---------------------------------------------------------------------------

typedef float  f32x4 __attribute__((ext_vector_type(4)));
typedef __bf16 bf16x8 __attribute__((ext_vector_type(8)));
typedef unsigned short u16x8 __attribute__((ext_vector_type(8)));
typedef unsigned short u16x4 __attribute__((ext_vector_type(4)));

#define DI __device__ __forceinline__

constexpr int TB = 2, TS = 1024, TD = 1024, TH = 16, TV = 32000, TL = 2,
              TDFF = 4096, THD = 64;
constexpr int BM = 128, BK = 64, BKP = 72;

DI unsigned short f2b(float f) {
  __bf16 h = (__bf16)f;
  return __builtin_bit_cast(unsigned short, h);
}
DI float b2f(unsigned short u) {
  unsigned v = ((unsigned)u) << 16;
  return __builtin_bit_cast(float, v);
}

DI void glds16(const void* g, void* l) {
  __builtin_amdgcn_global_load_lds(
      (const __attribute__((address_space(1))) unsigned int*)g,
      (__attribute__((address_space(3))) unsigned int*)l, 16, 0, 0);
}

// ---------------- embedding * sqrt(D) + sinusoidal posenc ----------------
__global__ __launch_bounds__(256) void embed_pe_k(const int* __restrict__ tok,
                                                  const float* __restrict__ emb,
                                                  float* __restrict__ x) {
  const int bs = blockIdx.x;
  const int s  = bs & (TS - 1);
  const int t  = tok[bs];
  const int d0 = threadIdx.x << 2;
  f32x4 e = *(const f32x4*)(emb + (size_t)t * TD + d0);
  f32x4 r;
#pragma unroll
  for (int j = 0; j < 4; ++j) {
    int d = d0 + j;
    int i2 = d >> 1;
    float freq = __expf((float)(2 * i2) * (-9.210340371976184f / (float)TD));
    float arg = (float)s * freq;
    float pe = (d & 1) ? __cosf(arg) : __sinf(arg);
    r[j] = e[j] * 32.0f + pe;
  }
  *(f32x4*)(x + (size_t)bs * TD + d0) = r;
}

// ---------------- RMS norm -> bf16 ----------------
__global__ __launch_bounds__(256) void rms_k(const float* __restrict__ xin,
                                             const float* __restrict__ alpha,
                                             unsigned short* __restrict__ out) {
  const int row = blockIdx.x;
  const int tid = threadIdx.x;
  const int d0 = tid << 2;
  f32x4 xv = *(const f32x4*)(xin + (size_t)row * TD + d0);
  float ss = xv[0] * xv[0] + xv[1] * xv[1] + xv[2] * xv[2] + xv[3] * xv[3];
#pragma unroll
  for (int o = 32; o > 0; o >>= 1) ss += __shfl_down(ss, o);
  __shared__ float ps[4];
  __shared__ float invs;
  if ((tid & 63) == 0) ps[tid >> 6] = ss;
  __syncthreads();
  if (tid == 0) {
    float tot = ps[0] + ps[1] + ps[2] + ps[3];
    invs = 1.0f / (sqrtf(tot * (1.0f / (float)TD)) + 1e-8f);
  }
  __syncthreads();
  const float inv = invs;
  f32x4 av = *(const f32x4*)(alpha + d0);
  u16x4 ov;
#pragma unroll
  for (int j = 0; j < 4; ++j) ov[j] = f2b(av[j] * xv[j] * inv);
  *(u16x4*)(out + (size_t)row * TD + d0) = ov;
}

// ---------------- fused flash attention -----------------------------------
__global__ __launch_bounds__(512) void attn_k(
    const unsigned short* __restrict__ qkv, const unsigned short* __restrict__ vt,
    unsigned short* __restrict__ ob) {
  const int q0 = blockIdx.x << 7;
  const int bh = blockIdx.y;
  const int b = bh >> 4, h = bh & 15;
  const unsigned short* Qg = qkv + (size_t)(b * TS) * 3072 + h * 64;
  const unsigned short* Kg = Qg + 1024;
  const unsigned short* Vg = vt + (size_t)b * TD * TS + (size_t)(h * 64) * TS;

  __shared__ __attribute__((aligned(16))) unsigned short Qs[128 * 64];
  __shared__ __attribute__((aligned(16))) unsigned short Ks[128 * 64];
  __shared__ __attribute__((aligned(16))) unsigned short Vs[64 * 128];
  __shared__ __attribute__((aligned(16))) unsigned short Sb[128 * 128];
  __shared__ float mi[128], li[128], scl[128];

  const int tid = threadIdx.x, lane = tid & 63, wid = tid >> 6;
  const int lm = lane & 15, hi = lane >> 4;
  const int wm = wid >> 2, wn = wid & 3;

  if (tid < 128) { mi[tid] = -3.0e38f; li[tid] = 0.f; }

  {
    const int srow = lane >> 3, schk = lane & 7;
#pragma unroll
    for (int i = 0; i < 2; ++i) {
      const int row = wid * 16 + i * 8 + srow;
      const unsigned char* src =
          (const unsigned char*)(Qg + (size_t)(q0 + row) * 3072) +
          ((schk * 16) ^ ((srow & 7) << 4));
      glds16(src, (unsigned char*)Qs + (wid * 16 + i * 8) * 128);
    }
  }

  f32x4 acc_o[4] = {};
  const int nt = blockIdx.x + 1;

  for (int t = 0; t < nt; ++t) {
    const int kv0 = t << 7;
    {
      const int srow = lane >> 3, schk = lane & 7;
#pragma unroll
      for (int i = 0; i < 2; ++i) {
        const int row = wid * 16 + i * 8 + srow;
        const unsigned char* src =
            (const unsigned char*)(Kg + (size_t)(kv0 + row) * 3072) +
            ((schk * 16) ^ ((srow & 7) << 4));
        glds16(src, (unsigned char*)Ks + (wid * 16 + i * 8) * 128);
      }
      const int vrow4 = lane >> 4, vchk = lane & 15;
#pragma unroll
      for (int i = 0; i < 2; ++i) {
        const int row = wid * 8 + i * 4 + vrow4;
        const unsigned char* src =
            (const unsigned char*)(Vg + (size_t)row * TS + kv0) +
            ((vchk * 16) ^ ((row & 15) << 4));
        glds16(src, (unsigned char*)Vs + (wid * 8 + i * 4) * 256);
      }
    }
    asm volatile("s_waitcnt vmcnt(0)");
    __syncthreads();

    f32x4 acc_s[4][2] = {};
#pragma unroll
    for (int kk = 0; kk < 2; ++kk) {
      bf16x8 af[4], bf[2];
#pragma unroll
      for (int i = 0; i < 4; ++i) {
        const int row = wm * 64 + i * 16 + lm;
        af[i] = __builtin_bit_cast(
            bf16x8, *(const u16x8*)((const unsigned char*)Qs + row * 128 +
                                    (((kk * 4 + hi) ^ (row & 7)) << 4)));
      }
#pragma unroll
      for (int j = 0; j < 2; ++j) {
        const int row = wn * 32 + j * 16 + lm;
        bf[j] = __builtin_bit_cast(
            bf16x8, *(const u16x8*)((const unsigned char*)Ks + row * 128 +
                                    (((kk * 4 + hi) ^ (row & 7)) << 4)));
      }
#pragma unroll
      for (int i = 0; i < 4; ++i)
#pragma unroll
        for (int j = 0; j < 2; ++j)
          acc_s[i][j] = __builtin_amdgcn_mfma_f32_16x16x32_bf16(af[i], bf[j],
                                                                acc_s[i][j], 0, 0, 0);
    }
#pragma unroll
    for (int i = 0; i < 4; ++i)
#pragma unroll
      for (int j = 0; j < 2; ++j)
#pragma unroll
        for (int e = 0; e < 4; ++e) {
          const int row = wm * 64 + i * 16 + hi * 4 + e;
          const int col = wn * 32 + j * 16 + lm;
          float v = acc_s[i][j][e] * 0.125f;
          if (kv0 + col > q0 + row) v = -1e30f;
          const int chunk = (col >> 3) ^ (row & 15);
          *(unsigned short*)((unsigned char*)Sb + row * 256 + chunk * 16 +
                             ((col & 7) << 1)) = f2b(v);
        }
    __syncthreads();

    {
      const int r = tid >> 2, qt = tid & 3;
      float v[32];
      float rmax = -3.0e38f;
#pragma unroll
      for (int cc = 0; cc < 4; ++cc) {
        const int c = qt * 4 + cc;
        u16x8 pk = *(const u16x8*)((const unsigned char*)Sb + r * 256 +
                                   ((c ^ (r & 15)) << 4));
#pragma unroll
        for (int j = 0; j < 8; ++j) {
          v[cc * 8 + j] = b2f(pk[j]);
          rmax = fmaxf(rmax, v[cc * 8 + j]);
        }
      }
      rmax = fmaxf(rmax, __shfl_xor(rmax, 1));
      rmax = fmaxf(rmax, __shfl_xor(rmax, 2));
      const float mold = mi[r];
      const float mnew = fmaxf(mold, rmax);
      float lsum = 0.f;
#pragma unroll
      for (int cc = 0; cc < 4; ++cc) {
        const int c = qt * 4 + cc;
        u16x8 pk;
#pragma unroll
        for (int j = 0; j < 8; ++j) {
          float p = __expf(v[cc * 8 + j] - mnew);
          lsum += p;
          pk[j] = f2b(p);
        }
        *(u16x8*)((unsigned char*)Sb + r * 256 + ((c ^ (r & 15)) << 4)) = pk;
      }
      lsum += __shfl_xor(lsum, 1);
      lsum += __shfl_xor(lsum, 2);
      if (qt == 0) {
        const float sc = __expf(mold - mnew);
        scl[r] = sc;
        li[r] = li[r] * sc + lsum;
        mi[r] = mnew;
      }
    }
    __syncthreads();

    {
      float sc[4];
#pragma unroll
      for (int e = 0; e < 4; ++e) sc[e] = scl[wid * 16 + hi * 4 + e];
#pragma unroll
      for (int j = 0; j < 4; ++j)
#pragma unroll
        for (int e = 0; e < 4; ++e) acc_o[j][e] *= sc[e];
#pragma unroll
      for (int ks = 0; ks < 4; ++ks) {
        const int arow = wid * 16 + lm;
        bf16x8 pa = __builtin_bit_cast(
            bf16x8, *(const u16x8*)((const unsigned char*)Sb + arow * 256 +
                                    (((ks * 4 + hi) ^ (arow & 15)) << 4)));
#pragma unroll
        for (int j = 0; j < 4; ++j) {
          const int drow = j * 16 + lm;
          bf16x8 vb = __builtin_bit_cast(
              bf16x8, *(const u16x8*)((const unsigned char*)Vs + drow * 256 +
                                      (((ks * 4 + hi) ^ (drow & 15)) << 4)));
          acc_o[j] = __builtin_amdgcn_mfma_f32_16x16x32_bf16(pa, vb, acc_o[j], 0, 0, 0);
        }
      }
    }
    __syncthreads();
  }

  float il[4];
#pragma unroll
  for (int e = 0; e < 4; ++e) il[e] = 1.0f / li[wid * 16 + hi * 4 + e];
#pragma unroll
  for (int j = 0; j < 4; ++j)
#pragma unroll
    for (int e = 0; e < 4; ++e) {
      const int row = q0 + wid * 16 + hi * 4 + e;
      const int col = h * 64 + j * 16 + lm;
      ob[(size_t)(b * TS + row) * TD + col] = f2b(acc_o[j][e] * il[e]);
    }
}

// ---------------- old f32->bf16 softmax (fallback path) ----------------
__global__ __launch_bounds__(256) void softmax_k(const float* __restrict__ Pf,
                                                 unsigned short* __restrict__ Pb) {
  const int r = blockIdx.x;
  const int valid = (r & (TS - 1)) + 1;
  const int tid = threadIdx.x;
  const float* row = Pf + (size_t)r * TS;
  unsigned short* orow = Pb + (size_t)r * TS;
  float vals[4];
  float lmax = -1e30f;
#pragma unroll
  for (int it = 0; it < 4; ++it) {
    int i = it * 256 + tid;
    float v = (i < valid) ? row[i] : -1e30f;
    vals[it] = v;
    lmax = fmaxf(lmax, v);
  }
#pragma unroll
  for (int o = 32; o > 0; o >>= 1) lmax = fmaxf(lmax, __shfl_down(lmax, o));
  __shared__ float ps[4];
  __shared__ float bcast;
  if ((tid & 63) == 0) ps[tid >> 6] = lmax;
  __syncthreads();
  if (tid == 0) bcast = fmaxf(fmaxf(ps[0], ps[1]), fmaxf(ps[2], ps[3]));
  __syncthreads();
  const float m = bcast;
  float lsum = 0.f;
#pragma unroll
  for (int it = 0; it < 4; ++it) {
    int i = it * 256 + tid;
    float e = (i < valid) ? __expf((vals[it] - m) * 0.125f) : 0.f;
    vals[it] = e;
    lsum += e;
  }
#pragma unroll
  for (int o = 32; o > 0; o >>= 1) lsum += __shfl_down(lsum, o);
  __syncthreads();
  if ((tid & 63) == 0) ps[tid >> 6] = lsum;
  __syncthreads();
  if (tid == 0) bcast = 1.0f / (ps[0] + ps[1] + ps[2] + ps[3]);
  __syncthreads();
  const float inv = bcast;
#pragma unroll
  for (int it = 0; it < 4; ++it) {
    int i = it * 256 + tid;
    orow[i] = f2b(vals[it] * inv);
  }
}

// ---------------- log_softmax over V, in place (fallback path) -------------
__global__ __launch_bounds__(256) void logsoftmax_k(float* __restrict__ logits) {
  const int r = blockIdx.x;
  float* row = logits + (size_t)r * TV;
  const int tid = threadIdx.x;
  float m = -1e30f, s = 0.f;
  for (int i = tid * 4; i < TV; i += 1024) {
    f32x4 v = *(const f32x4*)(row + i);
#pragma unroll
    for (int j = 0; j < 4; ++j) {
      float xv = v[j];
      if (xv > m) { s = s * __expf(m - xv) + 1.f; m = xv; }
      else s += __expf(xv - m);
    }
  }
#pragma unroll
  for (int o = 32; o > 0; o >>= 1) {
    float mo = __shfl_down(m, o);
    float so = __shfl_down(s, o);
    float M = fmaxf(m, mo);
    s = s * __expf(m - M) + so * __expf(mo - M);
    m = M;
  }
  __shared__ float pm[4], psv[4];
  __shared__ float blse;
  if ((tid & 63) == 0) { pm[tid >> 6] = m; psv[tid >> 6] = s; }
  __syncthreads();
  if (tid == 0) {
    float M = fmaxf(fmaxf(pm[0], pm[1]), fmaxf(pm[2], pm[3]));
    float S = psv[0] * __expf(pm[0] - M) + psv[1] * __expf(pm[1] - M) +
              psv[2] * __expf(pm[2] - M) + psv[3] * __expf(pm[3] - M);
    blse = M + logf(S);
  }
  __syncthreads();
  const float lse = blse;
  for (int i = tid * 4; i < TV; i += 1024) {
    f32x4 v = *(const f32x4*)(row + i);
    v[0] -= lse; v[1] -= lse; v[2] -= lse; v[3] -= lse;
    *(f32x4*)(row + i) = v;
  }
}

// ---------------- final: LSE from reg-buffered bf16 row; write f32 ---------
__global__ __launch_bounds__(1024) void lse_final_k(
    float* __restrict__ out, const unsigned short* __restrict__ lb) {
  const int r = blockIdx.x;
  const int tid = threadIdx.x;
  const unsigned short* row = lb + (size_t)r * 64000 + 32000;
  u16x4 buf[8];
#pragma unroll
  for (int i = 0; i < 8; ++i) {
    const int e = tid * 4 + i * 4096;
    if (e < TV) buf[i] = *(const u16x4*)(row + e);
  }
  float m = -1e30f;
#pragma unroll
  for (int i = 0; i < 8; ++i) {
    const int e = tid * 4 + i * 4096;
    if (e < TV) {
#pragma unroll
      for (int j = 0; j < 4; ++j) m = fmaxf(m, b2f(buf[i][j]));
    }
  }
  float s = 0.f;
#pragma unroll
  for (int i = 0; i < 8; ++i) {
    const int e = tid * 4 + i * 4096;
    if (e < TV) {
#pragma unroll
      for (int j = 0; j < 4; ++j) s += __expf(b2f(buf[i][j]) - m);
    }
  }
#pragma unroll
  for (int o = 32; o > 0; o >>= 1) {
    float mo = __shfl_xor(m, o);
    float so = __shfl_xor(s, o);
    float M = fmaxf(m, mo);
    s = s * __expf(m - M) + so * __expf(mo - M);
    m = M;
  }
  __shared__ float pm[16], psv[16];
  __shared__ float blse;
  if ((tid & 63) == 0) { pm[tid >> 6] = m; psv[tid >> 6] = s; }
  __syncthreads();
  if (tid == 0) {
    float M = pm[0];
#pragma unroll
    for (int w = 1; w < 16; ++w) M = fmaxf(M, pm[w]);
    float S = 0.f;
#pragma unroll
    for (int w = 0; w < 16; ++w) S += psv[w] * __expf(pm[w] - M);
    blse = M + logf(S);
  }
  __syncthreads();
  const float lse = blse;
  float* orow = out + (size_t)r * TV;
#pragma unroll
  for (int i = 0; i < 8; ++i) {
    const int e = tid * 4 + i * 4096;
    if (e < TV) {
      f32x4 v;
#pragma unroll
      for (int j = 0; j < 4; ++j) v[j] = b2f(buf[i][j]) - lse;
      *(f32x4*)(orow + e) = v;
    }
  }
}

// ---------------- weight transpose+convert: [K,N] f32 -> [N,K] bf16 --------
struct TEnt { const float* s; unsigned short* d; int K; int N; int t0; };
struct TTab { TEnt e[13]; };

__global__ __launch_bounds__(256) void transpose_all_k(TTab tab) {
  const int bid = blockIdx.x;
  int mi = 0;
#pragma unroll
  for (int i = 1; i < 13; ++i)
    if (bid >= tab.e[i].t0) mi = i;
  const TEnt E = tab.e[mi];
  const int lt = bid - E.t0;
  const int ntn = E.N >> 6;
  const int kt = lt / ntn, nt = lt - kt * ntn;
  const int k0 = kt << 6, n0 = nt << 6;
  __shared__ unsigned short t[64][68];
  const int tid = threadIdx.x;
  const int cr = tid >> 4, cc = (tid & 15) << 2;
#pragma unroll
  for (int it = 0; it < 4; ++it) {
    const int kl = it * 16 + cr;
    f32x4 v = *(const f32x4*)(E.s + (size_t)(k0 + kl) * E.N + n0 + cc);
    u16x4 o;
#pragma unroll
    for (int j = 0; j < 4; ++j) o[j] = f2b(v[j]);
    *(u16x4*)&t[kl][cc] = o;
  }
  __syncthreads();
  const int nl = tid & 63, kc = (tid >> 6) << 4;
  u16x8 r0, r1;
#pragma unroll
  for (int j = 0; j < 8; ++j) { r0[j] = t[kc + j][nl]; r1[j] = t[kc + 8 + j][nl]; }
  unsigned short* dp = E.d + (size_t)(n0 + nl) * E.K + k0 + kc;
  *(u16x8*)dp = r0;
  *(u16x8*)(dp + 8) = r1;
}

// ---------------- V slice transpose: qkv[:,2048+d] -> vt[b][d][s] ----------
__global__ __launch_bounds__(256) void vtrans_k(const unsigned short* __restrict__ qkv,
                                                unsigned short* __restrict__ vt) {
  const int d0 = blockIdx.x << 6, s0 = blockIdx.y << 6, b = blockIdx.z;
  __shared__ unsigned short t[64][68];
  const int tid = threadIdx.x;
  const int cr = tid >> 4, cc = (tid & 15) << 2;
#pragma unroll
  for (int it = 0; it < 4; ++it) {
    const int sl = it * 16 + cr;
    u16x4 v = *(const u16x4*)(qkv + (size_t)(b * TS + s0 + sl) * 3072 + 2048 + d0 + cc);
    *(u16x4*)&t[sl][cc] = v;
  }
  __syncthreads();
  const int dl = tid & 63, sc = (tid >> 6) << 4;
  u16x8 r0, r1;
#pragma unroll
  for (int j = 0; j < 8; ++j) { r0[j] = t[sc + j][dl]; r1[j] = t[sc + 8 + j][dl]; }
  unsigned short* dp = vt + (size_t)b * TD * TS + (size_t)(d0 + dl) * TS + s0 + sc;
  *(u16x8*)dp = r0;
  *(u16x8*)(dp + 8) = r1;
}

// ---------------- GEMM: A,B bf16 [*,K]; global_load_lds; opt. XCD swizzle --
template <int BM_, int BN, typename OT, bool HB, bool HS, bool HR, bool CSKIP,
          bool CAUSA, bool GSWAP, bool XSWZ>
__global__ __launch_bounds__(256) void gemm2_k(
    const unsigned short* __restrict__ A, int lda, long long sAo, long long sAi, int iA,
    const unsigned short* __restrict__ B, int ldb, long long sBo, long long sBi, int iB,
    OT* __restrict__ C, int ldc, long long sCo, long long sCi, int iC,
    const float* __restrict__ bias, const float* __restrict__ res, int K) {
  constexpr int WN = BN / 2;
  constexpr int FN = WN / 16;
  constexpr int FM = BM_ / 32;
  int bx = blockIdx.x, by = blockIdx.y;
  if constexpr (XSWZ) {
    const int nwg = gridDim.x * gridDim.y;
    const int bid = by * gridDim.x + bx;
    const int q = nwg >> 3, rr = nwg & 7;
    const int xcd = bid & 7, idx = bid >> 3;
    const int nid = (xcd < rr ? xcd * (q + 1) : rr * (q + 1) + (xcd - rr) * q) + idx;
    bx = nid % gridDim.x;
    by = nid / gridDim.x;
  }
  const int m0 = (GSWAP ? bx : by) * BM_;
  const int n0 = (GSWAP ? by : bx) * BN;
  if (CSKIP && n0 > m0 + BM_ - 1) return;
  const int bz = blockIdx.z;
  A += (long long)(bz / iA) * sAo + (long long)(bz % iA) * sAi;
  B += (long long)(bz / iB) * sBo + (long long)(bz % iB) * sBi;
  C += (long long)(bz / iC) * sCo + (long long)(bz % iC) * sCi;

  __shared__ __attribute__((aligned(16))) unsigned short As[BM_ * 64];
  __shared__ __attribute__((aligned(16))) unsigned short Bs[BN * 64];

  const int tid = threadIdx.x, lane = tid & 63, wid = tid >> 6;
  const int wm = wid >> 1, wn = wid & 1;
  const int lm = lane & 15, hi = lane >> 4;

  const int srow = lane >> 3, schk = lane & 7;
  const int sxor = (srow & 7) << 4;
  const unsigned char* Ag =
      (const unsigned char*)(A + (size_t)(m0 + wid * (BM_ / 4) + srow) * lda) +
      ((schk * 16) ^ sxor);
  const unsigned char* Bgp =
      (const unsigned char*)(B + (size_t)(n0 + wid * (BN / 4) + srow) * ldb) +
      ((schk * 16) ^ sxor);
  unsigned char* AsW = (unsigned char*)As + wid * (BM_ / 4) * 128;
  unsigned char* BsW = (unsigned char*)Bs + wid * (BN / 4) * 128;
  const size_t ldab = (size_t)lda * 2, ldbb = (size_t)ldb * 2;

  f32x4 acc[FM][FN] = {};
  const int kend = CAUSA ? ((K < m0 + BM_) ? K : m0 + BM_) : K;
  const int axor = (lm & 7) << 4;

  for (int k0 = 0; k0 < kend; k0 += 64) {
#pragma unroll
    for (int i = 0; i < BM_ / 32; ++i) glds16(Ag + (size_t)i * 8 * ldab, AsW + i * 1024);
#pragma unroll
    for (int i = 0; i < BN / 32; ++i) glds16(Bgp + (size_t)i * 8 * ldbb, BsW + i * 1024);
    Ag += 128;
    Bgp += 128;
    __syncthreads();
#pragma unroll
    for (int kk = 0; kk < 2; ++kk) {
      const int kb = (kk * 64 + hi * 16) ^ axor;
      bf16x8 af[FM], bfr[FN];
#pragma unroll
      for (int i = 0; i < FM; ++i)
        af[i] = __builtin_bit_cast(
            bf16x8, *(const u16x8*)((const unsigned char*)As +
                                    (wm * (BM_ / 2) + i * 16 + lm) * 128 + kb));
#pragma unroll
      for (int j = 0; j < FN; ++j)
        bfr[j] = __builtin_bit_cast(
            bf16x8,
            *(const u16x8*)((const unsigned char*)Bs + (wn * WN + j * 16 + lm) * 128 + kb));
#pragma unroll
      for (int i = 0; i < FM; ++i)
#pragma unroll
        for (int j = 0; j < FN; ++j)
          acc[i][j] = __builtin_amdgcn_mfma_f32_16x16x32_bf16(af[i], bfr[j],
                                                              acc[i][j], 0, 0, 0);
    }
    __syncthreads();
  }

#pragma unroll
  for (int i = 0; i < FM; ++i) {
    const int rbase = m0 + wm * (BM_ / 2) + i * 16 + (hi << 2);
#pragma unroll
    for (int j = 0; j < FN; ++j) {
      const int c = n0 + wn * WN + j * 16 + lm;
      const float bval = HB ? bias[c] : 0.f;
#pragma unroll
      for (int e = 0; e < 4; ++e) {
        float v = acc[i][j][e];
        if (HB) v += bval;
        if (HS) v = v / (1.f + __expf(-v));
        const long long off = (long long)(rbase + e) * ldc + c;
        if (HR) v += res[off];
        if constexpr (std::is_same_v<OT, float>) C[off] = v;
        else C[off] = f2b(v);
      }
    }
  }
}

// ---------------- old GEMM (round-1, fallback path) ----------------
template <int BN, typename BT, bool BNK, typename OT, bool HB, bool HS, bool HR,
          bool CSKIP, bool CAUSA>
__global__ __launch_bounds__(256) void gemm_k(
    const unsigned short* __restrict__ A, int lda, long long sAo, long long sAi, int iA,
    const BT* __restrict__ Bg, int ldb, long long sBo, long long sBi, int iB,
    OT* __restrict__ Cg, int ldc, long long sCo, long long sCi, int iC,
    const float* __restrict__ bias, const float* __restrict__ res, int K) {
  constexpr int WN = BN / 2;
  constexpr int FN = WN / 16;
  constexpr int FM = 4;
  const int m0 = blockIdx.y * BM;
  const int n0 = blockIdx.x * BN;
  if (CSKIP && n0 > m0 + BM - 1) return;
  const int bz = blockIdx.z;
  A  += (long long)(bz / iA) * sAo + (long long)(bz % iA) * sAi;
  Bg += (long long)(bz / iB) * sBo + (long long)(bz % iB) * sBi;
  Cg += (long long)(bz / iC) * sCo + (long long)(bz % iC) * sCi;

  __shared__ __attribute__((aligned(16))) unsigned short As[BM * BKP];
  __shared__ __attribute__((aligned(16))) unsigned short Bs[BN * BKP];

  const int tid = threadIdx.x;
  const int lane = tid & 63;
  const int wid = tid >> 6;
  const int wm = wid >> 1, wn = wid & 1;
  const int lm = lane & 15;
  const int lk = (lane >> 4) << 3;

  f32x4 acc[FM][FN] = {};
  const int kend = CAUSA ? ((K < m0 + BM) ? K : m0 + BM) : K;

  for (int k0 = 0; k0 < kend; k0 += BK) {
#pragma unroll
    for (int it = 0; it < (BM * BK / 8) / 256; ++it) {
      int idx = it * 256 + tid;
      int rowa = idx >> 3;
      int kc = (idx & 7) << 3;
      u16x8 av = *(const u16x8*)(A + (size_t)(m0 + rowa) * lda + (k0 + kc));
      *(u16x8*)&As[rowa * BKP + kc] = av;
    }
    if constexpr (BNK) {
#pragma unroll
      for (int it = 0; it < (BN * BK / 8) / 256; ++it) {
        int idx = it * 256 + tid;
        int rowb = idx >> 3;
        int kc = (idx & 7) << 3;
        u16x8 bv = *(const u16x8*)((const unsigned short*)Bg +
                                   (size_t)(n0 + rowb) * ldb + (k0 + kc));
        *(u16x8*)&Bs[rowb * BKP + (kc ^ (((rowb >> 3) & 7) << 3))] = bv;
      }
    } else {
      constexpr int NCH = BN / 8;
#pragma unroll
      for (int it = 0; it < (BK * NCH) / 256; ++it) {
        int idx = it * 256 + tid;
        int nc = (idx & (NCH - 1)) << 3;
        int kr = idx / NCH;
        unsigned short ub[8];
        if constexpr (std::is_same_v<BT, float>) {
          const float* bp = Bg + (size_t)(k0 + kr) * ldb + (n0 + nc);
          f32x4 b0 = *(const f32x4*)bp;
          f32x4 b1 = *(const f32x4*)(bp + 4);
#pragma unroll
          for (int j = 0; j < 4; ++j) { ub[j] = f2b(b0[j]); ub[4 + j] = f2b(b1[j]); }
        } else {
          const unsigned short* bp =
              (const unsigned short*)Bg + (size_t)(k0 + kr) * ldb + (n0 + nc);
          u16x8 raw = *(const u16x8*)bp;
#pragma unroll
          for (int j = 0; j < 8; ++j) ub[j] = raw[j];
        }
        const int sw = ((nc >> 3) & 7) << 3;
#pragma unroll
        for (int j = 0; j < 8; ++j) Bs[(nc + j) * BKP + (kr ^ sw)] = ub[j];
      }
    }
    __syncthreads();
#pragma unroll
    for (int kk = 0; kk < 2; ++kk) {
      bf16x8 af[FM];
      bf16x8 bfr[FN];
#pragma unroll
      for (int i = 0; i < FM; ++i)
        af[i] = __builtin_bit_cast(
            bf16x8, *(const u16x8*)&As[(wm * 64 + i * 16 + lm) * BKP + (kk * 32 + lk)]);
#pragma unroll
      for (int j = 0; j < FN; ++j) {
        const int nr = wn * WN + j * 16 + lm;
        bfr[j] = __builtin_bit_cast(
            bf16x8,
            *(const u16x8*)&Bs[nr * BKP + ((kk * 32 + lk) ^ (((nr >> 3) & 7) << 3))]);
      }
#pragma unroll
      for (int i = 0; i < FM; ++i)
#pragma unroll
        for (int j = 0; j < FN; ++j)
          acc[i][j] = __builtin_amdgcn_mfma_f32_16x16x32_bf16(af[i], bfr[j],
                                                              acc[i][j], 0, 0, 0);
    }
    __syncthreads();
  }

#pragma unroll
  for (int i = 0; i < FM; ++i) {
    const int rbase = m0 + wm * 64 + i * 16 + ((lane >> 4) << 2);
#pragma unroll
    for (int j = 0; j < FN; ++j) {
      const int c = n0 + wn * WN + j * 16 + lm;
      const float bval = HB ? bias[c] : 0.f;
#pragma unroll
      for (int e = 0; e < 4; ++e) {
        float v = acc[i][j][e];
        if (HB) v += bval;
        if (HS) v = v / (1.f + __expf(-v));
        const long long off = (long long)(rbase + e) * ldc + c;
        if (HR) v += res[off];
        if constexpr (std::is_same_v<OT, float>) Cg[off] = v;
        else Cg[off] = f2b(v);
      }
    }
  }
}

// ---------------------------------------------------------------------------
extern "C" void kernel_launch(void* const* d_in, const int* in_sizes, int n_in,
                              void* d_out, int out_size, void* d_ws, size_t ws_size,
                              hipStream_t stream) {
  const int*   tok = (const int*)d_in[0];
  const float* emb = (const float*)d_in[2];
  const float* Wq  = (const float*)d_in[3];
  const float* Wk  = (const float*)d_in[4];
  const float* Wv  = (const float*)d_in[5];
  const float* Wo  = (const float*)d_in[6];
  const float* al1 = (const float*)d_in[7];
  const float* al3 = (const float*)d_in[8];
  const float* W1  = (const float*)d_in[9];
  const float* b1  = (const float*)d_in[10];
  const float* W2  = (const float*)d_in[11];
  const float* b2  = (const float*)d_in[12];
  const float* alf = (const float*)d_in[13];
  const float* Wp  = (const float*)d_in[14];
  const float* bp  = (const float*)d_in[15];

  char* ws = (char*)d_ws;
  dim3 blk(256);

  const size_t NEED = 166199296ULL;
  if (ws_size >= NEED) {
    // ---------------- new path ----------------
    float* x           = (float*)(ws);                        // 8 MB
    unsigned short* nb = (unsigned short*)(ws + 8388608);     // 4 MB
    unsigned short* qkv= (unsigned short*)(ws + 12582912);    // 12 MB [2048,3072]
    unsigned short* vt = (unsigned short*)(ws + 25165824);    // 4 MB  [B][D][S]
    unsigned short* ob = (unsigned short*)(ws + 29360128);    // 4 MB
    unsigned short* f1b= (unsigned short*)(ws + 33554432);    // 16 MB [2048,4096]
    unsigned short* wqkvT = (unsigned short*)(ws + 50331648); // 12 MB
    unsigned short* woT   = (unsigned short*)(ws + 62914560); // 4 MB
    unsigned short* w1T   = (unsigned short*)(ws + 67108864); // 16 MB
    unsigned short* w2T   = (unsigned short*)(ws + 83886080); // 16 MB
    unsigned short* wpT   = (unsigned short*)(ws + 100663296);// 62.5 MB
    // bf16 logits: second half of each f32 row slot in d_out
    unsigned short* lgb = (unsigned short*)d_out + 32000;     // ldc=64000

    TTab tab;
    const int M1 = 1048576;
    tab.e[0]  = {Wq,           wqkvT,               1024, 1024, 0};
    tab.e[1]  = {Wk,           wqkvT + M1,          1024, 1024, 256};
    tab.e[2]  = {Wv,           wqkvT + 2 * M1,      1024, 1024, 512};
    tab.e[3]  = {Wq + M1,      wqkvT + 3 * M1,      1024, 1024, 768};
    tab.e[4]  = {Wk + M1,      wqkvT + 4 * M1,      1024, 1024, 1024};
    tab.e[5]  = {Wv + M1,      wqkvT + 5 * M1,      1024, 1024, 1280};
    tab.e[6]  = {Wo,           woT,                 1024, 1024, 1536};
    tab.e[7]  = {Wo + M1,      woT + M1,            1024, 1024, 1792};
    tab.e[8]  = {W1,           w1T,                 1024, 4096, 2048};
    tab.e[9]  = {W1 + 4 * M1,  w1T + 4 * M1,        1024, 4096, 3072};
    tab.e[10] = {W2,           w2T,                 4096, 1024, 4096};
    tab.e[11] = {W2 + 4 * M1,  w2T + 4 * M1,        4096, 1024, 5120};
    tab.e[12] = {Wp,           wpT,                 1024, 32000, 6144};
    transpose_all_k<<<14144, blk, 0, stream>>>(tab);

    embed_pe_k<<<TB * TS, blk, 0, stream>>>(tok, emb, x);

    for (int l = 0; l < TL; ++l) {
      rms_k<<<TB * TS, blk, 0, stream>>>(x, al1 + (size_t)l * TD, nb);

      // fused QKV: [2048,1024] x [3072,1024]^T -> qkv (128x96 tile, 512 blk)
      gemm2_k<128, 96, unsigned short, false, false, false, false, false, false, true>
          <<<dim3(32, 16, 1), blk, 0, stream>>>(
              nb, TD, 0, 0, 1, wqkvT + (size_t)l * 3 * M1, TD, 0, 0, 1,
              qkv, 3072, 0, 0, 1, nullptr, nullptr, TD);

      vtrans_k<<<dim3(16, 16, TB), blk, 0, stream>>>(qkv, vt);

      // fused flash attention: QK^T + online softmax + PV
      attn_k<<<dim3(8, TB * TH), dim3(512), 0, stream>>>(qkv, vt, ob);

      // x += O @ Wo  (128x64 tile, 256 blk)
      gemm2_k<128, 64, float, false, false, true, false, false, false, true>
          <<<dim3(16, 16, 1), blk, 0, stream>>>(
              ob, TD, 0, 0, 1, woT + (size_t)l * M1, TD, 0, 0, 1,
              x, TD, 0, 0, 1, nullptr, x, TD);

      rms_k<<<TB * TS, blk, 0, stream>>>(x, al3 + (size_t)l * TD, nb);

      // f1 = silu(n @ W1 + b1)  (128x128 tile, 512 blk)
      gemm2_k<128, 128, unsigned short, true, true, false, false, false, false, true>
          <<<dim3(32, 16, 1), blk, 0, stream>>>(
              nb, TD, 0, 0, 1, w1T + (size_t)l * 4 * M1, TD, 0, 0, 1,
              f1b, TDFF, 0, 0, 1, b1 + (size_t)l * TDFF, nullptr, TD);

      // x += f1 @ W2 + b2  (128x64 tile, 256 blk)
      gemm2_k<128, 64, float, true, false, true, false, false, false, true>
          <<<dim3(16, 16, 1), blk, 0, stream>>>(
              f1b, TDFF, 0, 0, 1, w2T + (size_t)l * 4 * M1, TDFF, 0, 0, 1,
              x, TD, 0, 0, 1, b2 + (size_t)l * TD, x, TDFF);
    }

    rms_k<<<TB * TS, blk, 0, stream>>>(x, alf, nb);

    // logits (bf16, colocated) = n @ Wp + bp (plain epilogue; LSE in finalizer)
    gemm2_k<128, 128, unsigned short, true, false, false, false, false, true, true>
        <<<dim3(16, 250, 1), blk, 0, stream>>>(
            nb, TD, 0, 0, 1, wpT, TD, 0, 0, 1, lgb, 64000, 0, 0, 1,
            bp, nullptr, TD);

    lse_final_k<<<TB * TS, dim3(1024), 0, stream>>>(
        (float*)d_out, (const unsigned short*)d_out);
    return;
  }

  // ---------------- fallback: round-1 path ----------------
  {
    float* x            = (float*)(ws);
    unsigned short* nb  = (unsigned short*)(ws + 8388608);
    unsigned short* qb  = (unsigned short*)(ws + 12582912);
    unsigned short* kb  = (unsigned short*)(ws + 16777216);
    unsigned short* vb  = (unsigned short*)(ws + 20971520);
    unsigned short* ob  = (unsigned short*)(ws + 25165824);
    unsigned short* f1b = (unsigned short*)(ws + 29360128);
    float* Pf = (float*)d_out;
    unsigned short* Pb = (unsigned short*)d_out + 67108864LL;

    embed_pe_k<<<TB * TS, blk, 0, stream>>>(tok, emb, x);
    for (int l = 0; l < TL; ++l) {
      const float* Wq_l = Wq + (size_t)l * TD * TD;
      const float* Wk_l = Wk + (size_t)l * TD * TD;
      const float* Wv_l = Wv + (size_t)l * TD * TD;
      const float* Wo_l = Wo + (size_t)l * TD * TD;
      const float* W1_l = W1 + (size_t)l * TD * TDFF;
      const float* W2_l = W2 + (size_t)l * TDFF * TD;

      rms_k<<<TB * TS, blk, 0, stream>>>(x, al1 + (size_t)l * TD, nb);
      gemm_k<128, float, false, unsigned short, false, false, false, false, false>
          <<<dim3(TD / 128, (TB * TS) / BM, 1), blk, 0, stream>>>(
              nb, TD, 0, 0, 1, Wq_l, TD, 0, 0, 1, qb, TD, 0, 0, 1, nullptr, nullptr, TD);
      gemm_k<128, float, false, unsigned short, false, false, false, false, false>
          <<<dim3(TD / 128, (TB * TS) / BM, 1), blk, 0, stream>>>(
              nb, TD, 0, 0, 1, Wk_l, TD, 0, 0, 1, kb, TD, 0, 0, 1, nullptr, nullptr, TD);
      gemm_k<128, float, false, unsigned short, false, false, false, false, false>
          <<<dim3(TD / 128, (TB * TS) / BM, 1), blk, 0, stream>>>(
              nb, TD, 0, 0, 1, Wv_l, TD, 0, 0, 1, vb, TD, 0, 0, 1, nullptr, nullptr, TD);
      gemm_k<128, unsigned short, true, float, false, false, false, true, false>
          <<<dim3(TS / 128, TS / 128, TB * TH), blk, 0, stream>>>(
              qb, TD, (long long)TS * TD, THD, TH,
              kb, TD, (long long)TS * TD, THD, TH,
              Pf, TS, (long long)TS * TS, 0, 1, nullptr, nullptr, THD);
      softmax_k<<<TB * TH * TS, blk, 0, stream>>>(Pf, Pb);
      gemm_k<64, unsigned short, false, unsigned short, false, false, false, false, true>
          <<<dim3(1, TS / 128, TB * TH), blk, 0, stream>>>(
              Pb, TS, (long long)TS * TS, 0, 1,
              vb, TD, (long long)TS * TD, THD, TH,
              ob, TD, (long long)TS * TD, THD, TH, nullptr, nullptr, TS);
      gemm_k<128, float, false, float, false, false, true, false, false>
          <<<dim3(TD / 128, (TB * TS) / BM, 1), blk, 0, stream>>>(
              ob, TD, 0, 0, 1, Wo_l, TD, 0, 0, 1, x, TD, 0, 0, 1, nullptr, x, TD);
      rms_k<<<TB * TS, blk, 0, stream>>>(x, al3 + (size_t)l * TD, nb);
      gemm_k<128, float, false, unsigned short, true, true, false, false, false>
          <<<dim3(TDFF / 128, (TB * TS) / BM, 1), blk, 0, stream>>>(
              nb, TD, 0, 0, 1, W1_l, TDFF, 0, 0, 1, f1b, TDFF, 0, 0, 1,
              b1 + (size_t)l * TDFF, nullptr, TD);
      gemm_k<128, float, false, float, true, false, true, false, false>
          <<<dim3(TD / 128, (TB * TS) / BM, 1), blk, 0, stream>>>(
              f1b, TDFF, 0, 0, 1, W2_l, TD, 0, 0, 1, x, TD, 0, 0, 1,
              b2 + (size_t)l * TD, x, TDFF);
    }
    rms_k<<<TB * TS, blk, 0, stream>>>(x, alf, nb);
    gemm_k<128, float, false, float, true, false, false, false, false>
        <<<dim3(TV / 128, (TB * TS) / BM, 1), blk, 0, stream>>>(
            nb, TD, 0, 0, 1, Wp, TV, 0, 0, 1, (float*)d_out, TV, 0, 0, 1,
            bp, nullptr, TD);
    logsoftmax_k<<<TB * TS, blk, 0, stream>>>((float*)d_out);
  }
}

// Round 8
// 652.795 us; speedup vs baseline: 1.0735x; 1.0735x over previous
//
#include <hip/hip_runtime.h>
#include <hip/hip_bf16.h>
#include <type_traits>

// ---------------------------------------------------------------------------
// Round 8: revert to R6 tile configs (R7 regressed: 1-2 blk/CU starved TLP).
// + 2-phase double-buffer on W2/Wo (no occupancy cost) + embed/rms0 fusion.
// ---------------------------------------------------------------------------

typedef float  f32x4 __attribute__((ext_vector_type(4)));
typedef __bf16 bf16x8 __attribute__((ext_vector_type(8)));
typedef unsigned short u16x8 __attribute__((ext_vector_type(8)));
typedef unsigned short u16x4 __attribute__((ext_vector_type(4)));

#define DI __device__ __forceinline__

constexpr int TB = 2, TS = 1024, TD = 1024, TH = 16, TV = 32000, TL = 2,
              TDFF = 4096, THD = 64;
constexpr int BM = 128, BK = 64, BKP = 72;

DI unsigned short f2b(float f) {
  __bf16 h = (__bf16)f;
  return __builtin_bit_cast(unsigned short, h);
}
DI float b2f(unsigned short u) {
  unsigned v = ((unsigned)u) << 16;
  return __builtin_bit_cast(float, v);
}

DI void glds16(const void* g, void* l) {
  __builtin_amdgcn_global_load_lds(
      (const __attribute__((address_space(1))) unsigned int*)g,
      (__attribute__((address_space(3))) unsigned int*)l, 16, 0, 0);
}

// ---------------- fused: embedding*sqrt(D) + posenc + layer-0 RMS ----------
__global__ __launch_bounds__(256) void embed_rms_k(
    const int* __restrict__ tok, const float* __restrict__ emb,
    const float* __restrict__ alpha, float* __restrict__ x,
    unsigned short* __restrict__ out) {
  const int bs = blockIdx.x;
  const int s  = bs & (TS - 1);
  const int t  = tok[bs];
  const int tid = threadIdx.x;
  const int d0 = tid << 2;
  f32x4 e = *(const f32x4*)(emb + (size_t)t * TD + d0);
  f32x4 r;
#pragma unroll
  for (int j = 0; j < 4; ++j) {
    int d = d0 + j;
    int i2 = d >> 1;
    float freq = __expf((float)(2 * i2) * (-9.210340371976184f / (float)TD));
    float arg = (float)s * freq;
    float pe = (d & 1) ? __cosf(arg) : __sinf(arg);
    r[j] = e[j] * 32.0f + pe;
  }
  *(f32x4*)(x + (size_t)bs * TD + d0) = r;
  float ss = r[0] * r[0] + r[1] * r[1] + r[2] * r[2] + r[3] * r[3];
#pragma unroll
  for (int o = 32; o > 0; o >>= 1) ss += __shfl_down(ss, o);
  __shared__ float ps[4];
  __shared__ float invs;
  if ((tid & 63) == 0) ps[tid >> 6] = ss;
  __syncthreads();
  if (tid == 0) {
    float tot = ps[0] + ps[1] + ps[2] + ps[3];
    invs = 1.0f / (sqrtf(tot * (1.0f / (float)TD)) + 1e-8f);
  }
  __syncthreads();
  const float inv = invs;
  f32x4 av = *(const f32x4*)(alpha + d0);
  u16x4 ov;
#pragma unroll
  for (int j = 0; j < 4; ++j) ov[j] = f2b(av[j] * r[j] * inv);
  *(u16x4*)(out + (size_t)bs * TD + d0) = ov;
}

// ---------------- embedding * sqrt(D) + sinusoidal posenc (fallback) -------
__global__ __launch_bounds__(256) void embed_pe_k(const int* __restrict__ tok,
                                                  const float* __restrict__ emb,
                                                  float* __restrict__ x) {
  const int bs = blockIdx.x;
  const int s  = bs & (TS - 1);
  const int t  = tok[bs];
  const int d0 = threadIdx.x << 2;
  f32x4 e = *(const f32x4*)(emb + (size_t)t * TD + d0);
  f32x4 r;
#pragma unroll
  for (int j = 0; j < 4; ++j) {
    int d = d0 + j;
    int i2 = d >> 1;
    float freq = __expf((float)(2 * i2) * (-9.210340371976184f / (float)TD));
    float arg = (float)s * freq;
    float pe = (d & 1) ? __cosf(arg) : __sinf(arg);
    r[j] = e[j] * 32.0f + pe;
  }
  *(f32x4*)(x + (size_t)bs * TD + d0) = r;
}

// ---------------- RMS norm -> bf16 ----------------
__global__ __launch_bounds__(256) void rms_k(const float* __restrict__ xin,
                                             const float* __restrict__ alpha,
                                             unsigned short* __restrict__ out) {
  const int row = blockIdx.x;
  const int tid = threadIdx.x;
  const int d0 = tid << 2;
  f32x4 xv = *(const f32x4*)(xin + (size_t)row * TD + d0);
  float ss = xv[0] * xv[0] + xv[1] * xv[1] + xv[2] * xv[2] + xv[3] * xv[3];
#pragma unroll
  for (int o = 32; o > 0; o >>= 1) ss += __shfl_down(ss, o);
  __shared__ float ps[4];
  __shared__ float invs;
  if ((tid & 63) == 0) ps[tid >> 6] = ss;
  __syncthreads();
  if (tid == 0) {
    float tot = ps[0] + ps[1] + ps[2] + ps[3];
    invs = 1.0f / (sqrtf(tot * (1.0f / (float)TD)) + 1e-8f);
  }
  __syncthreads();
  const float inv = invs;
  f32x4 av = *(const f32x4*)(alpha + d0);
  u16x4 ov;
#pragma unroll
  for (int j = 0; j < 4; ++j) ov[j] = f2b(av[j] * xv[j] * inv);
  *(u16x4*)(out + (size_t)row * TD + d0) = ov;
}

// ---------------- fused flash attention -----------------------------------
__global__ __launch_bounds__(512) void attn_k(
    const unsigned short* __restrict__ qkv, const unsigned short* __restrict__ vt,
    unsigned short* __restrict__ ob) {
  const int q0 = blockIdx.x << 7;
  const int bh = blockIdx.y;
  const int b = bh >> 4, h = bh & 15;
  const unsigned short* Qg = qkv + (size_t)(b * TS) * 3072 + h * 64;
  const unsigned short* Kg = Qg + 1024;
  const unsigned short* Vg = vt + (size_t)b * TD * TS + (size_t)(h * 64) * TS;

  __shared__ __attribute__((aligned(16))) unsigned short Qs[128 * 64];
  __shared__ __attribute__((aligned(16))) unsigned short Ks[128 * 64];
  __shared__ __attribute__((aligned(16))) unsigned short Vs[64 * 128];
  __shared__ __attribute__((aligned(16))) unsigned short Sb[128 * 128];
  __shared__ float mi[128], li[128], scl[128];

  const int tid = threadIdx.x, lane = tid & 63, wid = tid >> 6;
  const int lm = lane & 15, hi = lane >> 4;
  const int wm = wid >> 2, wn = wid & 3;

  if (tid < 128) { mi[tid] = -3.0e38f; li[tid] = 0.f; }

  {
    const int srow = lane >> 3, schk = lane & 7;
#pragma unroll
    for (int i = 0; i < 2; ++i) {
      const int row = wid * 16 + i * 8 + srow;
      const unsigned char* src =
          (const unsigned char*)(Qg + (size_t)(q0 + row) * 3072) +
          ((schk * 16) ^ ((srow & 7) << 4));
      glds16(src, (unsigned char*)Qs + (wid * 16 + i * 8) * 128);
    }
  }

  f32x4 acc_o[4] = {};
  const int nt = blockIdx.x + 1;

  for (int t = 0; t < nt; ++t) {
    const int kv0 = t << 7;
    {
      const int srow = lane >> 3, schk = lane & 7;
#pragma unroll
      for (int i = 0; i < 2; ++i) {
        const int row = wid * 16 + i * 8 + srow;
        const unsigned char* src =
            (const unsigned char*)(Kg + (size_t)(kv0 + row) * 3072) +
            ((schk * 16) ^ ((srow & 7) << 4));
        glds16(src, (unsigned char*)Ks + (wid * 16 + i * 8) * 128);
      }
      const int vrow4 = lane >> 4, vchk = lane & 15;
#pragma unroll
      for (int i = 0; i < 2; ++i) {
        const int row = wid * 8 + i * 4 + vrow4;
        const unsigned char* src =
            (const unsigned char*)(Vg + (size_t)row * TS + kv0) +
            ((vchk * 16) ^ ((row & 15) << 4));
        glds16(src, (unsigned char*)Vs + (wid * 8 + i * 4) * 256);
      }
    }
    asm volatile("s_waitcnt vmcnt(0)");
    __syncthreads();

    f32x4 acc_s[4][2] = {};
#pragma unroll
    for (int kk = 0; kk < 2; ++kk) {
      bf16x8 af[4], bf[2];
#pragma unroll
      for (int i = 0; i < 4; ++i) {
        const int row = wm * 64 + i * 16 + lm;
        af[i] = __builtin_bit_cast(
            bf16x8, *(const u16x8*)((const unsigned char*)Qs + row * 128 +
                                    (((kk * 4 + hi) ^ (row & 7)) << 4)));
      }
#pragma unroll
      for (int j = 0; j < 2; ++j) {
        const int row = wn * 32 + j * 16 + lm;
        bf[j] = __builtin_bit_cast(
            bf16x8, *(const u16x8*)((const unsigned char*)Ks + row * 128 +
                                    (((kk * 4 + hi) ^ (row & 7)) << 4)));
      }
#pragma unroll
      for (int i = 0; i < 4; ++i)
#pragma unroll
        for (int j = 0; j < 2; ++j)
          acc_s[i][j] = __builtin_amdgcn_mfma_f32_16x16x32_bf16(af[i], bf[j],
                                                                acc_s[i][j], 0, 0, 0);
    }
#pragma unroll
    for (int i = 0; i < 4; ++i)
#pragma unroll
      for (int j = 0; j < 2; ++j)
#pragma unroll
        for (int e = 0; e < 4; ++e) {
          const int row = wm * 64 + i * 16 + hi * 4 + e;
          const int col = wn * 32 + j * 16 + lm;
          float v = acc_s[i][j][e] * 0.125f;
          if (kv0 + col > q0 + row) v = -1e30f;
          const int chunk = (col >> 3) ^ (row & 15);
          *(unsigned short*)((unsigned char*)Sb + row * 256 + chunk * 16 +
                             ((col & 7) << 1)) = f2b(v);
        }
    __syncthreads();

    {
      const int r = tid >> 2, qt = tid & 3;
      float v[32];
      float rmax = -3.0e38f;
#pragma unroll
      for (int cc = 0; cc < 4; ++cc) {
        const int c = qt * 4 + cc;
        u16x8 pk = *(const u16x8*)((const unsigned char*)Sb + r * 256 +
                                   ((c ^ (r & 15)) << 4));
#pragma unroll
        for (int j = 0; j < 8; ++j) {
          v[cc * 8 + j] = b2f(pk[j]);
          rmax = fmaxf(rmax, v[cc * 8 + j]);
        }
      }
      rmax = fmaxf(rmax, __shfl_xor(rmax, 1));
      rmax = fmaxf(rmax, __shfl_xor(rmax, 2));
      const float mold = mi[r];
      const float mnew = fmaxf(mold, rmax);
      float lsum = 0.f;
#pragma unroll
      for (int cc = 0; cc < 4; ++cc) {
        const int c = qt * 4 + cc;
        u16x8 pk;
#pragma unroll
        for (int j = 0; j < 8; ++j) {
          float p = __expf(v[cc * 8 + j] - mnew);
          lsum += p;
          pk[j] = f2b(p);
        }
        *(u16x8*)((unsigned char*)Sb + r * 256 + ((c ^ (r & 15)) << 4)) = pk;
      }
      lsum += __shfl_xor(lsum, 1);
      lsum += __shfl_xor(lsum, 2);
      if (qt == 0) {
        const float sc = __expf(mold - mnew);
        scl[r] = sc;
        li[r] = li[r] * sc + lsum;
        mi[r] = mnew;
      }
    }
    __syncthreads();

    {
      float sc[4];
#pragma unroll
      for (int e = 0; e < 4; ++e) sc[e] = scl[wid * 16 + hi * 4 + e];
#pragma unroll
      for (int j = 0; j < 4; ++j)
#pragma unroll
        for (int e = 0; e < 4; ++e) acc_o[j][e] *= sc[e];
#pragma unroll
      for (int ks = 0; ks < 4; ++ks) {
        const int arow = wid * 16 + lm;
        bf16x8 pa = __builtin_bit_cast(
            bf16x8, *(const u16x8*)((const unsigned char*)Sb + arow * 256 +
                                    (((ks * 4 + hi) ^ (arow & 15)) << 4)));
#pragma unroll
        for (int j = 0; j < 4; ++j) {
          const int drow = j * 16 + lm;
          bf16x8 vb = __builtin_bit_cast(
              bf16x8, *(const u16x8*)((const unsigned char*)Vs + drow * 256 +
                                      (((ks * 4 + hi) ^ (drow & 15)) << 4)));
          acc_o[j] = __builtin_amdgcn_mfma_f32_16x16x32_bf16(pa, vb, acc_o[j], 0, 0, 0);
        }
      }
    }
    __syncthreads();
  }

  float il[4];
#pragma unroll
  for (int e = 0; e < 4; ++e) il[e] = 1.0f / li[wid * 16 + hi * 4 + e];
#pragma unroll
  for (int j = 0; j < 4; ++j)
#pragma unroll
    for (int e = 0; e < 4; ++e) {
      const int row = q0 + wid * 16 + hi * 4 + e;
      const int col = h * 64 + j * 16 + lm;
      ob[(size_t)(b * TS + row) * TD + col] = f2b(acc_o[j][e] * il[e]);
    }
}

// ---------------- old f32->bf16 softmax (fallback path) ----------------
__global__ __launch_bounds__(256) void softmax_k(const float* __restrict__ Pf,
                                                 unsigned short* __restrict__ Pb) {
  const int r = blockIdx.x;
  const int valid = (r & (TS - 1)) + 1;
  const int tid = threadIdx.x;
  const float* row = Pf + (size_t)r * TS;
  unsigned short* orow = Pb + (size_t)r * TS;
  float vals[4];
  float lmax = -1e30f;
#pragma unroll
  for (int it = 0; it < 4; ++it) {
    int i = it * 256 + tid;
    float v = (i < valid) ? row[i] : -1e30f;
    vals[it] = v;
    lmax = fmaxf(lmax, v);
  }
#pragma unroll
  for (int o = 32; o > 0; o >>= 1) lmax = fmaxf(lmax, __shfl_down(lmax, o));
  __shared__ float ps[4];
  __shared__ float bcast;
  if ((tid & 63) == 0) ps[tid >> 6] = lmax;
  __syncthreads();
  if (tid == 0) bcast = fmaxf(fmaxf(ps[0], ps[1]), fmaxf(ps[2], ps[3]));
  __syncthreads();
  const float m = bcast;
  float lsum = 0.f;
#pragma unroll
  for (int it = 0; it < 4; ++it) {
    int i = it * 256 + tid;
    float e = (i < valid) ? __expf((vals[it] - m) * 0.125f) : 0.f;
    vals[it] = e;
    lsum += e;
  }
#pragma unroll
  for (int o = 32; o > 0; o >>= 1) lsum += __shfl_down(lsum, o);
  __syncthreads();
  if ((tid & 63) == 0) ps[tid >> 6] = lsum;
  __syncthreads();
  if (tid == 0) bcast = 1.0f / (ps[0] + ps[1] + ps[2] + ps[3]);
  __syncthreads();
  const float inv = bcast;
#pragma unroll
  for (int it = 0; it < 4; ++it) {
    int i = it * 256 + tid;
    orow[i] = f2b(vals[it] * inv);
  }
}

// ---------------- log_softmax over V, in place (fallback path) -------------
__global__ __launch_bounds__(256) void logsoftmax_k(float* __restrict__ logits) {
  const int r = blockIdx.x;
  float* row = logits + (size_t)r * TV;
  const int tid = threadIdx.x;
  float m = -1e30f, s = 0.f;
  for (int i = tid * 4; i < TV; i += 1024) {
    f32x4 v = *(const f32x4*)(row + i);
#pragma unroll
    for (int j = 0; j < 4; ++j) {
      float xv = v[j];
      if (xv > m) { s = s * __expf(m - xv) + 1.f; m = xv; }
      else s += __expf(xv - m);
    }
  }
#pragma unroll
  for (int o = 32; o > 0; o >>= 1) {
    float mo = __shfl_down(m, o);
    float so = __shfl_down(s, o);
    float M = fmaxf(m, mo);
    s = s * __expf(m - M) + so * __expf(mo - M);
    m = M;
  }
  __shared__ float pm[4], psv[4];
  __shared__ float blse;
  if ((tid & 63) == 0) { pm[tid >> 6] = m; psv[tid >> 6] = s; }
  __syncthreads();
  if (tid == 0) {
    float M = fmaxf(fmaxf(pm[0], pm[1]), fmaxf(pm[2], pm[3]));
    float S = psv[0] * __expf(pm[0] - M) + psv[1] * __expf(pm[1] - M) +
              psv[2] * __expf(pm[2] - M) + psv[3] * __expf(pm[3] - M);
    blse = M + logf(S);
  }
  __syncthreads();
  const float lse = blse;
  for (int i = tid * 4; i < TV; i += 1024) {
    f32x4 v = *(const f32x4*)(row + i);
    v[0] -= lse; v[1] -= lse; v[2] -= lse; v[3] -= lse;
    *(f32x4*)(row + i) = v;
  }
}

// ---------------- final: LSE from reg-buffered bf16 row; write f32 ---------
__global__ __launch_bounds__(1024) void lse_final_k(
    float* __restrict__ out, const unsigned short* __restrict__ lb) {
  const int r = blockIdx.x;
  const int tid = threadIdx.x;
  const unsigned short* row = lb + (size_t)r * 64000 + 32000;
  u16x4 buf[8];
#pragma unroll
  for (int i = 0; i < 8; ++i) {
    const int e = tid * 4 + i * 4096;
    if (e < TV) buf[i] = *(const u16x4*)(row + e);
  }
  float m = -1e30f;
#pragma unroll
  for (int i = 0; i < 8; ++i) {
    const int e = tid * 4 + i * 4096;
    if (e < TV) {
#pragma unroll
      for (int j = 0; j < 4; ++j) m = fmaxf(m, b2f(buf[i][j]));
    }
  }
  float s = 0.f;
#pragma unroll
  for (int i = 0; i < 8; ++i) {
    const int e = tid * 4 + i * 4096;
    if (e < TV) {
#pragma unroll
      for (int j = 0; j < 4; ++j) s += __expf(b2f(buf[i][j]) - m);
    }
  }
#pragma unroll
  for (int o = 32; o > 0; o >>= 1) {
    float mo = __shfl_xor(m, o);
    float so = __shfl_xor(s, o);
    float M = fmaxf(m, mo);
    s = s * __expf(m - M) + so * __expf(mo - M);
    m = M;
  }
  __shared__ float pm[16], psv[16];
  __shared__ float blse;
  if ((tid & 63) == 0) { pm[tid >> 6] = m; psv[tid >> 6] = s; }
  __syncthreads();
  if (tid == 0) {
    float M = pm[0];
#pragma unroll
    for (int w = 1; w < 16; ++w) M = fmaxf(M, pm[w]);
    float S = 0.f;
#pragma unroll
    for (int w = 0; w < 16; ++w) S += psv[w] * __expf(pm[w] - M);
    blse = M + logf(S);
  }
  __syncthreads();
  const float lse = blse;
  float* orow = out + (size_t)r * TV;
#pragma unroll
  for (int i = 0; i < 8; ++i) {
    const int e = tid * 4 + i * 4096;
    if (e < TV) {
      f32x4 v;
#pragma unroll
      for (int j = 0; j < 4; ++j) v[j] = b2f(buf[i][j]) - lse;
      *(f32x4*)(orow + e) = v;
    }
  }
}

// ---------------- weight transpose+convert: [K,N] f32 -> [N,K] bf16 --------
struct TEnt { const float* s; unsigned short* d; int K; int N; int t0; };
struct TTab { TEnt e[13]; };

__global__ __launch_bounds__(256) void transpose_all_k(TTab tab) {
  const int bid = blockIdx.x;
  int mi = 0;
#pragma unroll
  for (int i = 1; i < 13; ++i)
    if (bid >= tab.e[i].t0) mi = i;
  const TEnt E = tab.e[mi];
  const int lt = bid - E.t0;
  const int ntn = E.N >> 6;
  const int kt = lt / ntn, nt = lt - kt * ntn;
  const int k0 = kt << 6, n0 = nt << 6;
  __shared__ unsigned short t[64][68];
  const int tid = threadIdx.x;
  const int cr = tid >> 4, cc = (tid & 15) << 2;
#pragma unroll
  for (int it = 0; it < 4; ++it) {
    const int kl = it * 16 + cr;
    f32x4 v = *(const f32x4*)(E.s + (size_t)(k0 + kl) * E.N + n0 + cc);
    u16x4 o;
#pragma unroll
    for (int j = 0; j < 4; ++j) o[j] = f2b(v[j]);
    *(u16x4*)&t[kl][cc] = o;
  }
  __syncthreads();
  const int nl = tid & 63, kc = (tid >> 6) << 4;
  u16x8 r0, r1;
#pragma unroll
  for (int j = 0; j < 8; ++j) { r0[j] = t[kc + j][nl]; r1[j] = t[kc + 8 + j][nl]; }
  unsigned short* dp = E.d + (size_t)(n0 + nl) * E.K + k0 + kc;
  *(u16x8*)dp = r0;
  *(u16x8*)(dp + 8) = r1;
}

// ---------------- V slice transpose: qkv[:,2048+d] -> vt[b][d][s] ----------
__global__ __launch_bounds__(256) void vtrans_k(const unsigned short* __restrict__ qkv,
                                                unsigned short* __restrict__ vt) {
  const int d0 = blockIdx.x << 6, s0 = blockIdx.y << 6, b = blockIdx.z;
  __shared__ unsigned short t[64][68];
  const int tid = threadIdx.x;
  const int cr = tid >> 4, cc = (tid & 15) << 2;
#pragma unroll
  for (int it = 0; it < 4; ++it) {
    const int sl = it * 16 + cr;
    u16x4 v = *(const u16x4*)(qkv + (size_t)(b * TS + s0 + sl) * 3072 + 2048 + d0 + cc);
    *(u16x4*)&t[sl][cc] = v;
  }
  __syncthreads();
  const int dl = tid & 63, sc = (tid >> 6) << 4;
  u16x8 r0, r1;
#pragma unroll
  for (int j = 0; j < 8; ++j) { r0[j] = t[sc + j][dl]; r1[j] = t[sc + 8 + j][dl]; }
  unsigned short* dp = vt + (size_t)b * TD * TS + (size_t)(d0 + dl) * TS + s0 + sc;
  *(u16x8*)dp = r0;
  *(u16x8*)(dp + 8) = r1;
}

// ---------------- GEMM: A,B bf16 [*,K]; global_load_lds; opt. XCD swizzle --
// DBUF: 2-phase double-buffer — stage(t+1) issued before compute(t), one
// barrier per K-step (loads drain at the compiler's pre-barrier waitcnt).
template <int BM_, int BN, typename OT, bool HB, bool HS, bool HR, bool CSKIP,
          bool CAUSA, bool GSWAP, bool XSWZ, bool DBUF>
__global__ __launch_bounds__(256) void gemm2_k(
    const unsigned short* __restrict__ A, int lda, long long sAo, long long sAi, int iA,
    const unsigned short* __restrict__ B, int ldb, long long sBo, long long sBi, int iB,
    OT* __restrict__ C, int ldc, long long sCo, long long sCi, int iC,
    const float* __restrict__ bias, const float* __restrict__ res, int K) {
  constexpr int WN = BN / 2;
  constexpr int FN = WN / 16;
  constexpr int FM = BM_ / 32;
  constexpr int NB = DBUF ? 2 : 1;
  int bx = blockIdx.x, by = blockIdx.y;
  if constexpr (XSWZ) {
    const int nwg = gridDim.x * gridDim.y;
    const int bid = by * gridDim.x + bx;
    const int q = nwg >> 3, rr = nwg & 7;
    const int xcd = bid & 7, idx = bid >> 3;
    const int nid = (xcd < rr ? xcd * (q + 1) : rr * (q + 1) + (xcd - rr) * q) + idx;
    bx = nid % gridDim.x;
    by = nid / gridDim.x;
  }
  const int m0 = (GSWAP ? bx : by) * BM_;
  const int n0 = (GSWAP ? by : bx) * BN;
  if (CSKIP && n0 > m0 + BM_ - 1) return;
  const int bz = blockIdx.z;
  A += (long long)(bz / iA) * sAo + (long long)(bz % iA) * sAi;
  B += (long long)(bz / iB) * sBo + (long long)(bz % iB) * sBi;
  C += (long long)(bz / iC) * sCo + (long long)(bz % iC) * sCi;

  __shared__ __attribute__((aligned(16))) unsigned short As[NB][BM_ * 64];
  __shared__ __attribute__((aligned(16))) unsigned short Bs[NB][BN * 64];

  const int tid = threadIdx.x, lane = tid & 63, wid = tid >> 6;
  const int wm = wid >> 1, wn = wid & 1;
  const int lm = lane & 15, hi = lane >> 4;

  const int srow = lane >> 3, schk = lane & 7;
  const int sxor = (srow & 7) << 4;
  const unsigned char* AgB =
      (const unsigned char*)(A + (size_t)(m0 + wid * (BM_ / 4) + srow) * lda) +
      ((schk * 16) ^ sxor);
  const unsigned char* BgB =
      (const unsigned char*)(B + (size_t)(n0 + wid * (BN / 4) + srow) * ldb) +
      ((schk * 16) ^ sxor);
  const size_t ldab = (size_t)lda * 2, ldbb = (size_t)ldb * 2;

  auto stage = [&](int kb, int bi) {
#pragma unroll
    for (int i = 0; i < BM_ / 32; ++i)
      glds16(AgB + kb + (size_t)i * 8 * ldab,
             (unsigned char*)As[bi] + wid * (BM_ / 4) * 128 + i * 1024);
#pragma unroll
    for (int i = 0; i < BN / 32; ++i)
      glds16(BgB + kb + (size_t)i * 8 * ldbb,
             (unsigned char*)Bs[bi] + wid * (BN / 4) * 128 + i * 1024);
  };

  f32x4 acc[FM][FN] = {};
  const int kend = CAUSA ? ((K < m0 + BM_) ? K : m0 + BM_) : K;
  const int axor = (lm & 7) << 4;

  int cur = 0;
  if constexpr (DBUF) {
    stage(0, 0);
    __syncthreads();
  }
  for (int k0 = 0; k0 < kend; k0 += 64) {
    if constexpr (DBUF) {
      if (k0 + 64 < kend) stage((k0 + 64) * 2, cur ^ 1);
    } else {
      stage(k0 * 2, 0);
      __syncthreads();
    }
    const unsigned char* AsP = (const unsigned char*)As[DBUF ? cur : 0];
    const unsigned char* BsP = (const unsigned char*)Bs[DBUF ? cur : 0];
#pragma unroll
    for (int kk = 0; kk < 2; ++kk) {
      const int kb = (kk * 64 + hi * 16) ^ axor;
      bf16x8 af[FM], bfr[FN];
#pragma unroll
      for (int i = 0; i < FM; ++i)
        af[i] = __builtin_bit_cast(
            bf16x8, *(const u16x8*)(AsP + (wm * (BM_ / 2) + i * 16 + lm) * 128 + kb));
#pragma unroll
      for (int j = 0; j < FN; ++j)
        bfr[j] = __builtin_bit_cast(
            bf16x8, *(const u16x8*)(BsP + (wn * WN + j * 16 + lm) * 128 + kb));
#pragma unroll
      for (int i = 0; i < FM; ++i)
#pragma unroll
        for (int j = 0; j < FN; ++j)
          acc[i][j] = __builtin_amdgcn_mfma_f32_16x16x32_bf16(af[i], bfr[j],
                                                              acc[i][j], 0, 0, 0);
    }
    __syncthreads();
    cur ^= 1;
  }

#pragma unroll
  for (int i = 0; i < FM; ++i) {
    const int rbase = m0 + wm * (BM_ / 2) + i * 16 + (hi << 2);
#pragma unroll
    for (int j = 0; j < FN; ++j) {
      const int c = n0 + wn * WN + j * 16 + lm;
      const float bval = HB ? bias[c] : 0.f;
#pragma unroll
      for (int e = 0; e < 4; ++e) {
        float v = acc[i][j][e];
        if (HB) v += bval;
        if (HS) v = v / (1.f + __expf(-v));
        const long long off = (long long)(rbase + e) * ldc + c;
        if (HR) v += res[off];
        if constexpr (std::is_same_v<OT, float>) C[off] = v;
        else C[off] = f2b(v);
      }
    }
  }
}

// ---------------- old GEMM (round-1, fallback path) ----------------
template <int BN, typename BT, bool BNK, typename OT, bool HB, bool HS, bool HR,
          bool CSKIP, bool CAUSA>
__global__ __launch_bounds__(256) void gemm_k(
    const unsigned short* __restrict__ A, int lda, long long sAo, long long sAi, int iA,
    const BT* __restrict__ Bg, int ldb, long long sBo, long long sBi, int iB,
    OT* __restrict__ Cg, int ldc, long long sCo, long long sCi, int iC,
    const float* __restrict__ bias, const float* __restrict__ res, int K) {
  constexpr int WN = BN / 2;
  constexpr int FN = WN / 16;
  constexpr int FM = 4;
  const int m0 = blockIdx.y * BM;
  const int n0 = blockIdx.x * BN;
  if (CSKIP && n0 > m0 + BM - 1) return;
  const int bz = blockIdx.z;
  A  += (long long)(bz / iA) * sAo + (long long)(bz % iA) * sAi;
  Bg += (long long)(bz / iB) * sBo + (long long)(bz % iB) * sBi;
  Cg += (long long)(bz / iC) * sCo + (long long)(bz % iC) * sCi;

  __shared__ __attribute__((aligned(16))) unsigned short As[BM * BKP];
  __shared__ __attribute__((aligned(16))) unsigned short Bs[BN * BKP];

  const int tid = threadIdx.x;
  const int lane = tid & 63;
  const int wid = tid >> 6;
  const int wm = wid >> 1, wn = wid & 1;
  const int lm = lane & 15;
  const int lk = (lane >> 4) << 3;

  f32x4 acc[FM][FN] = {};
  const int kend = CAUSA ? ((K < m0 + BM) ? K : m0 + BM) : K;

  for (int k0 = 0; k0 < kend; k0 += BK) {
#pragma unroll
    for (int it = 0; it < (BM * BK / 8) / 256; ++it) {
      int idx = it * 256 + tid;
      int rowa = idx >> 3;
      int kc = (idx & 7) << 3;
      u16x8 av = *(const u16x8*)(A + (size_t)(m0 + rowa) * lda + (k0 + kc));
      *(u16x8*)&As[rowa * BKP + kc] = av;
    }
    if constexpr (BNK) {
#pragma unroll
      for (int it = 0; it < (BN * BK / 8) / 256; ++it) {
        int idx = it * 256 + tid;
        int rowb = idx >> 3;
        int kc = (idx & 7) << 3;
        u16x8 bv = *(const u16x8*)((const unsigned short*)Bg +
                                   (size_t)(n0 + rowb) * ldb + (k0 + kc));
        *(u16x8*)&Bs[rowb * BKP + (kc ^ (((rowb >> 3) & 7) << 3))] = bv;
      }
    } else {
      constexpr int NCH = BN / 8;
#pragma unroll
      for (int it = 0; it < (BK * NCH) / 256; ++it) {
        int idx = it * 256 + tid;
        int nc = (idx & (NCH - 1)) << 3;
        int kr = idx / NCH;
        unsigned short ub[8];
        if constexpr (std::is_same_v<BT, float>) {
          const float* bp = Bg + (size_t)(k0 + kr) * ldb + (n0 + nc);
          f32x4 b0 = *(const f32x4*)bp;
          f32x4 b1 = *(const f32x4*)(bp + 4);
#pragma unroll
          for (int j = 0; j < 4; ++j) { ub[j] = f2b(b0[j]); ub[4 + j] = f2b(b1[j]); }
        } else {
          const unsigned short* bp =
              (const unsigned short*)Bg + (size_t)(k0 + kr) * ldb + (n0 + nc);
          u16x8 raw = *(const u16x8*)bp;
#pragma unroll
          for (int j = 0; j < 8; ++j) ub[j] = raw[j];
        }
        const int sw = ((nc >> 3) & 7) << 3;
#pragma unroll
        for (int j = 0; j < 8; ++j) Bs[(nc + j) * BKP + (kr ^ sw)] = ub[j];
      }
    }
    __syncthreads();
#pragma unroll
    for (int kk = 0; kk < 2; ++kk) {
      bf16x8 af[FM];
      bf16x8 bfr[FN];
#pragma unroll
      for (int i = 0; i < FM; ++i)
        af[i] = __builtin_bit_cast(
            bf16x8, *(const u16x8*)&As[(wm * 64 + i * 16 + lm) * BKP + (kk * 32 + lk)]);
#pragma unroll
      for (int j = 0; j < FN; ++j) {
        const int nr = wn * WN + j * 16 + lm;
        bfr[j] = __builtin_bit_cast(
            bf16x8,
            *(const u16x8*)&Bs[nr * BKP + ((kk * 32 + lk) ^ (((nr >> 3) & 7) << 3))]);
      }
#pragma unroll
      for (int i = 0; i < FM; ++i)
#pragma unroll
        for (int j = 0; j < FN; ++j)
          acc[i][j] = __builtin_amdgcn_mfma_f32_16x16x32_bf16(af[i], bfr[j],
                                                              acc[i][j], 0, 0, 0);
    }
    __syncthreads();
  }

#pragma unroll
  for (int i = 0; i < FM; ++i) {
    const int rbase = m0 + wm * 64 + i * 16 + ((lane >> 4) << 2);
#pragma unroll
    for (int j = 0; j < FN; ++j) {
      const int c = n0 + wn * WN + j * 16 + lm;
      const float bval = HB ? bias[c] : 0.f;
#pragma unroll
      for (int e = 0; e < 4; ++e) {
        float v = acc[i][j][e];
        if (HB) v += bval;
        if (HS) v = v / (1.f + __expf(-v));
        const long long off = (long long)(rbase + e) * ldc + c;
        if (HR) v += res[off];
        if constexpr (std::is_same_v<OT, float>) Cg[off] = v;
        else Cg[off] = f2b(v);
      }
    }
  }
}

// ---------------------------------------------------------------------------
extern "C" void kernel_launch(void* const* d_in, const int* in_sizes, int n_in,
                              void* d_out, int out_size, void* d_ws, size_t ws_size,
                              hipStream_t stream) {
  const int*   tok = (const int*)d_in[0];
  const float* emb = (const float*)d_in[2];
  const float* Wq  = (const float*)d_in[3];
  const float* Wk  = (const float*)d_in[4];
  const float* Wv  = (const float*)d_in[5];
  const float* Wo  = (const float*)d_in[6];
  const float* al1 = (const float*)d_in[7];
  const float* al3 = (const float*)d_in[8];
  const float* W1  = (const float*)d_in[9];
  const float* b1  = (const float*)d_in[10];
  const float* W2  = (const float*)d_in[11];
  const float* b2  = (const float*)d_in[12];
  const float* alf = (const float*)d_in[13];
  const float* Wp  = (const float*)d_in[14];
  const float* bp  = (const float*)d_in[15];

  char* ws = (char*)d_ws;
  dim3 blk(256);

  const size_t NEED = 166199296ULL;
  if (ws_size >= NEED) {
    // ---------------- new path ----------------
    float* x           = (float*)(ws);                        // 8 MB
    unsigned short* nb = (unsigned short*)(ws + 8388608);     // 4 MB
    unsigned short* qkv= (unsigned short*)(ws + 12582912);    // 12 MB [2048,3072]
    unsigned short* vt = (unsigned short*)(ws + 25165824);    // 4 MB  [B][D][S]
    unsigned short* ob = (unsigned short*)(ws + 29360128);    // 4 MB
    unsigned short* f1b= (unsigned short*)(ws + 33554432);    // 16 MB [2048,4096]
    unsigned short* wqkvT = (unsigned short*)(ws + 50331648); // 12 MB
    unsigned short* woT   = (unsigned short*)(ws + 62914560); // 4 MB
    unsigned short* w1T   = (unsigned short*)(ws + 67108864); // 16 MB
    unsigned short* w2T   = (unsigned short*)(ws + 83886080); // 16 MB
    unsigned short* wpT   = (unsigned short*)(ws + 100663296);// 62.5 MB
    // bf16 logits: second half of each f32 row slot in d_out
    unsigned short* lgb = (unsigned short*)d_out + 32000;     // ldc=64000

    TTab tab;
    const int M1 = 1048576;
    tab.e[0]  = {Wq,           wqkvT,               1024, 1024, 0};
    tab.e[1]  = {Wk,           wqkvT + M1,          1024, 1024, 256};
    tab.e[2]  = {Wv,           wqkvT + 2 * M1,      1024, 1024, 512};
    tab.e[3]  = {Wq + M1,      wqkvT + 3 * M1,      1024, 1024, 768};
    tab.e[4]  = {Wk + M1,      wqkvT + 4 * M1,      1024, 1024, 1024};
    tab.e[5]  = {Wv + M1,      wqkvT + 5 * M1,      1024, 1024, 1280};
    tab.e[6]  = {Wo,           woT,                 1024, 1024, 1536};
    tab.e[7]  = {Wo + M1,      woT + M1,            1024, 1024, 1792};
    tab.e[8]  = {W1,           w1T,                 1024, 4096, 2048};
    tab.e[9]  = {W1 + 4 * M1,  w1T + 4 * M1,        1024, 4096, 3072};
    tab.e[10] = {W2,           w2T,                 4096, 1024, 4096};
    tab.e[11] = {W2 + 4 * M1,  w2T + 4 * M1,        4096, 1024, 5120};
    tab.e[12] = {Wp,           wpT,                 1024, 32000, 6144};
    transpose_all_k<<<14144, blk, 0, stream>>>(tab);

    // fused embedding + posenc + layer-0 RMS
    embed_rms_k<<<TB * TS, blk, 0, stream>>>(tok, emb, al1, x, nb);

    for (int l = 0; l < TL; ++l) {
      if (l > 0) rms_k<<<TB * TS, blk, 0, stream>>>(x, al1 + (size_t)l * TD, nb);

      // fused QKV: [2048,1024] x [3072,1024]^T -> qkv [2048,3072] (BM=64)
      gemm2_k<64, 128, unsigned short, false, false, false, false, false, false, true, false>
          <<<dim3(24, 32, 1), blk, 0, stream>>>(
              nb, TD, 0, 0, 1, wqkvT + (size_t)l * 3 * M1, TD, 0, 0, 1,
              qkv, 3072, 0, 0, 1, nullptr, nullptr, TD);

      vtrans_k<<<dim3(16, 16, TB), blk, 0, stream>>>(qkv, vt);

      // fused flash attention: QK^T + online softmax + PV
      attn_k<<<dim3(8, TB * TH), dim3(512), 0, stream>>>(qkv, vt, ob);

      // x += O @ Wo  (64x64, 512 blk, 2-phase dbuf)
      gemm2_k<64, 64, float, false, false, true, false, false, false, true, true>
          <<<dim3(16, 32, 1), blk, 0, stream>>>(
              ob, TD, 0, 0, 1, woT + (size_t)l * M1, TD, 0, 0, 1,
              x, TD, 0, 0, 1, nullptr, x, TD);

      rms_k<<<TB * TS, blk, 0, stream>>>(x, al3 + (size_t)l * TD, nb);

      // f1 = silu(n @ W1 + b1)  (64x128, 1024 blk)
      gemm2_k<64, 128, unsigned short, true, true, false, false, false, false, true, false>
          <<<dim3(32, 32, 1), blk, 0, stream>>>(
              nb, TD, 0, 0, 1, w1T + (size_t)l * 4 * M1, TD, 0, 0, 1,
              f1b, TDFF, 0, 0, 1, b1 + (size_t)l * TDFF, nullptr, TD);

      // x += f1 @ W2 + b2  (64x64, 512 blk, 2-phase dbuf)
      gemm2_k<64, 64, float, true, false, true, false, false, false, true, true>
          <<<dim3(16, 32, 1), blk, 0, stream>>>(
              f1b, TDFF, 0, 0, 1, w2T + (size_t)l * 4 * M1, TDFF, 0, 0, 1,
              x, TD, 0, 0, 1, b2 + (size_t)l * TD, x, TDFF);
    }

    rms_k<<<TB * TS, blk, 0, stream>>>(x, alf, nb);

    // logits (bf16, colocated) = n @ Wp + bp (plain epilogue; LSE in finalizer)
    gemm2_k<128, 128, unsigned short, true, false, false, false, false, true, true, false>
        <<<dim3(16, 250, 1), blk, 0, stream>>>(
            nb, TD, 0, 0, 1, wpT, TD, 0, 0, 1, lgb, 64000, 0, 0, 1,
            bp, nullptr, TD);

    lse_final_k<<<TB * TS, dim3(1024), 0, stream>>>(
        (float*)d_out, (const unsigned short*)d_out);
    return;
  }

  // ---------------- fallback: round-1 path ----------------
  {
    float* x            = (float*)(ws);
    unsigned short* nb  = (unsigned short*)(ws + 8388608);
    unsigned short* qb  = (unsigned short*)(ws + 12582912);
    unsigned short* kb  = (unsigned short*)(ws + 16777216);
    unsigned short* vb  = (unsigned short*)(ws + 20971520);
    unsigned short* ob  = (unsigned short*)(ws + 25165824);
    unsigned short* f1b = (unsigned short*)(ws + 29360128);
    float* Pf = (float*)d_out;
    unsigned short* Pb = (unsigned short*)d_out + 67108864LL;

    embed_pe_k<<<TB * TS, blk, 0, stream>>>(tok, emb, x);
    for (int l = 0; l < TL; ++l) {
      const float* Wq_l = Wq + (size_t)l * TD * TD;
      const float* Wk_l = Wk + (size_t)l * TD * TD;
      const float* Wv_l = Wv + (size_t)l * TD * TD;
      const float* Wo_l = Wo + (size_t)l * TD * TD;
      const float* W1_l = W1 + (size_t)l * TD * TDFF;
      const float* W2_l = W2 + (size_t)l * TDFF * TD;

      rms_k<<<TB * TS, blk, 0, stream>>>(x, al1 + (size_t)l * TD, nb);
      gemm_k<128, float, false, unsigned short, false, false, false, false, false>
          <<<dim3(TD / 128, (TB * TS) / BM, 1), blk, 0, stream>>>(
              nb, TD, 0, 0, 1, Wq_l, TD, 0, 0, 1, qb, TD, 0, 0, 1, nullptr, nullptr, TD);
      gemm_k<128, float, false, unsigned short, false, false, false, false, false>
          <<<dim3(TD / 128, (TB * TS) / BM, 1), blk, 0, stream>>>(
              nb, TD, 0, 0, 1, Wk_l, TD, 0, 0, 1, kb, TD, 0, 0, 1, nullptr, nullptr, TD);
      gemm_k<128, float, false, unsigned short, false, false, false, false, false>
          <<<dim3(TD / 128, (TB * TS) / BM, 1), blk, 0, stream>>>(
              nb, TD, 0, 0, 1, Wv_l, TD, 0, 0, 1, vb, TD, 0, 0, 1, nullptr, nullptr, TD);
      gemm_k<128, unsigned short, true, float, false, false, false, true, false>
          <<<dim3(TS / 128, TS / 128, TB * TH), blk, 0, stream>>>(
              qb, TD, (long long)TS * TD, THD, TH,
              kb, TD, (long long)TS * TD, THD, TH,
              Pf, TS, (long long)TS * TS, 0, 1, nullptr, nullptr, THD);
      softmax_k<<<TB * TH * TS, blk, 0, stream>>>(Pf, Pb);
      gemm_k<64, unsigned short, false, unsigned short, false, false, false, false, true>
          <<<dim3(1, TS / 128, TB * TH), blk, 0, stream>>>(
              Pb, TS, (long long)TS * TS, 0, 1,
              vb, TD, (long long)TS * TD, THD, TH,
              ob, TD, (long long)TS * TD, THD, TH, nullptr, nullptr, TS);
      gemm_k<128, float, false, float, false, false, true, false, false>
          <<<dim3(TD / 128, (TB * TS) / BM, 1), blk, 0, stream>>>(
              ob, TD, 0, 0, 1, Wo_l, TD, 0, 0, 1, x, TD, 0, 0, 1, nullptr, x, TD);
      rms_k<<<TB * TS, blk, 0, stream>>>(x, al3 + (size_t)l * TD, nb);
      gemm_k<128, float, false, unsigned short, true, true, false, false, false>
          <<<dim3(TDFF / 128, (TB * TS) / BM, 1), blk, 0, stream>>>(
              nb, TD, 0, 0, 1, W1_l, TDFF, 0, 0, 1, f1b, TDFF, 0, 0, 1,
              b1 + (size_t)l * TDFF, nullptr, TD);
      gemm_k<128, float, false, float, true, false, true, false, false>
          <<<dim3(TD / 128, (TB * TS) / BM, 1), blk, 0, stream>>>(
              f1b, TDFF, 0, 0, 1, W2_l, TD, 0, 0, 1, x, TD, 0, 0, 1,
              b2 + (size_t)l * TD, x, TDFF);
    }
    rms_k<<<TB * TS, blk, 0, stream>>>(x, alf, nb);
    gemm_k<128, float, false, float, true, false, false, false, false>
        <<<dim3(TV / 128, (TB * TS) / BM, 1), blk, 0, stream>>>(
            nb, TD, 0, 0, 1, Wp, TV, 0, 0, 1, (float*)d_out, TV, 0, 0, 1,
            bp, nullptr, TD);
    logsoftmax_k<<<TB * TS, blk, 0, stream>>>((float*)d_out);
  }
}

// Round 9
// 633.284 us; speedup vs baseline: 1.1066x; 1.0308x over previous
//
#include <hip/hip_runtime.h>
#include <hip/hip_bf16.h>
#include <type_traits>

// ---------------------------------------------------------------------------
// Round 9: 8-phase 256x256 pipelined GEMM (counted vmcnt, raw s_barrier,
// setprio) for the final projection only. Rest identical to round 8.
// ---------------------------------------------------------------------------

typedef float  f32x4 __attribute__((ext_vector_type(4)));
typedef __bf16 bf16x8 __attribute__((ext_vector_type(8)));
typedef unsigned short u16x8 __attribute__((ext_vector_type(8)));
typedef unsigned short u16x4 __attribute__((ext_vector_type(4)));

#define DI __device__ __forceinline__
#define VMW(n) asm volatile("s_waitcnt vmcnt(" #n ")" ::: "memory")
#define BARX   asm volatile("s_barrier" ::: "memory")

constexpr int TB = 2, TS = 1024, TD = 1024, TH = 16, TV = 32000, TL = 2,
              TDFF = 4096, THD = 64;
constexpr int BM = 128, BK = 64, BKP = 72;

DI unsigned short f2b(float f) {
  __bf16 h = (__bf16)f;
  return __builtin_bit_cast(unsigned short, h);
}
DI float b2f(unsigned short u) {
  unsigned v = ((unsigned)u) << 16;
  return __builtin_bit_cast(float, v);
}

DI void glds16(const void* g, void* l) {
  __builtin_amdgcn_global_load_lds(
      (const __attribute__((address_space(1))) unsigned int*)g,
      (__attribute__((address_space(3))) unsigned int*)l, 16, 0, 0);
}

// ---------------- fused: embedding*sqrt(D) + posenc + layer-0 RMS ----------
__global__ __launch_bounds__(256) void embed_rms_k(
    const int* __restrict__ tok, const float* __restrict__ emb,
    const float* __restrict__ alpha, float* __restrict__ x,
    unsigned short* __restrict__ out) {
  const int bs = blockIdx.x;
  const int s  = bs & (TS - 1);
  const int t  = tok[bs];
  const int tid = threadIdx.x;
  const int d0 = tid << 2;
  f32x4 e = *(const f32x4*)(emb + (size_t)t * TD + d0);
  f32x4 r;
#pragma unroll
  for (int j = 0; j < 4; ++j) {
    int d = d0 + j;
    int i2 = d >> 1;
    float freq = __expf((float)(2 * i2) * (-9.210340371976184f / (float)TD));
    float arg = (float)s * freq;
    float pe = (d & 1) ? __cosf(arg) : __sinf(arg);
    r[j] = e[j] * 32.0f + pe;
  }
  *(f32x4*)(x + (size_t)bs * TD + d0) = r;
  float ss = r[0] * r[0] + r[1] * r[1] + r[2] * r[2] + r[3] * r[3];
#pragma unroll
  for (int o = 32; o > 0; o >>= 1) ss += __shfl_down(ss, o);
  __shared__ float ps[4];
  __shared__ float invs;
  if ((tid & 63) == 0) ps[tid >> 6] = ss;
  __syncthreads();
  if (tid == 0) {
    float tot = ps[0] + ps[1] + ps[2] + ps[3];
    invs = 1.0f / (sqrtf(tot * (1.0f / (float)TD)) + 1e-8f);
  }
  __syncthreads();
  const float inv = invs;
  f32x4 av = *(const f32x4*)(alpha + d0);
  u16x4 ov;
#pragma unroll
  for (int j = 0; j < 4; ++j) ov[j] = f2b(av[j] * r[j] * inv);
  *(u16x4*)(out + (size_t)bs * TD + d0) = ov;
}

// ---------------- embedding * sqrt(D) + sinusoidal posenc (fallback) -------
__global__ __launch_bounds__(256) void embed_pe_k(const int* __restrict__ tok,
                                                  const float* __restrict__ emb,
                                                  float* __restrict__ x) {
  const int bs = blockIdx.x;
  const int s  = bs & (TS - 1);
  const int t  = tok[bs];
  const int d0 = threadIdx.x << 2;
  f32x4 e = *(const f32x4*)(emb + (size_t)t * TD + d0);
  f32x4 r;
#pragma unroll
  for (int j = 0; j < 4; ++j) {
    int d = d0 + j;
    int i2 = d >> 1;
    float freq = __expf((float)(2 * i2) * (-9.210340371976184f / (float)TD));
    float arg = (float)s * freq;
    float pe = (d & 1) ? __cosf(arg) : __sinf(arg);
    r[j] = e[j] * 32.0f + pe;
  }
  *(f32x4*)(x + (size_t)bs * TD + d0) = r;
}

// ---------------- RMS norm -> bf16 ----------------
__global__ __launch_bounds__(256) void rms_k(const float* __restrict__ xin,
                                             const float* __restrict__ alpha,
                                             unsigned short* __restrict__ out) {
  const int row = blockIdx.x;
  const int tid = threadIdx.x;
  const int d0 = tid << 2;
  f32x4 xv = *(const f32x4*)(xin + (size_t)row * TD + d0);
  float ss = xv[0] * xv[0] + xv[1] * xv[1] + xv[2] * xv[2] + xv[3] * xv[3];
#pragma unroll
  for (int o = 32; o > 0; o >>= 1) ss += __shfl_down(ss, o);
  __shared__ float ps[4];
  __shared__ float invs;
  if ((tid & 63) == 0) ps[tid >> 6] = ss;
  __syncthreads();
  if (tid == 0) {
    float tot = ps[0] + ps[1] + ps[2] + ps[3];
    invs = 1.0f / (sqrtf(tot * (1.0f / (float)TD)) + 1e-8f);
  }
  __syncthreads();
  const float inv = invs;
  f32x4 av = *(const f32x4*)(alpha + d0);
  u16x4 ov;
#pragma unroll
  for (int j = 0; j < 4; ++j) ov[j] = f2b(av[j] * xv[j] * inv);
  *(u16x4*)(out + (size_t)row * TD + d0) = ov;
}

// ---------------- fused flash attention -----------------------------------
__global__ __launch_bounds__(512) void attn_k(
    const unsigned short* __restrict__ qkv, const unsigned short* __restrict__ vt,
    unsigned short* __restrict__ ob) {
  const int q0 = blockIdx.x << 7;
  const int bh = blockIdx.y;
  const int b = bh >> 4, h = bh & 15;
  const unsigned short* Qg = qkv + (size_t)(b * TS) * 3072 + h * 64;
  const unsigned short* Kg = Qg + 1024;
  const unsigned short* Vg = vt + (size_t)b * TD * TS + (size_t)(h * 64) * TS;

  __shared__ __attribute__((aligned(16))) unsigned short Qs[128 * 64];
  __shared__ __attribute__((aligned(16))) unsigned short Ks[128 * 64];
  __shared__ __attribute__((aligned(16))) unsigned short Vs[64 * 128];
  __shared__ __attribute__((aligned(16))) unsigned short Sb[128 * 128];
  __shared__ float mi[128], li[128], scl[128];

  const int tid = threadIdx.x, lane = tid & 63, wid = tid >> 6;
  const int lm = lane & 15, hi = lane >> 4;
  const int wm = wid >> 2, wn = wid & 3;

  if (tid < 128) { mi[tid] = -3.0e38f; li[tid] = 0.f; }

  {
    const int srow = lane >> 3, schk = lane & 7;
#pragma unroll
    for (int i = 0; i < 2; ++i) {
      const int row = wid * 16 + i * 8 + srow;
      const unsigned char* src =
          (const unsigned char*)(Qg + (size_t)(q0 + row) * 3072) +
          ((schk * 16) ^ ((srow & 7) << 4));
      glds16(src, (unsigned char*)Qs + (wid * 16 + i * 8) * 128);
    }
  }

  f32x4 acc_o[4] = {};
  const int nt = blockIdx.x + 1;

  for (int t = 0; t < nt; ++t) {
    const int kv0 = t << 7;
    {
      const int srow = lane >> 3, schk = lane & 7;
#pragma unroll
      for (int i = 0; i < 2; ++i) {
        const int row = wid * 16 + i * 8 + srow;
        const unsigned char* src =
            (const unsigned char*)(Kg + (size_t)(kv0 + row) * 3072) +
            ((schk * 16) ^ ((srow & 7) << 4));
        glds16(src, (unsigned char*)Ks + (wid * 16 + i * 8) * 128);
      }
      const int vrow4 = lane >> 4, vchk = lane & 15;
#pragma unroll
      for (int i = 0; i < 2; ++i) {
        const int row = wid * 8 + i * 4 + vrow4;
        const unsigned char* src =
            (const unsigned char*)(Vg + (size_t)row * TS + kv0) +
            ((vchk * 16) ^ ((row & 15) << 4));
        glds16(src, (unsigned char*)Vs + (wid * 8 + i * 4) * 256);
      }
    }
    asm volatile("s_waitcnt vmcnt(0)");
    __syncthreads();

    f32x4 acc_s[4][2] = {};
#pragma unroll
    for (int kk = 0; kk < 2; ++kk) {
      bf16x8 af[4], bf[2];
#pragma unroll
      for (int i = 0; i < 4; ++i) {
        const int row = wm * 64 + i * 16 + lm;
        af[i] = __builtin_bit_cast(
            bf16x8, *(const u16x8*)((const unsigned char*)Qs + row * 128 +
                                    (((kk * 4 + hi) ^ (row & 7)) << 4)));
      }
#pragma unroll
      for (int j = 0; j < 2; ++j) {
        const int row = wn * 32 + j * 16 + lm;
        bf[j] = __builtin_bit_cast(
            bf16x8, *(const u16x8*)((const unsigned char*)Ks + row * 128 +
                                    (((kk * 4 + hi) ^ (row & 7)) << 4)));
      }
#pragma unroll
      for (int i = 0; i < 4; ++i)
#pragma unroll
        for (int j = 0; j < 2; ++j)
          acc_s[i][j] = __builtin_amdgcn_mfma_f32_16x16x32_bf16(af[i], bf[j],
                                                                acc_s[i][j], 0, 0, 0);
    }
#pragma unroll
    for (int i = 0; i < 4; ++i)
#pragma unroll
      for (int j = 0; j < 2; ++j)
#pragma unroll
        for (int e = 0; e < 4; ++e) {
          const int row = wm * 64 + i * 16 + hi * 4 + e;
          const int col = wn * 32 + j * 16 + lm;
          float v = acc_s[i][j][e] * 0.125f;
          if (kv0 + col > q0 + row) v = -1e30f;
          const int chunk = (col >> 3) ^ (row & 15);
          *(unsigned short*)((unsigned char*)Sb + row * 256 + chunk * 16 +
                             ((col & 7) << 1)) = f2b(v);
        }
    __syncthreads();

    {
      const int r = tid >> 2, qt = tid & 3;
      float v[32];
      float rmax = -3.0e38f;
#pragma unroll
      for (int cc = 0; cc < 4; ++cc) {
        const int c = qt * 4 + cc;
        u16x8 pk = *(const u16x8*)((const unsigned char*)Sb + r * 256 +
                                   ((c ^ (r & 15)) << 4));
#pragma unroll
        for (int j = 0; j < 8; ++j) {
          v[cc * 8 + j] = b2f(pk[j]);
          rmax = fmaxf(rmax, v[cc * 8 + j]);
        }
      }
      rmax = fmaxf(rmax, __shfl_xor(rmax, 1));
      rmax = fmaxf(rmax, __shfl_xor(rmax, 2));
      const float mold = mi[r];
      const float mnew = fmaxf(mold, rmax);
      float lsum = 0.f;
#pragma unroll
      for (int cc = 0; cc < 4; ++cc) {
        const int c = qt * 4 + cc;
        u16x8 pk;
#pragma unroll
        for (int j = 0; j < 8; ++j) {
          float p = __expf(v[cc * 8 + j] - mnew);
          lsum += p;
          pk[j] = f2b(p);
        }
        *(u16x8*)((unsigned char*)Sb + r * 256 + ((c ^ (r & 15)) << 4)) = pk;
      }
      lsum += __shfl_xor(lsum, 1);
      lsum += __shfl_xor(lsum, 2);
      if (qt == 0) {
        const float sc = __expf(mold - mnew);
        scl[r] = sc;
        li[r] = li[r] * sc + lsum;
        mi[r] = mnew;
      }
    }
    __syncthreads();

    {
      float sc[4];
#pragma unroll
      for (int e = 0; e < 4; ++e) sc[e] = scl[wid * 16 + hi * 4 + e];
#pragma unroll
      for (int j = 0; j < 4; ++j)
#pragma unroll
        for (int e = 0; e < 4; ++e) acc_o[j][e] *= sc[e];
#pragma unroll
      for (int ks = 0; ks < 4; ++ks) {
        const int arow = wid * 16 + lm;
        bf16x8 pa = __builtin_bit_cast(
            bf16x8, *(const u16x8*)((const unsigned char*)Sb + arow * 256 +
                                    (((ks * 4 + hi) ^ (arow & 15)) << 4)));
#pragma unroll
        for (int j = 0; j < 4; ++j) {
          const int drow = j * 16 + lm;
          bf16x8 vb = __builtin_bit_cast(
              bf16x8, *(const u16x8*)((const unsigned char*)Vs + drow * 256 +
                                      (((ks * 4 + hi) ^ (drow & 15)) << 4)));
          acc_o[j] = __builtin_amdgcn_mfma_f32_16x16x32_bf16(pa, vb, acc_o[j], 0, 0, 0);
        }
      }
    }
    __syncthreads();
  }

  float il[4];
#pragma unroll
  for (int e = 0; e < 4; ++e) il[e] = 1.0f / li[wid * 16 + hi * 4 + e];
#pragma unroll
  for (int j = 0; j < 4; ++j)
#pragma unroll
    for (int e = 0; e < 4; ++e) {
      const int row = q0 + wid * 16 + hi * 4 + e;
      const int col = h * 64 + j * 16 + lm;
      ob[(size_t)(b * TS + row) * TD + col] = f2b(acc_o[j][e] * il[e]);
    }
}

// ---------------- old f32->bf16 softmax (fallback path) ----------------
__global__ __launch_bounds__(256) void softmax_k(const float* __restrict__ Pf,
                                                 unsigned short* __restrict__ Pb) {
  const int r = blockIdx.x;
  const int valid = (r & (TS - 1)) + 1;
  const int tid = threadIdx.x;
  const float* row = Pf + (size_t)r * TS;
  unsigned short* orow = Pb + (size_t)r * TS;
  float vals[4];
  float lmax = -1e30f;
#pragma unroll
  for (int it = 0; it < 4; ++it) {
    int i = it * 256 + tid;
    float v = (i < valid) ? row[i] : -1e30f;
    vals[it] = v;
    lmax = fmaxf(lmax, v);
  }
#pragma unroll
  for (int o = 32; o > 0; o >>= 1) lmax = fmaxf(lmax, __shfl_down(lmax, o));
  __shared__ float ps[4];
  __shared__ float bcast;
  if ((tid & 63) == 0) ps[tid >> 6] = lmax;
  __syncthreads();
  if (tid == 0) bcast = fmaxf(fmaxf(ps[0], ps[1]), fmaxf(ps[2], ps[3]));
  __syncthreads();
  const float m = bcast;
  float lsum = 0.f;
#pragma unroll
  for (int it = 0; it < 4; ++it) {
    int i = it * 256 + tid;
    float e = (i < valid) ? __expf((vals[it] - m) * 0.125f) : 0.f;
    vals[it] = e;
    lsum += e;
  }
#pragma unroll
  for (int o = 32; o > 0; o >>= 1) lsum += __shfl_down(lsum, o);
  __syncthreads();
  if ((tid & 63) == 0) ps[tid >> 6] = lsum;
  __syncthreads();
  if (tid == 0) bcast = 1.0f / (ps[0] + ps[1] + ps[2] + ps[3]);
  __syncthreads();
  const float inv = bcast;
#pragma unroll
  for (int it = 0; it < 4; ++it) {
    int i = it * 256 + tid;
    orow[i] = f2b(vals[it] * inv);
  }
}

// ---------------- log_softmax over V, in place (fallback path) -------------
__global__ __launch_bounds__(256) void logsoftmax_k(float* __restrict__ logits) {
  const int r = blockIdx.x;
  float* row = logits + (size_t)r * TV;
  const int tid = threadIdx.x;
  float m = -1e30f, s = 0.f;
  for (int i = tid * 4; i < TV; i += 1024) {
    f32x4 v = *(const f32x4*)(row + i);
#pragma unroll
    for (int j = 0; j < 4; ++j) {
      float xv = v[j];
      if (xv > m) { s = s * __expf(m - xv) + 1.f; m = xv; }
      else s += __expf(xv - m);
    }
  }
#pragma unroll
  for (int o = 32; o > 0; o >>= 1) {
    float mo = __shfl_down(m, o);
    float so = __shfl_down(s, o);
    float M = fmaxf(m, mo);
    s = s * __expf(m - M) + so * __expf(mo - M);
    m = M;
  }
  __shared__ float pm[4], psv[4];
  __shared__ float blse;
  if ((tid & 63) == 0) { pm[tid >> 6] = m; psv[tid >> 6] = s; }
  __syncthreads();
  if (tid == 0) {
    float M = fmaxf(fmaxf(pm[0], pm[1]), fmaxf(pm[2], pm[3]));
    float S = psv[0] * __expf(pm[0] - M) + psv[1] * __expf(pm[1] - M) +
              psv[2] * __expf(pm[2] - M) + psv[3] * __expf(pm[3] - M);
    blse = M + logf(S);
  }
  __syncthreads();
  const float lse = blse;
  for (int i = tid * 4; i < TV; i += 1024) {
    f32x4 v = *(const f32x4*)(row + i);
    v[0] -= lse; v[1] -= lse; v[2] -= lse; v[3] -= lse;
    *(f32x4*)(row + i) = v;
  }
}

// ---------------- final: LSE from reg-buffered bf16 row; write f32 ---------
__global__ __launch_bounds__(1024) void lse_final_k(
    float* __restrict__ out, const unsigned short* __restrict__ lb) {
  const int r = blockIdx.x;
  const int tid = threadIdx.x;
  const unsigned short* row = lb + (size_t)r * 64000 + 32000;
  u16x4 buf[8];
#pragma unroll
  for (int i = 0; i < 8; ++i) {
    const int e = tid * 4 + i * 4096;
    if (e < TV) buf[i] = *(const u16x4*)(row + e);
  }
  float m = -1e30f;
#pragma unroll
  for (int i = 0; i < 8; ++i) {
    const int e = tid * 4 + i * 4096;
    if (e < TV) {
#pragma unroll
      for (int j = 0; j < 4; ++j) m = fmaxf(m, b2f(buf[i][j]));
    }
  }
  float s = 0.f;
#pragma unroll
  for (int i = 0; i < 8; ++i) {
    const int e = tid * 4 + i * 4096;
    if (e < TV) {
#pragma unroll
      for (int j = 0; j < 4; ++j) s += __expf(b2f(buf[i][j]) - m);
    }
  }
#pragma unroll
  for (int o = 32; o > 0; o >>= 1) {
    float mo = __shfl_xor(m, o);
    float so = __shfl_xor(s, o);
    float M = fmaxf(m, mo);
    s = s * __expf(m - M) + so * __expf(mo - M);
    m = M;
  }
  __shared__ float pm[16], psv[16];
  __shared__ float blse;
  if ((tid & 63) == 0) { pm[tid >> 6] = m; psv[tid >> 6] = s; }
  __syncthreads();
  if (tid == 0) {
    float M = pm[0];
#pragma unroll
    for (int w = 1; w < 16; ++w) M = fmaxf(M, pm[w]);
    float S = 0.f;
#pragma unroll
    for (int w = 0; w < 16; ++w) S += psv[w] * __expf(pm[w] - M);
    blse = M + logf(S);
  }
  __syncthreads();
  const float lse = blse;
  float* orow = out + (size_t)r * TV;
#pragma unroll
  for (int i = 0; i < 8; ++i) {
    const int e = tid * 4 + i * 4096;
    if (e < TV) {
      f32x4 v;
#pragma unroll
      for (int j = 0; j < 4; ++j) v[j] = b2f(buf[i][j]) - lse;
      *(f32x4*)(orow + e) = v;
    }
  }
}

// ---------------- weight transpose+convert: [K,N] f32 -> [N,K] bf16 --------
struct TEnt { const float* s; unsigned short* d; int K; int N; int t0; };
struct TTab { TEnt e[13]; };

__global__ __launch_bounds__(256) void transpose_all_k(TTab tab) {
  const int bid = blockIdx.x;
  int mi = 0;
#pragma unroll
  for (int i = 1; i < 13; ++i)
    if (bid >= tab.e[i].t0) mi = i;
  const TEnt E = tab.e[mi];
  const int lt = bid - E.t0;
  const int ntn = E.N >> 6;
  const int kt = lt / ntn, nt = lt - kt * ntn;
  const int k0 = kt << 6, n0 = nt << 6;
  __shared__ unsigned short t[64][68];
  const int tid = threadIdx.x;
  const int cr = tid >> 4, cc = (tid & 15) << 2;
#pragma unroll
  for (int it = 0; it < 4; ++it) {
    const int kl = it * 16 + cr;
    f32x4 v = *(const f32x4*)(E.s + (size_t)(k0 + kl) * E.N + n0 + cc);
    u16x4 o;
#pragma unroll
    for (int j = 0; j < 4; ++j) o[j] = f2b(v[j]);
    *(u16x4*)&t[kl][cc] = o;
  }
  __syncthreads();
  const int nl = tid & 63, kc = (tid >> 6) << 4;
  u16x8 r0, r1;
#pragma unroll
  for (int j = 0; j < 8; ++j) { r0[j] = t[kc + j][nl]; r1[j] = t[kc + 8 + j][nl]; }
  unsigned short* dp = E.d + (size_t)(n0 + nl) * E.K + k0 + kc;
  *(u16x8*)dp = r0;
  *(u16x8*)(dp + 8) = r1;
}

// ---------------- V slice transpose: qkv[:,2048+d] -> vt[b][d][s] ----------
__global__ __launch_bounds__(256) void vtrans_k(const unsigned short* __restrict__ qkv,
                                                unsigned short* __restrict__ vt) {
  const int d0 = blockIdx.x << 6, s0 = blockIdx.y << 6, b = blockIdx.z;
  __shared__ unsigned short t[64][68];
  const int tid = threadIdx.x;
  const int cr = tid >> 4, cc = (tid & 15) << 2;
#pragma unroll
  for (int it = 0; it < 4; ++it) {
    const int sl = it * 16 + cr;
    u16x4 v = *(const u16x4*)(qkv + (size_t)(b * TS + s0 + sl) * 3072 + 2048 + d0 + cc);
    *(u16x4*)&t[sl][cc] = v;
  }
  __syncthreads();
  const int dl = tid & 63, sc = (tid >> 6) << 4;
  u16x8 r0, r1;
#pragma unroll
  for (int j = 0; j < 8; ++j) { r0[j] = t[sc + j][dl]; r1[j] = t[sc + 8 + j][dl]; }
  unsigned short* dp = vt + (size_t)b * TD * TS + (size_t)(d0 + dl) * TS + s0 + sc;
  *(u16x8*)dp = r0;
  *(u16x8*)(dp + 8) = r1;
}

// ---------------- 8-phase 256x256 pipelined GEMM (projection) --------------
// A:[M,K] bf16, B:[N,K] bf16, C:[M,N] bf16 (+bias). 512 thr = 8 waves (2Mx4N),
// per-wave out 128x64. LDS: 8 quarter-slots x 16KB (dynamic 128KB).
// Quarter order per K-tile: [B0,B1,A0,A1]; stage lead = 4 quarters; counted
// per-wave vmcnt at tile boundary (wm0: A0 -> vmcnt(4); wm1: A1 -> vmcnt(2)).
__global__ __launch_bounds__(512, 2) void gemm8p_k(
    const unsigned short* __restrict__ A, int lda,
    const unsigned short* __restrict__ B, int ldb,
    unsigned short* __restrict__ C, long long ldc,
    const float* __restrict__ bias, int K) {
  extern __shared__ __attribute__((aligned(16))) char smem[];
  const int NT = K >> 6;
  int bx = blockIdx.x, by = blockIdx.y;
  {
    const int nwg = gridDim.x * gridDim.y;
    const int bid = by * gridDim.x + bx;
    const int q = nwg >> 3, rr = nwg & 7;
    const int xcd = bid & 7, idx = bid >> 3;
    const int nid = (xcd < rr ? xcd * (q + 1) : rr * (q + 1) + (xcd - rr) * q) + idx;
    bx = nid % gridDim.x;
    by = nid / gridDim.x;
  }
  const int m0 = bx * 256, n0 = by * 256;
  const int tid = threadIdx.x, lane = tid & 63, wid = tid >> 6;
  const int wm = wid >> 2, wn = wid & 3;
  const int lm = lane & 15, hi = lane >> 4;
  const int srow = lane >> 3, schk = lane & 7;
  const int axor = (lm & 7) << 4;
  const int swz = (schk * 16) ^ ((srow & 7) << 4);
  const int rb = (wn & 1) * 64;

  const char* srcA = (const char*)(A + (size_t)(m0 + wid * 8 + srow) * lda) + swz;
  const char* srcB = (const char*)(B + (size_t)(n0 + wid * 8 + srow) * ldb) + swz;
  char* dstW = smem + wid * 8 * 128;

  auto stage_q = [&](int q) {
    const int kt_t = q >> 2, jj = q & 3;
    char* d = dstW + (q & 7) * 16384;
    if (jj < 2) {
      const char* s = srcB + ((size_t)(jj * 128) * ldb + (size_t)kt_t * 64) * 2;
      glds16(s, d);
      glds16(s + (size_t)64 * ldb * 2, d + 64 * 128);
    } else {
      const char* s = srcA + ((size_t)((jj - 2) * 128) * lda + (size_t)kt_t * 64) * 2;
      glds16(s, d);
      glds16(s + (size_t)64 * lda * 2, d + 64 * 128);
    }
  };

  // prologue: tile 0's quarters
  stage_q(0); stage_q(1); stage_q(2); stage_q(3);

  f32x4 acc[8][4] = {};

  for (int kt = 0; kt < NT; ++kt) {
    const char* ta = smem + ((kt & 1) * 4 + 2 + wm) * 16384;
    const char* tb = smem + ((kt & 1) * 4 + (wn >> 1)) * 16384;
    const bool more = (kt + 1 < NT);
    bf16x8 bfr[4], af[4];

    // ---- phase 0 (mh=0, kk=0): boundary wait ----
    if (more) stage_q(4 * kt + 4);
    if (more) { if (wm == 0) { VMW(4); } else { VMW(2); } }
    else      { if (wm == 0) { VMW(2); } else { VMW(0); } }
    BARX;
#pragma unroll
    for (int j = 0; j < 4; ++j)
      bfr[j] = __builtin_bit_cast(
          bf16x8, *(const u16x8*)(tb + (rb + j * 16 + lm) * 128 + ((hi * 16) ^ axor)));
#pragma unroll
    for (int i = 0; i < 4; ++i)
      af[i] = __builtin_bit_cast(
          bf16x8, *(const u16x8*)(ta + (i * 16 + lm) * 128 + ((hi * 16) ^ axor)));
    __builtin_amdgcn_s_setprio(1);
#pragma unroll
    for (int i = 0; i < 4; ++i)
#pragma unroll
      for (int j = 0; j < 4; ++j)
        acc[i][j] = __builtin_amdgcn_mfma_f32_16x16x32_bf16(af[i], bfr[j],
                                                            acc[i][j], 0, 0, 0);
    __builtin_amdgcn_s_setprio(0);
    BARX;

    // ---- phase 1 (mh=1, kk=0) ----
    if (more) stage_q(4 * kt + 5);
    BARX;
#pragma unroll
    for (int i = 0; i < 4; ++i)
      af[i] = __builtin_bit_cast(
          bf16x8, *(const u16x8*)(ta + (64 + i * 16 + lm) * 128 + ((hi * 16) ^ axor)));
    __builtin_amdgcn_s_setprio(1);
#pragma unroll
    for (int i = 0; i < 4; ++i)
#pragma unroll
      for (int j = 0; j < 4; ++j)
        acc[4 + i][j] = __builtin_amdgcn_mfma_f32_16x16x32_bf16(af[i], bfr[j],
                                                                acc[4 + i][j], 0, 0, 0);
    __builtin_amdgcn_s_setprio(0);
    BARX;

    // ---- phase 2 (mh=0, kk=1) ----
    if (more) stage_q(4 * kt + 6);
    BARX;
#pragma unroll
    for (int j = 0; j < 4; ++j)
      bfr[j] = __builtin_bit_cast(
          bf16x8,
          *(const u16x8*)(tb + (rb + j * 16 + lm) * 128 + ((64 + hi * 16) ^ axor)));
#pragma unroll
    for (int i = 0; i < 4; ++i)
      af[i] = __builtin_bit_cast(
          bf16x8, *(const u16x8*)(ta + (i * 16 + lm) * 128 + ((64 + hi * 16) ^ axor)));
    __builtin_amdgcn_s_setprio(1);
#pragma unroll
    for (int i = 0; i < 4; ++i)
#pragma unroll
      for (int j = 0; j < 4; ++j)
        acc[i][j] = __builtin_amdgcn_mfma_f32_16x16x32_bf16(af[i], bfr[j],
                                                            acc[i][j], 0, 0, 0);
    __builtin_amdgcn_s_setprio(0);
    BARX;

    // ---- phase 3 (mh=1, kk=1) ----
    if (more) stage_q(4 * kt + 7);
    BARX;
#pragma unroll
    for (int i = 0; i < 4; ++i)
      af[i] = __builtin_bit_cast(
          bf16x8,
          *(const u16x8*)(ta + (64 + i * 16 + lm) * 128 + ((64 + hi * 16) ^ axor)));
    __builtin_amdgcn_s_setprio(1);
#pragma unroll
    for (int i = 0; i < 4; ++i)
#pragma unroll
      for (int j = 0; j < 4; ++j)
        acc[4 + i][j] = __builtin_amdgcn_mfma_f32_16x16x32_bf16(af[i], bfr[j],
                                                                acc[4 + i][j], 0, 0, 0);
    __builtin_amdgcn_s_setprio(0);
    BARX;
  }

  // ---- epilogue ----
#pragma unroll
  for (int mi = 0; mi < 8; ++mi)
#pragma unroll
    for (int j = 0; j < 4; ++j) {
      const int col = n0 + wn * 64 + j * 16 + lm;
      const float bv = bias[col];
#pragma unroll
      for (int e = 0; e < 4; ++e) {
        const long long row = m0 + wm * 128 + mi * 16 + hi * 4 + e;
        C[row * ldc + col] = f2b(acc[mi][j][e] + bv);
      }
    }
}

// ---------------- GEMM: A,B bf16 [*,K]; global_load_lds; opt. XCD swizzle --
template <int BM_, int BN, typename OT, bool HB, bool HS, bool HR, bool CSKIP,
          bool CAUSA, bool GSWAP, bool XSWZ, bool DBUF>
__global__ __launch_bounds__(256) void gemm2_k(
    const unsigned short* __restrict__ A, int lda, long long sAo, long long sAi, int iA,
    const unsigned short* __restrict__ B, int ldb, long long sBo, long long sBi, int iB,
    OT* __restrict__ C, int ldc, long long sCo, long long sCi, int iC,
    const float* __restrict__ bias, const float* __restrict__ res, int K) {
  constexpr int WN = BN / 2;
  constexpr int FN = WN / 16;
  constexpr int FM = BM_ / 32;
  constexpr int NB = DBUF ? 2 : 1;
  int bx = blockIdx.x, by = blockIdx.y;
  if constexpr (XSWZ) {
    const int nwg = gridDim.x * gridDim.y;
    const int bid = by * gridDim.x + bx;
    const int q = nwg >> 3, rr = nwg & 7;
    const int xcd = bid & 7, idx = bid >> 3;
    const int nid = (xcd < rr ? xcd * (q + 1) : rr * (q + 1) + (xcd - rr) * q) + idx;
    bx = nid % gridDim.x;
    by = nid / gridDim.x;
  }
  const int m0 = (GSWAP ? bx : by) * BM_;
  const int n0 = (GSWAP ? by : bx) * BN;
  if (CSKIP && n0 > m0 + BM_ - 1) return;
  const int bz = blockIdx.z;
  A += (long long)(bz / iA) * sAo + (long long)(bz % iA) * sAi;
  B += (long long)(bz / iB) * sBo + (long long)(bz % iB) * sBi;
  C += (long long)(bz / iC) * sCo + (long long)(bz % iC) * sCi;

  __shared__ __attribute__((aligned(16))) unsigned short As[NB][BM_ * 64];
  __shared__ __attribute__((aligned(16))) unsigned short Bs[NB][BN * 64];

  const int tid = threadIdx.x, lane = tid & 63, wid = tid >> 6;
  const int wm = wid >> 1, wn = wid & 1;
  const int lm = lane & 15, hi = lane >> 4;

  const int srow = lane >> 3, schk = lane & 7;
  const int sxor = (srow & 7) << 4;
  const unsigned char* AgB =
      (const unsigned char*)(A + (size_t)(m0 + wid * (BM_ / 4) + srow) * lda) +
      ((schk * 16) ^ sxor);
  const unsigned char* BgB =
      (const unsigned char*)(B + (size_t)(n0 + wid * (BN / 4) + srow) * ldb) +
      ((schk * 16) ^ sxor);
  const size_t ldab = (size_t)lda * 2, ldbb = (size_t)ldb * 2;

  auto stage = [&](int kb, int bi) {
#pragma unroll
    for (int i = 0; i < BM_ / 32; ++i)
      glds16(AgB + kb + (size_t)i * 8 * ldab,
             (unsigned char*)As[bi] + wid * (BM_ / 4) * 128 + i * 1024);
#pragma unroll
    for (int i = 0; i < BN / 32; ++i)
      glds16(BgB + kb + (size_t)i * 8 * ldbb,
             (unsigned char*)Bs[bi] + wid * (BN / 4) * 128 + i * 1024);
  };

  f32x4 acc[FM][FN] = {};
  const int kend = CAUSA ? ((K < m0 + BM_) ? K : m0 + BM_) : K;
  const int axor = (lm & 7) << 4;

  int cur = 0;
  if constexpr (DBUF) {
    stage(0, 0);
    __syncthreads();
  }
  for (int k0 = 0; k0 < kend; k0 += 64) {
    if constexpr (DBUF) {
      if (k0 + 64 < kend) stage((k0 + 64) * 2, cur ^ 1);
    } else {
      stage(k0 * 2, 0);
      __syncthreads();
    }
    const unsigned char* AsP = (const unsigned char*)As[DBUF ? cur : 0];
    const unsigned char* BsP = (const unsigned char*)Bs[DBUF ? cur : 0];
#pragma unroll
    for (int kk = 0; kk < 2; ++kk) {
      const int kb = (kk * 64 + hi * 16) ^ axor;
      bf16x8 af[FM], bfr[FN];
#pragma unroll
      for (int i = 0; i < FM; ++i)
        af[i] = __builtin_bit_cast(
            bf16x8, *(const u16x8*)(AsP + (wm * (BM_ / 2) + i * 16 + lm) * 128 + kb));
#pragma unroll
      for (int j = 0; j < FN; ++j)
        bfr[j] = __builtin_bit_cast(
            bf16x8, *(const u16x8*)(BsP + (wn * WN + j * 16 + lm) * 128 + kb));
#pragma unroll
      for (int i = 0; i < FM; ++i)
#pragma unroll
        for (int j = 0; j < FN; ++j)
          acc[i][j] = __builtin_amdgcn_mfma_f32_16x16x32_bf16(af[i], bfr[j],
                                                              acc[i][j], 0, 0, 0);
    }
    __syncthreads();
    cur ^= 1;
  }

#pragma unroll
  for (int i = 0; i < FM; ++i) {
    const int rbase = m0 + wm * (BM_ / 2) + i * 16 + (hi << 2);
#pragma unroll
    for (int j = 0; j < FN; ++j) {
      const int c = n0 + wn * WN + j * 16 + lm;
      const float bval = HB ? bias[c] : 0.f;
#pragma unroll
      for (int e = 0; e < 4; ++e) {
        float v = acc[i][j][e];
        if (HB) v += bval;
        if (HS) v = v / (1.f + __expf(-v));
        const long long off = (long long)(rbase + e) * ldc + c;
        if (HR) v += res[off];
        if constexpr (std::is_same_v<OT, float>) C[off] = v;
        else C[off] = f2b(v);
      }
    }
  }
}

// ---------------- old GEMM (round-1, fallback path) ----------------
template <int BN, typename BT, bool BNK, typename OT, bool HB, bool HS, bool HR,
          bool CSKIP, bool CAUSA>
__global__ __launch_bounds__(256) void gemm_k(
    const unsigned short* __restrict__ A, int lda, long long sAo, long long sAi, int iA,
    const BT* __restrict__ Bg, int ldb, long long sBo, long long sBi, int iB,
    OT* __restrict__ Cg, int ldc, long long sCo, long long sCi, int iC,
    const float* __restrict__ bias, const float* __restrict__ res, int K) {
  constexpr int WN = BN / 2;
  constexpr int FN = WN / 16;
  constexpr int FM = 4;
  const int m0 = blockIdx.y * BM;
  const int n0 = blockIdx.x * BN;
  if (CSKIP && n0 > m0 + BM - 1) return;
  const int bz = blockIdx.z;
  A  += (long long)(bz / iA) * sAo + (long long)(bz % iA) * sAi;
  Bg += (long long)(bz / iB) * sBo + (long long)(bz % iB) * sBi;
  Cg += (long long)(bz / iC) * sCo + (long long)(bz % iC) * sCi;

  __shared__ __attribute__((aligned(16))) unsigned short As[BM * BKP];
  __shared__ __attribute__((aligned(16))) unsigned short Bs[BN * BKP];

  const int tid = threadIdx.x;
  const int lane = tid & 63;
  const int wid = tid >> 6;
  const int wm = wid >> 1, wn = wid & 1;
  const int lm = lane & 15;
  const int lk = (lane >> 4) << 3;

  f32x4 acc[FM][FN] = {};
  const int kend = CAUSA ? ((K < m0 + BM) ? K : m0 + BM) : K;

  for (int k0 = 0; k0 < kend; k0 += BK) {
#pragma unroll
    for (int it = 0; it < (BM * BK / 8) / 256; ++it) {
      int idx = it * 256 + tid;
      int rowa = idx >> 3;
      int kc = (idx & 7) << 3;
      u16x8 av = *(const u16x8*)(A + (size_t)(m0 + rowa) * lda + (k0 + kc));
      *(u16x8*)&As[rowa * BKP + kc] = av;
    }
    if constexpr (BNK) {
#pragma unroll
      for (int it = 0; it < (BN * BK / 8) / 256; ++it) {
        int idx = it * 256 + tid;
        int rowb = idx >> 3;
        int kc = (idx & 7) << 3;
        u16x8 bv = *(const u16x8*)((const unsigned short*)Bg +
                                   (size_t)(n0 + rowb) * ldb + (k0 + kc));
        *(u16x8*)&Bs[rowb * BKP + (kc ^ (((rowb >> 3) & 7) << 3))] = bv;
      }
    } else {
      constexpr int NCH = BN / 8;
#pragma unroll
      for (int it = 0; it < (BK * NCH) / 256; ++it) {
        int idx = it * 256 + tid;
        int nc = (idx & (NCH - 1)) << 3;
        int kr = idx / NCH;
        unsigned short ub[8];
        if constexpr (std::is_same_v<BT, float>) {
          const float* bp = Bg + (size_t)(k0 + kr) * ldb + (n0 + nc);
          f32x4 b0 = *(const f32x4*)bp;
          f32x4 b1 = *(const f32x4*)(bp + 4);
#pragma unroll
          for (int j = 0; j < 4; ++j) { ub[j] = f2b(b0[j]); ub[4 + j] = f2b(b1[j]); }
        } else {
          const unsigned short* bp =
              (const unsigned short*)Bg + (size_t)(k0 + kr) * ldb + (n0 + nc);
          u16x8 raw = *(const u16x8*)bp;
#pragma unroll
          for (int j = 0; j < 8; ++j) ub[j] = raw[j];
        }
        const int sw = ((nc >> 3) & 7) << 3;
#pragma unroll
        for (int j = 0; j < 8; ++j) Bs[(nc + j) * BKP + (kr ^ sw)] = ub[j];
      }
    }
    __syncthreads();
#pragma unroll
    for (int kk = 0; kk < 2; ++kk) {
      bf16x8 af[FM];
      bf16x8 bfr[FN];
#pragma unroll
      for (int i = 0; i < FM; ++i)
        af[i] = __builtin_bit_cast(
            bf16x8, *(const u16x8*)&As[(wm * 64 + i * 16 + lm) * BKP + (kk * 32 + lk)]);
#pragma unroll
      for (int j = 0; j < FN; ++j) {
        const int nr = wn * WN + j * 16 + lm;
        bfr[j] = __builtin_bit_cast(
            bf16x8,
            *(const u16x8*)&Bs[nr * BKP + ((kk * 32 + lk) ^ (((nr >> 3) & 7) << 3))]);
      }
#pragma unroll
      for (int i = 0; i < FM; ++i)
#pragma unroll
        for (int j = 0; j < FN; ++j)
          acc[i][j] = __builtin_amdgcn_mfma_f32_16x16x32_bf16(af[i], bfr[j],
                                                              acc[i][j], 0, 0, 0);
    }
    __syncthreads();
  }

#pragma unroll
  for (int i = 0; i < FM; ++i) {
    const int rbase = m0 + wm * 64 + i * 16 + ((lane >> 4) << 2);
#pragma unroll
    for (int j = 0; j < FN; ++j) {
      const int c = n0 + wn * WN + j * 16 + lm;
      const float bval = HB ? bias[c] : 0.f;
#pragma unroll
      for (int e = 0; e < 4; ++e) {
        float v = acc[i][j][e];
        if (HB) v += bval;
        if (HS) v = v / (1.f + __expf(-v));
        const long long off = (long long)(rbase + e) * ldc + c;
        if (HR) v += res[off];
        if constexpr (std::is_same_v<OT, float>) Cg[off] = v;
        else Cg[off] = f2b(v);
      }
    }
  }
}

// ---------------------------------------------------------------------------
extern "C" void kernel_launch(void* const* d_in, const int* in_sizes, int n_in,
                              void* d_out, int out_size, void* d_ws, size_t ws_size,
                              hipStream_t stream) {
  const int*   tok = (const int*)d_in[0];
  const float* emb = (const float*)d_in[2];
  const float* Wq  = (const float*)d_in[3];
  const float* Wk  = (const float*)d_in[4];
  const float* Wv  = (const float*)d_in[5];
  const float* Wo  = (const float*)d_in[6];
  const float* al1 = (const float*)d_in[7];
  const float* al3 = (const float*)d_in[8];
  const float* W1  = (const float*)d_in[9];
  const float* b1  = (const float*)d_in[10];
  const float* W2  = (const float*)d_in[11];
  const float* b2  = (const float*)d_in[12];
  const float* alf = (const float*)d_in[13];
  const float* Wp  = (const float*)d_in[14];
  const float* bp  = (const float*)d_in[15];

  char* ws = (char*)d_ws;
  dim3 blk(256);

  const size_t NEED = 166199296ULL;
  if (ws_size >= NEED) {
    // ---------------- new path ----------------
    float* x           = (float*)(ws);                        // 8 MB
    unsigned short* nb = (unsigned short*)(ws + 8388608);     // 4 MB
    unsigned short* qkv= (unsigned short*)(ws + 12582912);    // 12 MB [2048,3072]
    unsigned short* vt = (unsigned short*)(ws + 25165824);    // 4 MB  [B][D][S]
    unsigned short* ob = (unsigned short*)(ws + 29360128);    // 4 MB
    unsigned short* f1b= (unsigned short*)(ws + 33554432);    // 16 MB [2048,4096]
    unsigned short* wqkvT = (unsigned short*)(ws + 50331648); // 12 MB
    unsigned short* woT   = (unsigned short*)(ws + 62914560); // 4 MB
    unsigned short* w1T   = (unsigned short*)(ws + 67108864); // 16 MB
    unsigned short* w2T   = (unsigned short*)(ws + 83886080); // 16 MB
    unsigned short* wpT   = (unsigned short*)(ws + 100663296);// 62.5 MB
    // bf16 logits: second half of each f32 row slot in d_out
    unsigned short* lgb = (unsigned short*)d_out + 32000;     // ldc=64000

    hipFuncSetAttribute((const void*)gemm8p_k,
                        hipFuncAttributeMaxDynamicSharedMemorySize, 131072);

    TTab tab;
    const int M1 = 1048576;
    tab.e[0]  = {Wq,           wqkvT,               1024, 1024, 0};
    tab.e[1]  = {Wk,           wqkvT + M1,          1024, 1024, 256};
    tab.e[2]  = {Wv,           wqkvT + 2 * M1,      1024, 1024, 512};
    tab.e[3]  = {Wq + M1,      wqkvT + 3 * M1,      1024, 1024, 768};
    tab.e[4]  = {Wk + M1,      wqkvT + 4 * M1,      1024, 1024, 1024};
    tab.e[5]  = {Wv + M1,      wqkvT + 5 * M1,      1024, 1024, 1280};
    tab.e[6]  = {Wo,           woT,                 1024, 1024, 1536};
    tab.e[7]  = {Wo + M1,      woT + M1,            1024, 1024, 1792};
    tab.e[8]  = {W1,           w1T,                 1024, 4096, 2048};
    tab.e[9]  = {W1 + 4 * M1,  w1T + 4 * M1,        1024, 4096, 3072};
    tab.e[10] = {W2,           w2T,                 4096, 1024, 4096};
    tab.e[11] = {W2 + 4 * M1,  w2T + 4 * M1,        4096, 1024, 5120};
    tab.e[12] = {Wp,           wpT,                 1024, 32000, 6144};
    transpose_all_k<<<14144, blk, 0, stream>>>(tab);

    // fused embedding + posenc + layer-0 RMS
    embed_rms_k<<<TB * TS, blk, 0, stream>>>(tok, emb, al1, x, nb);

    for (int l = 0; l < TL; ++l) {
      if (l > 0) rms_k<<<TB * TS, blk, 0, stream>>>(x, al1 + (size_t)l * TD, nb);

      // fused QKV: [2048,1024] x [3072,1024]^T -> qkv [2048,3072] (BM=64)
      gemm2_k<64, 128, unsigned short, false, false, false, false, false, false, true, false>
          <<<dim3(24, 32, 1), blk, 0, stream>>>(
              nb, TD, 0, 0, 1, wqkvT + (size_t)l * 3 * M1, TD, 0, 0, 1,
              qkv, 3072, 0, 0, 1, nullptr, nullptr, TD);

      vtrans_k<<<dim3(16, 16, TB), blk, 0, stream>>>(qkv, vt);

      // fused flash attention: QK^T + online softmax + PV
      attn_k<<<dim3(8, TB * TH), dim3(512), 0, stream>>>(qkv, vt, ob);

      // x += O @ Wo  (64x64, 512 blk, 2-phase dbuf)
      gemm2_k<64, 64, float, false, false, true, false, false, false, true, true>
          <<<dim3(16, 32, 1), blk, 0, stream>>>(
              ob, TD, 0, 0, 1, woT + (size_t)l * M1, TD, 0, 0, 1,
              x, TD, 0, 0, 1, nullptr, x, TD);

      rms_k<<<TB * TS, blk, 0, stream>>>(x, al3 + (size_t)l * TD, nb);

      // f1 = silu(n @ W1 + b1)  (64x128, 1024 blk)
      gemm2_k<64, 128, unsigned short, true, true, false, false, false, false, true, false>
          <<<dim3(32, 32, 1), blk, 0, stream>>>(
              nb, TD, 0, 0, 1, w1T + (size_t)l * 4 * M1, TD, 0, 0, 1,
              f1b, TDFF, 0, 0, 1, b1 + (size_t)l * TDFF, nullptr, TD);

      // x += f1 @ W2 + b2  (64x64, 512 blk, 2-phase dbuf)
      gemm2_k<64, 64, float, true, false, true, false, false, false, true, true>
          <<<dim3(16, 32, 1), blk, 0, stream>>>(
              f1b, TDFF, 0, 0, 1, w2T + (size_t)l * 4 * M1, TDFF, 0, 0, 1,
              x, TD, 0, 0, 1, b2 + (size_t)l * TD, x, TDFF);
    }

    rms_k<<<TB * TS, blk, 0, stream>>>(x, alf, nb);

    // logits (bf16, colocated) = n @ Wp + bp : 8-phase 256x256 pipeline
    gemm8p_k<<<dim3(8, 125, 1), dim3(512), 131072, stream>>>(
        nb, TD, wpT, TD, lgb, 64000, bp, TD);

    lse_final_k<<<TB * TS, dim3(1024), 0, stream>>>(
        (float*)d_out, (const unsigned short*)d_out);
    return;
  }

  // ---------------- fallback: round-1 path ----------------
  {
    float* x            = (float*)(ws);
    unsigned short* nb  = (unsigned short*)(ws + 8388608);
    unsigned short* qb  = (unsigned short*)(ws + 12582912);
    unsigned short* kb  = (unsigned short*)(ws + 16777216);
    unsigned short* vb  = (unsigned short*)(ws + 20971520);
    unsigned short* ob  = (unsigned short*)(ws + 25165824);
    unsigned short* f1b = (unsigned short*)(ws + 29360128);
    float* Pf = (float*)d_out;
    unsigned short* Pb = (unsigned short*)d_out + 67108864LL;

    embed_pe_k<<<TB * TS, blk, 0, stream>>>(tok, emb, x);
    for (int l = 0; l < TL; ++l) {
      const float* Wq_l = Wq + (size_t)l * TD * TD;
      const float* Wk_l = Wk + (size_t)l * TD * TD;
      const float* Wv_l = Wv + (size_t)l * TD * TD;
      const float* Wo_l = Wo + (size_t)l * TD * TD;
      const float* W1_l = W1 + (size_t)l * TD * TDFF;
      const float* W2_l = W2 + (size_t)l * TDFF * TD;

      rms_k<<<TB * TS, blk, 0, stream>>>(x, al1 + (size_t)l * TD, nb);
      gemm_k<128, float, false, unsigned short, false, false, false, false, false>
          <<<dim3(TD / 128, (TB * TS) / BM, 1), blk, 0, stream>>>(
              nb, TD, 0, 0, 1, Wq_l, TD, 0, 0, 1, qb, TD, 0, 0, 1, nullptr, nullptr, TD);
      gemm_k<128, float, false, unsigned short, false, false, false, false, false>
          <<<dim3(TD / 128, (TB * TS) / BM, 1), blk, 0, stream>>>(
              nb, TD, 0, 0, 1, Wk_l, TD, 0, 0, 1, kb, TD, 0, 0, 1, nullptr, nullptr, TD);
      gemm_k<128, float, false, unsigned short, false, false, false, false, false>
          <<<dim3(TD / 128, (TB * TS) / BM, 1), blk, 0, stream>>>(
              nb, TD, 0, 0, 1, Wv_l, TD, 0, 0, 1, vb, TD, 0, 0, 1, nullptr, nullptr, TD);
      gemm_k<128, unsigned short, true, float, false, false, false, true, false>
          <<<dim3(TS / 128, TS / 128, TB * TH), blk, 0, stream>>>(
              qb, TD, (long long)TS * TD, THD, TH,
              kb, TD, (long long)TS * TD, THD, TH,
              Pf, TS, (long long)TS * TS, 0, 1, nullptr, nullptr, THD);
      softmax_k<<<TB * TH * TS, blk, 0, stream>>>(Pf, Pb);
      gemm_k<64, unsigned short, false, unsigned short, false, false, false, false, true>
          <<<dim3(1, TS / 128, TB * TH), blk, 0, stream>>>(
              Pb, TS, (long long)TS * TS, 0, 1,
              vb, TD, (long long)TS * TD, THD, TH,
              ob, TD, (long long)TS * TD, THD, TH, nullptr, nullptr, TS);
      gemm_k<128, float, false, float, false, false, true, false, false>
          <<<dim3(TD / 128, (TB * TS) / BM, 1), blk, 0, stream>>>(
              ob, TD, 0, 0, 1, Wo_l, TD, 0, 0, 1, x, TD, 0, 0, 1, nullptr, x, TD);
      rms_k<<<TB * TS, blk, 0, stream>>>(x, al3 + (size_t)l * TD, nb);
      gemm_k<128, float, false, unsigned short, true, true, false, false, false>
          <<<dim3(TDFF / 128, (TB * TS) / BM, 1), blk, 0, stream>>>(
              nb, TD, 0, 0, 1, W1_l, TDFF, 0, 0, 1, f1b, TDFF, 0, 0, 1,
              b1 + (size_t)l * TDFF, nullptr, TD);
      gemm_k<128, float, false, float, true, false, true, false, false>
          <<<dim3(TD / 128, (TB * TS) / BM, 1), blk, 0, stream>>>(
              f1b, TDFF, 0, 0, 1, W2_l, TD, 0, 0, 1, x, TD, 0, 0, 1,
              b2 + (size_t)l * TD, x, TDFF);
    }
    rms_k<<<TB * TS, blk, 0, stream>>>(x, alf, nb);
    gemm_k<128, float, false, float, true, false, false, false, false>
        <<<dim3(TV / 128, (TB * TS) / BM, 1), blk, 0, stream>>>(
            nb, TD, 0, 0, 1, Wp, TV, 0, 0, 1, (float*)d_out, TV, 0, 0, 1,
            bp, nullptr, TD);
    logsoftmax_k<<<TB * TS, blk, 0, stream>>>((float*)d_out);
  }
}

// Round 10
// 630.276 us; speedup vs baseline: 1.1119x; 1.0048x over previous
//
#include <hip/hip_runtime.h>
#include <hip/hip_bf16.h>
#include <type_traits>

// ---------------------------------------------------------------------------
// Round 10: gemm8p with merged phases (2 phases/K-tile, 32 MFMA per barrier
// pair) to halve barrier count. Rest identical to round 9.
// ---------------------------------------------------------------------------

typedef float  f32x4 __attribute__((ext_vector_type(4)));
typedef __bf16 bf16x8 __attribute__((ext_vector_type(8)));
typedef unsigned short u16x8 __attribute__((ext_vector_type(8)));
typedef unsigned short u16x4 __attribute__((ext_vector_type(4)));

#define DI __device__ __forceinline__
#define VMW(n) asm volatile("s_waitcnt vmcnt(" #n ")" ::: "memory")
#define BARX   asm volatile("s_barrier" ::: "memory")

constexpr int TB = 2, TS = 1024, TD = 1024, TH = 16, TV = 32000, TL = 2,
              TDFF = 4096, THD = 64;
constexpr int BM = 128, BK = 64, BKP = 72;

DI unsigned short f2b(float f) {
  __bf16 h = (__bf16)f;
  return __builtin_bit_cast(unsigned short, h);
}
DI float b2f(unsigned short u) {
  unsigned v = ((unsigned)u) << 16;
  return __builtin_bit_cast(float, v);
}

DI void glds16(const void* g, void* l) {
  __builtin_amdgcn_global_load_lds(
      (const __attribute__((address_space(1))) unsigned int*)g,
      (__attribute__((address_space(3))) unsigned int*)l, 16, 0, 0);
}

// ---------------- fused: embedding*sqrt(D) + posenc + layer-0 RMS ----------
__global__ __launch_bounds__(256) void embed_rms_k(
    const int* __restrict__ tok, const float* __restrict__ emb,
    const float* __restrict__ alpha, float* __restrict__ x,
    unsigned short* __restrict__ out) {
  const int bs = blockIdx.x;
  const int s  = bs & (TS - 1);
  const int t  = tok[bs];
  const int tid = threadIdx.x;
  const int d0 = tid << 2;
  f32x4 e = *(const f32x4*)(emb + (size_t)t * TD + d0);
  f32x4 r;
#pragma unroll
  for (int j = 0; j < 4; ++j) {
    int d = d0 + j;
    int i2 = d >> 1;
    float freq = __expf((float)(2 * i2) * (-9.210340371976184f / (float)TD));
    float arg = (float)s * freq;
    float pe = (d & 1) ? __cosf(arg) : __sinf(arg);
    r[j] = e[j] * 32.0f + pe;
  }
  *(f32x4*)(x + (size_t)bs * TD + d0) = r;
  float ss = r[0] * r[0] + r[1] * r[1] + r[2] * r[2] + r[3] * r[3];
#pragma unroll
  for (int o = 32; o > 0; o >>= 1) ss += __shfl_down(ss, o);
  __shared__ float ps[4];
  __shared__ float invs;
  if ((tid & 63) == 0) ps[tid >> 6] = ss;
  __syncthreads();
  if (tid == 0) {
    float tot = ps[0] + ps[1] + ps[2] + ps[3];
    invs = 1.0f / (sqrtf(tot * (1.0f / (float)TD)) + 1e-8f);
  }
  __syncthreads();
  const float inv = invs;
  f32x4 av = *(const f32x4*)(alpha + d0);
  u16x4 ov;
#pragma unroll
  for (int j = 0; j < 4; ++j) ov[j] = f2b(av[j] * r[j] * inv);
  *(u16x4*)(out + (size_t)bs * TD + d0) = ov;
}

// ---------------- embedding * sqrt(D) + sinusoidal posenc (fallback) -------
__global__ __launch_bounds__(256) void embed_pe_k(const int* __restrict__ tok,
                                                  const float* __restrict__ emb,
                                                  float* __restrict__ x) {
  const int bs = blockIdx.x;
  const int s  = bs & (TS - 1);
  const int t  = tok[bs];
  const int d0 = threadIdx.x << 2;
  f32x4 e = *(const f32x4*)(emb + (size_t)t * TD + d0);
  f32x4 r;
#pragma unroll
  for (int j = 0; j < 4; ++j) {
    int d = d0 + j;
    int i2 = d >> 1;
    float freq = __expf((float)(2 * i2) * (-9.210340371976184f / (float)TD));
    float arg = (float)s * freq;
    float pe = (d & 1) ? __cosf(arg) : __sinf(arg);
    r[j] = e[j] * 32.0f + pe;
  }
  *(f32x4*)(x + (size_t)bs * TD + d0) = r;
}

// ---------------- RMS norm -> bf16 ----------------
__global__ __launch_bounds__(256) void rms_k(const float* __restrict__ xin,
                                             const float* __restrict__ alpha,
                                             unsigned short* __restrict__ out) {
  const int row = blockIdx.x;
  const int tid = threadIdx.x;
  const int d0 = tid << 2;
  f32x4 xv = *(const f32x4*)(xin + (size_t)row * TD + d0);
  float ss = xv[0] * xv[0] + xv[1] * xv[1] + xv[2] * xv[2] + xv[3] * xv[3];
#pragma unroll
  for (int o = 32; o > 0; o >>= 1) ss += __shfl_down(ss, o);
  __shared__ float ps[4];
  __shared__ float invs;
  if ((tid & 63) == 0) ps[tid >> 6] = ss;
  __syncthreads();
  if (tid == 0) {
    float tot = ps[0] + ps[1] + ps[2] + ps[3];
    invs = 1.0f / (sqrtf(tot * (1.0f / (float)TD)) + 1e-8f);
  }
  __syncthreads();
  const float inv = invs;
  f32x4 av = *(const f32x4*)(alpha + d0);
  u16x4 ov;
#pragma unroll
  for (int j = 0; j < 4; ++j) ov[j] = f2b(av[j] * xv[j] * inv);
  *(u16x4*)(out + (size_t)row * TD + d0) = ov;
}

// ---------------- fused flash attention -----------------------------------
__global__ __launch_bounds__(512) void attn_k(
    const unsigned short* __restrict__ qkv, const unsigned short* __restrict__ vt,
    unsigned short* __restrict__ ob) {
  const int q0 = blockIdx.x << 7;
  const int bh = blockIdx.y;
  const int b = bh >> 4, h = bh & 15;
  const unsigned short* Qg = qkv + (size_t)(b * TS) * 3072 + h * 64;
  const unsigned short* Kg = Qg + 1024;
  const unsigned short* Vg = vt + (size_t)b * TD * TS + (size_t)(h * 64) * TS;

  __shared__ __attribute__((aligned(16))) unsigned short Qs[128 * 64];
  __shared__ __attribute__((aligned(16))) unsigned short Ks[128 * 64];
  __shared__ __attribute__((aligned(16))) unsigned short Vs[64 * 128];
  __shared__ __attribute__((aligned(16))) unsigned short Sb[128 * 128];
  __shared__ float mi[128], li[128], scl[128];

  const int tid = threadIdx.x, lane = tid & 63, wid = tid >> 6;
  const int lm = lane & 15, hi = lane >> 4;
  const int wm = wid >> 2, wn = wid & 3;

  if (tid < 128) { mi[tid] = -3.0e38f; li[tid] = 0.f; }

  {
    const int srow = lane >> 3, schk = lane & 7;
#pragma unroll
    for (int i = 0; i < 2; ++i) {
      const int row = wid * 16 + i * 8 + srow;
      const unsigned char* src =
          (const unsigned char*)(Qg + (size_t)(q0 + row) * 3072) +
          ((schk * 16) ^ ((srow & 7) << 4));
      glds16(src, (unsigned char*)Qs + (wid * 16 + i * 8) * 128);
    }
  }

  f32x4 acc_o[4] = {};
  const int nt = blockIdx.x + 1;

  for (int t = 0; t < nt; ++t) {
    const int kv0 = t << 7;
    {
      const int srow = lane >> 3, schk = lane & 7;
#pragma unroll
      for (int i = 0; i < 2; ++i) {
        const int row = wid * 16 + i * 8 + srow;
        const unsigned char* src =
            (const unsigned char*)(Kg + (size_t)(kv0 + row) * 3072) +
            ((schk * 16) ^ ((srow & 7) << 4));
        glds16(src, (unsigned char*)Ks + (wid * 16 + i * 8) * 128);
      }
      const int vrow4 = lane >> 4, vchk = lane & 15;
#pragma unroll
      for (int i = 0; i < 2; ++i) {
        const int row = wid * 8 + i * 4 + vrow4;
        const unsigned char* src =
            (const unsigned char*)(Vg + (size_t)row * TS + kv0) +
            ((vchk * 16) ^ ((row & 15) << 4));
        glds16(src, (unsigned char*)Vs + (wid * 8 + i * 4) * 256);
      }
    }
    asm volatile("s_waitcnt vmcnt(0)");
    __syncthreads();

    f32x4 acc_s[4][2] = {};
#pragma unroll
    for (int kk = 0; kk < 2; ++kk) {
      bf16x8 af[4], bf[2];
#pragma unroll
      for (int i = 0; i < 4; ++i) {
        const int row = wm * 64 + i * 16 + lm;
        af[i] = __builtin_bit_cast(
            bf16x8, *(const u16x8*)((const unsigned char*)Qs + row * 128 +
                                    (((kk * 4 + hi) ^ (row & 7)) << 4)));
      }
#pragma unroll
      for (int j = 0; j < 2; ++j) {
        const int row = wn * 32 + j * 16 + lm;
        bf[j] = __builtin_bit_cast(
            bf16x8, *(const u16x8*)((const unsigned char*)Ks + row * 128 +
                                    (((kk * 4 + hi) ^ (row & 7)) << 4)));
      }
#pragma unroll
      for (int i = 0; i < 4; ++i)
#pragma unroll
        for (int j = 0; j < 2; ++j)
          acc_s[i][j] = __builtin_amdgcn_mfma_f32_16x16x32_bf16(af[i], bf[j],
                                                                acc_s[i][j], 0, 0, 0);
    }
#pragma unroll
    for (int i = 0; i < 4; ++i)
#pragma unroll
      for (int j = 0; j < 2; ++j)
#pragma unroll
        for (int e = 0; e < 4; ++e) {
          const int row = wm * 64 + i * 16 + hi * 4 + e;
          const int col = wn * 32 + j * 16 + lm;
          float v = acc_s[i][j][e] * 0.125f;
          if (kv0 + col > q0 + row) v = -1e30f;
          const int chunk = (col >> 3) ^ (row & 15);
          *(unsigned short*)((unsigned char*)Sb + row * 256 + chunk * 16 +
                             ((col & 7) << 1)) = f2b(v);
        }
    __syncthreads();

    {
      const int r = tid >> 2, qt = tid & 3;
      float v[32];
      float rmax = -3.0e38f;
#pragma unroll
      for (int cc = 0; cc < 4; ++cc) {
        const int c = qt * 4 + cc;
        u16x8 pk = *(const u16x8*)((const unsigned char*)Sb + r * 256 +
                                   ((c ^ (r & 15)) << 4));
#pragma unroll
        for (int j = 0; j < 8; ++j) {
          v[cc * 8 + j] = b2f(pk[j]);
          rmax = fmaxf(rmax, v[cc * 8 + j]);
        }
      }
      rmax = fmaxf(rmax, __shfl_xor(rmax, 1));
      rmax = fmaxf(rmax, __shfl_xor(rmax, 2));
      const float mold = mi[r];
      const float mnew = fmaxf(mold, rmax);
      float lsum = 0.f;
#pragma unroll
      for (int cc = 0; cc < 4; ++cc) {
        const int c = qt * 4 + cc;
        u16x8 pk;
#pragma unroll
        for (int j = 0; j < 8; ++j) {
          float p = __expf(v[cc * 8 + j] - mnew);
          lsum += p;
          pk[j] = f2b(p);
        }
        *(u16x8*)((unsigned char*)Sb + r * 256 + ((c ^ (r & 15)) << 4)) = pk;
      }
      lsum += __shfl_xor(lsum, 1);
      lsum += __shfl_xor(lsum, 2);
      if (qt == 0) {
        const float sc = __expf(mold - mnew);
        scl[r] = sc;
        li[r] = li[r] * sc + lsum;
        mi[r] = mnew;
      }
    }
    __syncthreads();

    {
      float sc[4];
#pragma unroll
      for (int e = 0; e < 4; ++e) sc[e] = scl[wid * 16 + hi * 4 + e];
#pragma unroll
      for (int j = 0; j < 4; ++j)
#pragma unroll
        for (int e = 0; e < 4; ++e) acc_o[j][e] *= sc[e];
#pragma unroll
      for (int ks = 0; ks < 4; ++ks) {
        const int arow = wid * 16 + lm;
        bf16x8 pa = __builtin_bit_cast(
            bf16x8, *(const u16x8*)((const unsigned char*)Sb + arow * 256 +
                                    (((ks * 4 + hi) ^ (arow & 15)) << 4)));
#pragma unroll
        for (int j = 0; j < 4; ++j) {
          const int drow = j * 16 + lm;
          bf16x8 vb = __builtin_bit_cast(
              bf16x8, *(const u16x8*)((const unsigned char*)Vs + drow * 256 +
                                      (((ks * 4 + hi) ^ (drow & 15)) << 4)));
          acc_o[j] = __builtin_amdgcn_mfma_f32_16x16x32_bf16(pa, vb, acc_o[j], 0, 0, 0);
        }
      }
    }
    __syncthreads();
  }

  float il[4];
#pragma unroll
  for (int e = 0; e < 4; ++e) il[e] = 1.0f / li[wid * 16 + hi * 4 + e];
#pragma unroll
  for (int j = 0; j < 4; ++j)
#pragma unroll
    for (int e = 0; e < 4; ++e) {
      const int row = q0 + wid * 16 + hi * 4 + e;
      const int col = h * 64 + j * 16 + lm;
      ob[(size_t)(b * TS + row) * TD + col] = f2b(acc_o[j][e] * il[e]);
    }
}

// ---------------- old f32->bf16 softmax (fallback path) ----------------
__global__ __launch_bounds__(256) void softmax_k(const float* __restrict__ Pf,
                                                 unsigned short* __restrict__ Pb) {
  const int r = blockIdx.x;
  const int valid = (r & (TS - 1)) + 1;
  const int tid = threadIdx.x;
  const float* row = Pf + (size_t)r * TS;
  unsigned short* orow = Pb + (size_t)r * TS;
  float vals[4];
  float lmax = -1e30f;
#pragma unroll
  for (int it = 0; it < 4; ++it) {
    int i = it * 256 + tid;
    float v = (i < valid) ? row[i] : -1e30f;
    vals[it] = v;
    lmax = fmaxf(lmax, v);
  }
#pragma unroll
  for (int o = 32; o > 0; o >>= 1) lmax = fmaxf(lmax, __shfl_down(lmax, o));
  __shared__ float ps[4];
  __shared__ float bcast;
  if ((tid & 63) == 0) ps[tid >> 6] = lmax;
  __syncthreads();
  if (tid == 0) bcast = fmaxf(fmaxf(ps[0], ps[1]), fmaxf(ps[2], ps[3]));
  __syncthreads();
  const float m = bcast;
  float lsum = 0.f;
#pragma unroll
  for (int it = 0; it < 4; ++it) {
    int i = it * 256 + tid;
    float e = (i < valid) ? __expf((vals[it] - m) * 0.125f) : 0.f;
    vals[it] = e;
    lsum += e;
  }
#pragma unroll
  for (int o = 32; o > 0; o >>= 1) lsum += __shfl_down(lsum, o);
  __syncthreads();
  if ((tid & 63) == 0) ps[tid >> 6] = lsum;
  __syncthreads();
  if (tid == 0) bcast = 1.0f / (ps[0] + ps[1] + ps[2] + ps[3]);
  __syncthreads();
  const float inv = bcast;
#pragma unroll
  for (int it = 0; it < 4; ++it) {
    int i = it * 256 + tid;
    orow[i] = f2b(vals[it] * inv);
  }
}

// ---------------- log_softmax over V, in place (fallback path) -------------
__global__ __launch_bounds__(256) void logsoftmax_k(float* __restrict__ logits) {
  const int r = blockIdx.x;
  float* row = logits + (size_t)r * TV;
  const int tid = threadIdx.x;
  float m = -1e30f, s = 0.f;
  for (int i = tid * 4; i < TV; i += 1024) {
    f32x4 v = *(const f32x4*)(row + i);
#pragma unroll
    for (int j = 0; j < 4; ++j) {
      float xv = v[j];
      if (xv > m) { s = s * __expf(m - xv) + 1.f; m = xv; }
      else s += __expf(xv - m);
    }
  }
#pragma unroll
  for (int o = 32; o > 0; o >>= 1) {
    float mo = __shfl_down(m, o);
    float so = __shfl_down(s, o);
    float M = fmaxf(m, mo);
    s = s * __expf(m - M) + so * __expf(mo - M);
    m = M;
  }
  __shared__ float pm[4], psv[4];
  __shared__ float blse;
  if ((tid & 63) == 0) { pm[tid >> 6] = m; psv[tid >> 6] = s; }
  __syncthreads();
  if (tid == 0) {
    float M = fmaxf(fmaxf(pm[0], pm[1]), fmaxf(pm[2], pm[3]));
    float S = psv[0] * __expf(pm[0] - M) + psv[1] * __expf(pm[1] - M) +
              psv[2] * __expf(pm[2] - M) + psv[3] * __expf(pm[3] - M);
    blse = M + logf(S);
  }
  __syncthreads();
  const float lse = blse;
  for (int i = tid * 4; i < TV; i += 1024) {
    f32x4 v = *(const f32x4*)(row + i);
    v[0] -= lse; v[1] -= lse; v[2] -= lse; v[3] -= lse;
    *(f32x4*)(row + i) = v;
  }
}

// ---------------- final: LSE from reg-buffered bf16 row; write f32 ---------
__global__ __launch_bounds__(1024) void lse_final_k(
    float* __restrict__ out, const unsigned short* __restrict__ lb) {
  const int r = blockIdx.x;
  const int tid = threadIdx.x;
  const unsigned short* row = lb + (size_t)r * 64000 + 32000;
  u16x4 buf[8];
#pragma unroll
  for (int i = 0; i < 8; ++i) {
    const int e = tid * 4 + i * 4096;
    if (e < TV) buf[i] = *(const u16x4*)(row + e);
  }
  float m = -1e30f;
#pragma unroll
  for (int i = 0; i < 8; ++i) {
    const int e = tid * 4 + i * 4096;
    if (e < TV) {
#pragma unroll
      for (int j = 0; j < 4; ++j) m = fmaxf(m, b2f(buf[i][j]));
    }
  }
  float s = 0.f;
#pragma unroll
  for (int i = 0; i < 8; ++i) {
    const int e = tid * 4 + i * 4096;
    if (e < TV) {
#pragma unroll
      for (int j = 0; j < 4; ++j) s += __expf(b2f(buf[i][j]) - m);
    }
  }
#pragma unroll
  for (int o = 32; o > 0; o >>= 1) {
    float mo = __shfl_xor(m, o);
    float so = __shfl_xor(s, o);
    float M = fmaxf(m, mo);
    s = s * __expf(m - M) + so * __expf(mo - M);
    m = M;
  }
  __shared__ float pm[16], psv[16];
  __shared__ float blse;
  if ((tid & 63) == 0) { pm[tid >> 6] = m; psv[tid >> 6] = s; }
  __syncthreads();
  if (tid == 0) {
    float M = pm[0];
#pragma unroll
    for (int w = 1; w < 16; ++w) M = fmaxf(M, pm[w]);
    float S = 0.f;
#pragma unroll
    for (int w = 0; w < 16; ++w) S += psv[w] * __expf(pm[w] - M);
    blse = M + logf(S);
  }
  __syncthreads();
  const float lse = blse;
  float* orow = out + (size_t)r * TV;
#pragma unroll
  for (int i = 0; i < 8; ++i) {
    const int e = tid * 4 + i * 4096;
    if (e < TV) {
      f32x4 v;
#pragma unroll
      for (int j = 0; j < 4; ++j) v[j] = b2f(buf[i][j]) - lse;
      *(f32x4*)(orow + e) = v;
    }
  }
}

// ---------------- weight transpose+convert: [K,N] f32 -> [N,K] bf16 --------
struct TEnt { const float* s; unsigned short* d; int K; int N; int t0; };
struct TTab { TEnt e[13]; };

__global__ __launch_bounds__(256) void transpose_all_k(TTab tab) {
  const int bid = blockIdx.x;
  int mi = 0;
#pragma unroll
  for (int i = 1; i < 13; ++i)
    if (bid >= tab.e[i].t0) mi = i;
  const TEnt E = tab.e[mi];
  const int lt = bid - E.t0;
  const int ntn = E.N >> 6;
  const int kt = lt / ntn, nt = lt - kt * ntn;
  const int k0 = kt << 6, n0 = nt << 6;
  __shared__ unsigned short t[64][68];
  const int tid = threadIdx.x;
  const int cr = tid >> 4, cc = (tid & 15) << 2;
#pragma unroll
  for (int it = 0; it < 4; ++it) {
    const int kl = it * 16 + cr;
    f32x4 v = *(const f32x4*)(E.s + (size_t)(k0 + kl) * E.N + n0 + cc);
    u16x4 o;
#pragma unroll
    for (int j = 0; j < 4; ++j) o[j] = f2b(v[j]);
    *(u16x4*)&t[kl][cc] = o;
  }
  __syncthreads();
  const int nl = tid & 63, kc = (tid >> 6) << 4;
  u16x8 r0, r1;
#pragma unroll
  for (int j = 0; j < 8; ++j) { r0[j] = t[kc + j][nl]; r1[j] = t[kc + 8 + j][nl]; }
  unsigned short* dp = E.d + (size_t)(n0 + nl) * E.K + k0 + kc;
  *(u16x8*)dp = r0;
  *(u16x8*)(dp + 8) = r1;
}

// ---------------- V slice transpose: qkv[:,2048+d] -> vt[b][d][s] ----------
__global__ __launch_bounds__(256) void vtrans_k(const unsigned short* __restrict__ qkv,
                                                unsigned short* __restrict__ vt) {
  const int d0 = blockIdx.x << 6, s0 = blockIdx.y << 6, b = blockIdx.z;
  __shared__ unsigned short t[64][68];
  const int tid = threadIdx.x;
  const int cr = tid >> 4, cc = (tid & 15) << 2;
#pragma unroll
  for (int it = 0; it < 4; ++it) {
    const int sl = it * 16 + cr;
    u16x4 v = *(const u16x4*)(qkv + (size_t)(b * TS + s0 + sl) * 3072 + 2048 + d0 + cc);
    *(u16x4*)&t[sl][cc] = v;
  }
  __syncthreads();
  const int dl = tid & 63, sc = (tid >> 6) << 4;
  u16x8 r0, r1;
#pragma unroll
  for (int j = 0; j < 8; ++j) { r0[j] = t[sc + j][dl]; r1[j] = t[sc + 8 + j][dl]; }
  unsigned short* dp = vt + (size_t)b * TD * TS + (size_t)(d0 + dl) * TS + s0 + sc;
  *(u16x8*)dp = r0;
  *(u16x8*)(dp + 8) = r1;
}

// ---------------- merged-phase 256x256 pipelined GEMM (projection) ---------
// A:[M,K] bf16, B:[N,K] bf16, C:[M,N] bf16 (+bias). 512 thr = 8 waves (2Mx4N).
// LDS ring: 8 quarter-slots x 16KB; tile kt uses slots {0-3} or {4-7};
// staging targets the other half (strict dbuf). 2 phases per K-tile, each:
// [2x stage_q, (boundary vmcnt), s_barrier, 12x ds_read_b128, setprio,
//  32 MFMA, setprio, s_barrier]. Counted waits in glds-instruction units
// (2 per quarter): steady 12 outstanding -> wm0 vmcnt(6), wm1 vmcnt(4);
// last tile 8 outstanding -> vmcnt(2)/(0).
__global__ __launch_bounds__(512, 2) void gemm8p_k(
    const unsigned short* __restrict__ A, int lda,
    const unsigned short* __restrict__ B, int ldb,
    unsigned short* __restrict__ C, long long ldc,
    const float* __restrict__ bias, int K) {
  extern __shared__ __attribute__((aligned(16))) char smem[];
  const int NT = K >> 6;
  int bx = blockIdx.x, by = blockIdx.y;
  {
    const int nwg = gridDim.x * gridDim.y;
    const int bid = by * gridDim.x + bx;
    const int q = nwg >> 3, rr = nwg & 7;
    const int xcd = bid & 7, idx = bid >> 3;
    const int nid = (xcd < rr ? xcd * (q + 1) : rr * (q + 1) + (xcd - rr) * q) + idx;
    bx = nid % gridDim.x;
    by = nid / gridDim.x;
  }
  const int m0 = bx * 256, n0 = by * 256;
  const int tid = threadIdx.x, lane = tid & 63, wid = tid >> 6;
  const int wm = wid >> 2, wn = wid & 3;
  const int lm = lane & 15, hi = lane >> 4;
  const int srow = lane >> 3, schk = lane & 7;
  const int axor = (lm & 7) << 4;
  const int swz = (schk * 16) ^ ((srow & 7) << 4);
  const int rb = (wn & 1) * 64;

  const char* srcA = (const char*)(A + (size_t)(m0 + wid * 8 + srow) * lda) + swz;
  const char* srcB = (const char*)(B + (size_t)(n0 + wid * 8 + srow) * ldb) + swz;
  char* dstW = smem + wid * 8 * 128;

  auto stage_q = [&](int q) {
    const int kt_t = q >> 2, jj = q & 3;
    char* d = dstW + (q & 7) * 16384;
    if (jj < 2) {
      const char* s = srcB + ((size_t)(jj * 128) * ldb + (size_t)kt_t * 64) * 2;
      glds16(s, d);
      glds16(s + (size_t)64 * ldb * 2, d + 64 * 128);
    } else {
      const char* s = srcA + ((size_t)((jj - 2) * 128) * lda + (size_t)kt_t * 64) * 2;
      glds16(s, d);
      glds16(s + (size_t)64 * lda * 2, d + 64 * 128);
    }
  };

  // prologue: tile 0's quarters
  stage_q(0); stage_q(1); stage_q(2); stage_q(3);

  f32x4 acc[8][4] = {};

  for (int kt = 0; kt < NT; ++kt) {
    const char* ta = smem + ((kt & 1) * 4 + 2 + wm) * 16384;
    const char* tb = smem + ((kt & 1) * 4 + (wn >> 1)) * 16384;
    const bool more = (kt + 1 < NT);
    bf16x8 bfr[4], af[8];

    // ---- phase 0 (kk=0, all 8 M-fragments): boundary wait ----
    if (more) { stage_q(4 * kt + 4); stage_q(4 * kt + 5); }
    if (more) { if (wm == 0) { VMW(6); } else { VMW(4); } }
    else      { if (wm == 0) { VMW(2); } else { VMW(0); } }
    BARX;
#pragma unroll
    for (int j = 0; j < 4; ++j)
      bfr[j] = __builtin_bit_cast(
          bf16x8, *(const u16x8*)(tb + (rb + j * 16 + lm) * 128 + ((hi * 16) ^ axor)));
#pragma unroll
    for (int i = 0; i < 8; ++i)
      af[i] = __builtin_bit_cast(
          bf16x8, *(const u16x8*)(ta + (i * 16 + lm) * 128 + ((hi * 16) ^ axor)));
    __builtin_amdgcn_s_setprio(1);
#pragma unroll
    for (int i = 0; i < 8; ++i)
#pragma unroll
      for (int j = 0; j < 4; ++j)
        acc[i][j] = __builtin_amdgcn_mfma_f32_16x16x32_bf16(af[i], bfr[j],
                                                            acc[i][j], 0, 0, 0);
    __builtin_amdgcn_s_setprio(0);
    BARX;

    // ---- phase 1 (kk=1, all 8 M-fragments) ----
    if (more) { stage_q(4 * kt + 6); stage_q(4 * kt + 7); }
    BARX;
#pragma unroll
    for (int j = 0; j < 4; ++j)
      bfr[j] = __builtin_bit_cast(
          bf16x8,
          *(const u16x8*)(tb + (rb + j * 16 + lm) * 128 + ((64 + hi * 16) ^ axor)));
#pragma unroll
    for (int i = 0; i < 8; ++i)
      af[i] = __builtin_bit_cast(
          bf16x8, *(const u16x8*)(ta + (i * 16 + lm) * 128 + ((64 + hi * 16) ^ axor)));
    __builtin_amdgcn_s_setprio(1);
#pragma unroll
    for (int i = 0; i < 8; ++i)
#pragma unroll
      for (int j = 0; j < 4; ++j)
        acc[i][j] = __builtin_amdgcn_mfma_f32_16x16x32_bf16(af[i], bfr[j],
                                                            acc[i][j], 0, 0, 0);
    __builtin_amdgcn_s_setprio(0);
    BARX;
  }

  // ---- epilogue ----
#pragma unroll
  for (int mi = 0; mi < 8; ++mi)
#pragma unroll
    for (int j = 0; j < 4; ++j) {
      const int col = n0 + wn * 64 + j * 16 + lm;
      const float bv = bias[col];
#pragma unroll
      for (int e = 0; e < 4; ++e) {
        const long long row = m0 + wm * 128 + mi * 16 + hi * 4 + e;
        C[row * ldc + col] = f2b(acc[mi][j][e] + bv);
      }
    }
}

// ---------------- GEMM: A,B bf16 [*,K]; global_load_lds; opt. XCD swizzle --
template <int BM_, int BN, typename OT, bool HB, bool HS, bool HR, bool CSKIP,
          bool CAUSA, bool GSWAP, bool XSWZ, bool DBUF>
__global__ __launch_bounds__(256) void gemm2_k(
    const unsigned short* __restrict__ A, int lda, long long sAo, long long sAi, int iA,
    const unsigned short* __restrict__ B, int ldb, long long sBo, long long sBi, int iB,
    OT* __restrict__ C, int ldc, long long sCo, long long sCi, int iC,
    const float* __restrict__ bias, const float* __restrict__ res, int K) {
  constexpr int WN = BN / 2;
  constexpr int FN = WN / 16;
  constexpr int FM = BM_ / 32;
  constexpr int NB = DBUF ? 2 : 1;
  int bx = blockIdx.x, by = blockIdx.y;
  if constexpr (XSWZ) {
    const int nwg = gridDim.x * gridDim.y;
    const int bid = by * gridDim.x + bx;
    const int q = nwg >> 3, rr = nwg & 7;
    const int xcd = bid & 7, idx = bid >> 3;
    const int nid = (xcd < rr ? xcd * (q + 1) : rr * (q + 1) + (xcd - rr) * q) + idx;
    bx = nid % gridDim.x;
    by = nid / gridDim.x;
  }
  const int m0 = (GSWAP ? bx : by) * BM_;
  const int n0 = (GSWAP ? by : bx) * BN;
  if (CSKIP && n0 > m0 + BM_ - 1) return;
  const int bz = blockIdx.z;
  A += (long long)(bz / iA) * sAo + (long long)(bz % iA) * sAi;
  B += (long long)(bz / iB) * sBo + (long long)(bz % iB) * sBi;
  C += (long long)(bz / iC) * sCo + (long long)(bz % iC) * sCi;

  __shared__ __attribute__((aligned(16))) unsigned short As[NB][BM_ * 64];
  __shared__ __attribute__((aligned(16))) unsigned short Bs[NB][BN * 64];

  const int tid = threadIdx.x, lane = tid & 63, wid = tid >> 6;
  const int wm = wid >> 1, wn = wid & 1;
  const int lm = lane & 15, hi = lane >> 4;

  const int srow = lane >> 3, schk = lane & 7;
  const int sxor = (srow & 7) << 4;
  const unsigned char* AgB =
      (const unsigned char*)(A + (size_t)(m0 + wid * (BM_ / 4) + srow) * lda) +
      ((schk * 16) ^ sxor);
  const unsigned char* BgB =
      (const unsigned char*)(B + (size_t)(n0 + wid * (BN / 4) + srow) * ldb) +
      ((schk * 16) ^ sxor);
  const size_t ldab = (size_t)lda * 2, ldbb = (size_t)ldb * 2;

  auto stage = [&](int kb, int bi) {
#pragma unroll
    for (int i = 0; i < BM_ / 32; ++i)
      glds16(AgB + kb + (size_t)i * 8 * ldab,
             (unsigned char*)As[bi] + wid * (BM_ / 4) * 128 + i * 1024);
#pragma unroll
    for (int i = 0; i < BN / 32; ++i)
      glds16(BgB + kb + (size_t)i * 8 * ldbb,
             (unsigned char*)Bs[bi] + wid * (BN / 4) * 128 + i * 1024);
  };

  f32x4 acc[FM][FN] = {};
  const int kend = CAUSA ? ((K < m0 + BM_) ? K : m0 + BM_) : K;
  const int axor = (lm & 7) << 4;

  int cur = 0;
  if constexpr (DBUF) {
    stage(0, 0);
    __syncthreads();
  }
  for (int k0 = 0; k0 < kend; k0 += 64) {
    if constexpr (DBUF) {
      if (k0 + 64 < kend) stage((k0 + 64) * 2, cur ^ 1);
    } else {
      stage(k0 * 2, 0);
      __syncthreads();
    }
    const unsigned char* AsP = (const unsigned char*)As[DBUF ? cur : 0];
    const unsigned char* BsP = (const unsigned char*)Bs[DBUF ? cur : 0];
#pragma unroll
    for (int kk = 0; kk < 2; ++kk) {
      const int kb = (kk * 64 + hi * 16) ^ axor;
      bf16x8 af[FM], bfr[FN];
#pragma unroll
      for (int i = 0; i < FM; ++i)
        af[i] = __builtin_bit_cast(
            bf16x8, *(const u16x8*)(AsP + (wm * (BM_ / 2) + i * 16 + lm) * 128 + kb));
#pragma unroll
      for (int j = 0; j < FN; ++j)
        bfr[j] = __builtin_bit_cast(
            bf16x8, *(const u16x8*)(BsP + (wn * WN + j * 16 + lm) * 128 + kb));
#pragma unroll
      for (int i = 0; i < FM; ++i)
#pragma unroll
        for (int j = 0; j < FN; ++j)
          acc[i][j] = __builtin_amdgcn_mfma_f32_16x16x32_bf16(af[i], bfr[j],
                                                              acc[i][j], 0, 0, 0);
    }
    __syncthreads();
    cur ^= 1;
  }

#pragma unroll
  for (int i = 0; i < FM; ++i) {
    const int rbase = m0 + wm * (BM_ / 2) + i * 16 + (hi << 2);
#pragma unroll
    for (int j = 0; j < FN; ++j) {
      const int c = n0 + wn * WN + j * 16 + lm;
      const float bval = HB ? bias[c] : 0.f;
#pragma unroll
      for (int e = 0; e < 4; ++e) {
        float v = acc[i][j][e];
        if (HB) v += bval;
        if (HS) v = v / (1.f + __expf(-v));
        const long long off = (long long)(rbase + e) * ldc + c;
        if (HR) v += res[off];
        if constexpr (std::is_same_v<OT, float>) C[off] = v;
        else C[off] = f2b(v);
      }
    }
  }
}

// ---------------- old GEMM (round-1, fallback path) ----------------
template <int BN, typename BT, bool BNK, typename OT, bool HB, bool HS, bool HR,
          bool CSKIP, bool CAUSA>
__global__ __launch_bounds__(256) void gemm_k(
    const unsigned short* __restrict__ A, int lda, long long sAo, long long sAi, int iA,
    const BT* __restrict__ Bg, int ldb, long long sBo, long long sBi, int iB,
    OT* __restrict__ Cg, int ldc, long long sCo, long long sCi, int iC,
    const float* __restrict__ bias, const float* __restrict__ res, int K) {
  constexpr int WN = BN / 2;
  constexpr int FN = WN / 16;
  constexpr int FM = 4;
  const int m0 = blockIdx.y * BM;
  const int n0 = blockIdx.x * BN;
  if (CSKIP && n0 > m0 + BM - 1) return;
  const int bz = blockIdx.z;
  A  += (long long)(bz / iA) * sAo + (long long)(bz % iA) * sAi;
  Bg += (long long)(bz / iB) * sBo + (long long)(bz % iB) * sBi;
  Cg += (long long)(bz / iC) * sCo + (long long)(bz % iC) * sCi;

  __shared__ __attribute__((aligned(16))) unsigned short As[BM * BKP];
  __shared__ __attribute__((aligned(16))) unsigned short Bs[BN * BKP];

  const int tid = threadIdx.x;
  const int lane = tid & 63;
  const int wid = tid >> 6;
  const int wm = wid >> 1, wn = wid & 1;
  const int lm = lane & 15;
  const int lk = (lane >> 4) << 3;

  f32x4 acc[FM][FN] = {};
  const int kend = CAUSA ? ((K < m0 + BM) ? K : m0 + BM) : K;

  for (int k0 = 0; k0 < kend; k0 += BK) {
#pragma unroll
    for (int it = 0; it < (BM * BK / 8) / 256; ++it) {
      int idx = it * 256 + tid;
      int rowa = idx >> 3;
      int kc = (idx & 7) << 3;
      u16x8 av = *(const u16x8*)(A + (size_t)(m0 + rowa) * lda + (k0 + kc));
      *(u16x8*)&As[rowa * BKP + kc] = av;
    }
    if constexpr (BNK) {
#pragma unroll
      for (int it = 0; it < (BN * BK / 8) / 256; ++it) {
        int idx = it * 256 + tid;
        int rowb = idx >> 3;
        int kc = (idx & 7) << 3;
        u16x8 bv = *(const u16x8*)((const unsigned short*)Bg +
                                   (size_t)(n0 + rowb) * ldb + (k0 + kc));
        *(u16x8*)&Bs[rowb * BKP + (kc ^ (((rowb >> 3) & 7) << 3))] = bv;
      }
    } else {
      constexpr int NCH = BN / 8;
#pragma unroll
      for (int it = 0; it < (BK * NCH) / 256; ++it) {
        int idx = it * 256 + tid;
        int nc = (idx & (NCH - 1)) << 3;
        int kr = idx / NCH;
        unsigned short ub[8];
        if constexpr (std::is_same_v<BT, float>) {
          const float* bp = Bg + (size_t)(k0 + kr) * ldb + (n0 + nc);
          f32x4 b0 = *(const f32x4*)bp;
          f32x4 b1 = *(const f32x4*)(bp + 4);
#pragma unroll
          for (int j = 0; j < 4; ++j) { ub[j] = f2b(b0[j]); ub[4 + j] = f2b(b1[j]); }
        } else {
          const unsigned short* bp =
              (const unsigned short*)Bg + (size_t)(k0 + kr) * ldb + (n0 + nc);
          u16x8 raw = *(const u16x8*)bp;
#pragma unroll
          for (int j = 0; j < 8; ++j) ub[j] = raw[j];
        }
        const int sw = ((nc >> 3) & 7) << 3;
#pragma unroll
        for (int j = 0; j < 8; ++j) Bs[(nc + j) * BKP + (kr ^ sw)] = ub[j];
      }
    }
    __syncthreads();
#pragma unroll
    for (int kk = 0; kk < 2; ++kk) {
      bf16x8 af[FM];
      bf16x8 bfr[FN];
#pragma unroll
      for (int i = 0; i < FM; ++i)
        af[i] = __builtin_bit_cast(
            bf16x8, *(const u16x8*)&As[(wm * 64 + i * 16 + lm) * BKP + (kk * 32 + lk)]);
#pragma unroll
      for (int j = 0; j < FN; ++j) {
        const int nr = wn * WN + j * 16 + lm;
        bfr[j] = __builtin_bit_cast(
            bf16x8,
            *(const u16x8*)&Bs[nr * BKP + ((kk * 32 + lk) ^ (((nr >> 3) & 7) << 3))]);
      }
#pragma unroll
      for (int i = 0; i < FM; ++i)
#pragma unroll
        for (int j = 0; j < FN; ++j)
          acc[i][j] = __builtin_amdgcn_mfma_f32_16x16x32_bf16(af[i], bfr[j],
                                                              acc[i][j], 0, 0, 0);
    }
    __syncthreads();
  }

#pragma unroll
  for (int i = 0; i < FM; ++i) {
    const int rbase = m0 + wm * 64 + i * 16 + ((lane >> 4) << 2);
#pragma unroll
    for (int j = 0; j < FN; ++j) {
      const int c = n0 + wn * WN + j * 16 + lm;
      const float bval = HB ? bias[c] : 0.f;
#pragma unroll
      for (int e = 0; e < 4; ++e) {
        float v = acc[i][j][e];
        if (HB) v += bval;
        if (HS) v = v / (1.f + __expf(-v));
        const long long off = (long long)(rbase + e) * ldc + c;
        if (HR) v += res[off];
        if constexpr (std::is_same_v<OT, float>) Cg[off] = v;
        else Cg[off] = f2b(v);
      }
    }
  }
}

// ---------------------------------------------------------------------------
extern "C" void kernel_launch(void* const* d_in, const int* in_sizes, int n_in,
                              void* d_out, int out_size, void* d_ws, size_t ws_size,
                              hipStream_t stream) {
  const int*   tok = (const int*)d_in[0];
  const float* emb = (const float*)d_in[2];
  const float* Wq  = (const float*)d_in[3];
  const float* Wk  = (const float*)d_in[4];
  const float* Wv  = (const float*)d_in[5];
  const float* Wo  = (const float*)d_in[6];
  const float* al1 = (const float*)d_in[7];
  const float* al3 = (const float*)d_in[8];
  const float* W1  = (const float*)d_in[9];
  const float* b1  = (const float*)d_in[10];
  const float* W2  = (const float*)d_in[11];
  const float* b2  = (const float*)d_in[12];
  const float* alf = (const float*)d_in[13];
  const float* Wp  = (const float*)d_in[14];
  const float* bp  = (const float*)d_in[15];

  char* ws = (char*)d_ws;
  dim3 blk(256);

  const size_t NEED = 166199296ULL;
  if (ws_size >= NEED) {
    // ---------------- new path ----------------
    float* x           = (float*)(ws);                        // 8 MB
    unsigned short* nb = (unsigned short*)(ws + 8388608);     // 4 MB
    unsigned short* qkv= (unsigned short*)(ws + 12582912);    // 12 MB [2048,3072]
    unsigned short* vt = (unsigned short*)(ws + 25165824);    // 4 MB  [B][D][S]
    unsigned short* ob = (unsigned short*)(ws + 29360128);    // 4 MB
    unsigned short* f1b= (unsigned short*)(ws + 33554432);    // 16 MB [2048,4096]
    unsigned short* wqkvT = (unsigned short*)(ws + 50331648); // 12 MB
    unsigned short* woT   = (unsigned short*)(ws + 62914560); // 4 MB
    unsigned short* w1T   = (unsigned short*)(ws + 67108864); // 16 MB
    unsigned short* w2T   = (unsigned short*)(ws + 83886080); // 16 MB
    unsigned short* wpT   = (unsigned short*)(ws + 100663296);// 62.5 MB
    // bf16 logits: second half of each f32 row slot in d_out
    unsigned short* lgb = (unsigned short*)d_out + 32000;     // ldc=64000

    hipFuncSetAttribute((const void*)gemm8p_k,
                        hipFuncAttributeMaxDynamicSharedMemorySize, 131072);

    TTab tab;
    const int M1 = 1048576;
    tab.e[0]  = {Wq,           wqkvT,               1024, 1024, 0};
    tab.e[1]  = {Wk,           wqkvT + M1,          1024, 1024, 256};
    tab.e[2]  = {Wv,           wqkvT + 2 * M1,      1024, 1024, 512};
    tab.e[3]  = {Wq + M1,      wqkvT + 3 * M1,      1024, 1024, 768};
    tab.e[4]  = {Wk + M1,      wqkvT + 4 * M1,      1024, 1024, 1024};
    tab.e[5]  = {Wv + M1,      wqkvT + 5 * M1,      1024, 1024, 1280};
    tab.e[6]  = {Wo,           woT,                 1024, 1024, 1536};
    tab.e[7]  = {Wo + M1,      woT + M1,            1024, 1024, 1792};
    tab.e[8]  = {W1,           w1T,                 1024, 4096, 2048};
    tab.e[9]  = {W1 + 4 * M1,  w1T + 4 * M1,        1024, 4096, 3072};
    tab.e[10] = {W2,           w2T,                 4096, 1024, 4096};
    tab.e[11] = {W2 + 4 * M1,  w2T + 4 * M1,        4096, 1024, 5120};
    tab.e[12] = {Wp,           wpT,                 1024, 32000, 6144};
    transpose_all_k<<<14144, blk, 0, stream>>>(tab);

    // fused embedding + posenc + layer-0 RMS
    embed_rms_k<<<TB * TS, blk, 0, stream>>>(tok, emb, al1, x, nb);

    for (int l = 0; l < TL; ++l) {
      if (l > 0) rms_k<<<TB * TS, blk, 0, stream>>>(x, al1 + (size_t)l * TD, nb);

      // fused QKV: [2048,1024] x [3072,1024]^T -> qkv [2048,3072] (BM=64)
      gemm2_k<64, 128, unsigned short, false, false, false, false, false, false, true, false>
          <<<dim3(24, 32, 1), blk, 0, stream>>>(
              nb, TD, 0, 0, 1, wqkvT + (size_t)l * 3 * M1, TD, 0, 0, 1,
              qkv, 3072, 0, 0, 1, nullptr, nullptr, TD);

      vtrans_k<<<dim3(16, 16, TB), blk, 0, stream>>>(qkv, vt);

      // fused flash attention: QK^T + online softmax + PV
      attn_k<<<dim3(8, TB * TH), dim3(512), 0, stream>>>(qkv, vt, ob);

      // x += O @ Wo  (64x64, 512 blk, 2-phase dbuf)
      gemm2_k<64, 64, float, false, false, true, false, false, false, true, true>
          <<<dim3(16, 32, 1), blk, 0, stream>>>(
              ob, TD, 0, 0, 1, woT + (size_t)l * M1, TD, 0, 0, 1,
              x, TD, 0, 0, 1, nullptr, x, TD);

      rms_k<<<TB * TS, blk, 0, stream>>>(x, al3 + (size_t)l * TD, nb);

      // f1 = silu(n @ W1 + b1)  (64x128, 1024 blk)
      gemm2_k<64, 128, unsigned short, true, true, false, false, false, false, true, false>
          <<<dim3(32, 32, 1), blk, 0, stream>>>(
              nb, TD, 0, 0, 1, w1T + (size_t)l * 4 * M1, TD, 0, 0, 1,
              f1b, TDFF, 0, 0, 1, b1 + (size_t)l * TDFF, nullptr, TD);

      // x += f1 @ W2 + b2  (64x64, 512 blk, 2-phase dbuf)
      gemm2_k<64, 64, float, true, false, true, false, false, false, true, true>
          <<<dim3(16, 32, 1), blk, 0, stream>>>(
              f1b, TDFF, 0, 0, 1, w2T + (size_t)l * 4 * M1, TDFF, 0, 0, 1,
              x, TD, 0, 0, 1, b2 + (size_t)l * TD, x, TDFF);
    }

    rms_k<<<TB * TS, blk, 0, stream>>>(x, alf, nb);

    // logits (bf16, colocated) = n @ Wp + bp : merged-phase 256x256 pipeline
    gemm8p_k<<<dim3(8, 125, 1), dim3(512), 131072, stream>>>(
        nb, TD, wpT, TD, lgb, 64000, bp, TD);

    lse_final_k<<<TB * TS, dim3(1024), 0, stream>>>(
        (float*)d_out, (const unsigned short*)d_out);
    return;
  }

  // ---------------- fallback: round-1 path ----------------
  {
    float* x            = (float*)(ws);
    unsigned short* nb  = (unsigned short*)(ws + 8388608);
    unsigned short* qb  = (unsigned short*)(ws + 12582912);
    unsigned short* kb  = (unsigned short*)(ws + 16777216);
    unsigned short* vb  = (unsigned short*)(ws + 20971520);
    unsigned short* ob  = (unsigned short*)(ws + 25165824);
    unsigned short* f1b = (unsigned short*)(ws + 29360128);
    float* Pf = (float*)d_out;
    unsigned short* Pb = (unsigned short*)d_out + 67108864LL;

    embed_pe_k<<<TB * TS, blk, 0, stream>>>(tok, emb, x);
    for (int l = 0; l < TL; ++l) {
      const float* Wq_l = Wq + (size_t)l * TD * TD;
      const float* Wk_l = Wk + (size_t)l * TD * TD;
      const float* Wv_l = Wv + (size_t)l * TD * TD;
      const float* Wo_l = Wo + (size_t)l * TD * TD;
      const float* W1_l = W1 + (size_t)l * TD * TDFF;
      const float* W2_l = W2 + (size_t)l * TDFF * TD;

      rms_k<<<TB * TS, blk, 0, stream>>>(x, al1 + (size_t)l * TD, nb);
      gemm_k<128, float, false, unsigned short, false, false, false, false, false>
          <<<dim3(TD / 128, (TB * TS) / BM, 1), blk, 0, stream>>>(
              nb, TD, 0, 0, 1, Wq_l, TD, 0, 0, 1, qb, TD, 0, 0, 1, nullptr, nullptr, TD);
      gemm_k<128, float, false, unsigned short, false, false, false, false, false>
          <<<dim3(TD / 128, (TB * TS) / BM, 1), blk, 0, stream>>>(
              nb, TD, 0, 0, 1, Wk_l, TD, 0, 0, 1, kb, TD, 0, 0, 1, nullptr, nullptr, TD);
      gemm_k<128, float, false, unsigned short, false, false, false, false, false>
          <<<dim3(TD / 128, (TB * TS) / BM, 1), blk, 0, stream>>>(
              nb, TD, 0, 0, 1, Wv_l, TD, 0, 0, 1, vb, TD, 0, 0, 1, nullptr, nullptr, TD);
      gemm_k<128, unsigned short, true, float, false, false, false, true, false>
          <<<dim3(TS / 128, TS / 128, TB * TH), blk, 0, stream>>>(
              qb, TD, (long long)TS * TD, THD, TH,
              kb, TD, (long long)TS * TD, THD, TH,
              Pf, TS, (long long)TS * TS, 0, 1, nullptr, nullptr, THD);
      softmax_k<<<TB * TH * TS, blk, 0, stream>>>(Pf, Pb);
      gemm_k<64, unsigned short, false, unsigned short, false, false, false, false, true>
          <<<dim3(1, TS / 128, TB * TH), blk, 0, stream>>>(
              Pb, TS, (long long)TS * TS, 0, 1,
              vb, TD, (long long)TS * TD, THD, TH,
              ob, TD, (long long)TS * TD, THD, TH, nullptr, nullptr, TS);
      gemm_k<128, float, false, float, false, false, true, false, false>
          <<<dim3(TD / 128, (TB * TS) / BM, 1), blk, 0, stream>>>(
              ob, TD, 0, 0, 1, Wo_l, TD, 0, 0, 1, x, TD, 0, 0, 1, nullptr, x, TD);
      rms_k<<<TB * TS, blk, 0, stream>>>(x, al3 + (size_t)l * TD, nb);
      gemm_k<128, float, false, unsigned short, true, true, false, false, false>
          <<<dim3(TDFF / 128, (TB * TS) / BM, 1), blk, 0, stream>>>(
              nb, TD, 0, 0, 1, W1_l, TDFF, 0, 0, 1, f1b, TDFF, 0, 0, 1,
              b1 + (size_t)l * TDFF, nullptr, TD);
      gemm_k<128, float, false, float, true, false, true, false, false>
          <<<dim3(TD / 128, (TB * TS) / BM, 1), blk, 0, stream>>>(
              f1b, TDFF, 0, 0, 1, W2_l, TD, 0, 0, 1, x, TD, 0, 0, 1,
              b2 + (size_t)l * TD, x, TDFF);
    }
    rms_k<<<TB * TS, blk, 0, stream>>>(x, alf, nb);
    gemm_k<128, float, false, float, true, false, false, false, false>
        <<<dim3(TV / 128, (TB * TS) / BM, 1), blk, 0, stream>>>(
            nb, TD, 0, 0, 1, Wp, TV, 0, 0, 1, (float*)d_out, TV, 0, 0, 1,
            bp, nullptr, TD);
    logsoftmax_k<<<TB * TS, blk, 0, stream>>>((float*)d_out);
  }
}

// Round 11
// 621.060 us; speedup vs baseline: 1.1284x; 1.0148x over previous
//
#include <hip/hip_runtime.h>
#include <hip/hip_bf16.h>
#include <type_traits>

// ---------------------------------------------------------------------------
// Round 11: gemm8p restructured — 2 barriers/K-tile, uniform (provably safe)
// vmcnt(4) drain, all 24 ds_reads issued up front so kk1 reads overlap kk0
// MFMAs. Rest identical to round 10.
// ---------------------------------------------------------------------------

typedef float  f32x4 __attribute__((ext_vector_type(4)));
typedef __bf16 bf16x8 __attribute__((ext_vector_type(8)));
typedef unsigned short u16x8 __attribute__((ext_vector_type(8)));
typedef unsigned short u16x4 __attribute__((ext_vector_type(4)));

#define DI __device__ __forceinline__
#define VMW(n) asm volatile("s_waitcnt vmcnt(" #n ")" ::: "memory")
#define BARX   asm volatile("s_barrier" ::: "memory")

constexpr int TB = 2, TS = 1024, TD = 1024, TH = 16, TV = 32000, TL = 2,
              TDFF = 4096, THD = 64;
constexpr int BM = 128, BK = 64, BKP = 72;

DI unsigned short f2b(float f) {
  __bf16 h = (__bf16)f;
  return __builtin_bit_cast(unsigned short, h);
}
DI float b2f(unsigned short u) {
  unsigned v = ((unsigned)u) << 16;
  return __builtin_bit_cast(float, v);
}

DI void glds16(const void* g, void* l) {
  __builtin_amdgcn_global_load_lds(
      (const __attribute__((address_space(1))) unsigned int*)g,
      (__attribute__((address_space(3))) unsigned int*)l, 16, 0, 0);
}

// ---------------- fused: embedding*sqrt(D) + posenc + layer-0 RMS ----------
__global__ __launch_bounds__(256) void embed_rms_k(
    const int* __restrict__ tok, const float* __restrict__ emb,
    const float* __restrict__ alpha, float* __restrict__ x,
    unsigned short* __restrict__ out) {
  const int bs = blockIdx.x;
  const int s  = bs & (TS - 1);
  const int t  = tok[bs];
  const int tid = threadIdx.x;
  const int d0 = tid << 2;
  f32x4 e = *(const f32x4*)(emb + (size_t)t * TD + d0);
  f32x4 r;
#pragma unroll
  for (int j = 0; j < 4; ++j) {
    int d = d0 + j;
    int i2 = d >> 1;
    float freq = __expf((float)(2 * i2) * (-9.210340371976184f / (float)TD));
    float arg = (float)s * freq;
    float pe = (d & 1) ? __cosf(arg) : __sinf(arg);
    r[j] = e[j] * 32.0f + pe;
  }
  *(f32x4*)(x + (size_t)bs * TD + d0) = r;
  float ss = r[0] * r[0] + r[1] * r[1] + r[2] * r[2] + r[3] * r[3];
#pragma unroll
  for (int o = 32; o > 0; o >>= 1) ss += __shfl_down(ss, o);
  __shared__ float ps[4];
  __shared__ float invs;
  if ((tid & 63) == 0) ps[tid >> 6] = ss;
  __syncthreads();
  if (tid == 0) {
    float tot = ps[0] + ps[1] + ps[2] + ps[3];
    invs = 1.0f / (sqrtf(tot * (1.0f / (float)TD)) + 1e-8f);
  }
  __syncthreads();
  const float inv = invs;
  f32x4 av = *(const f32x4*)(alpha + d0);
  u16x4 ov;
#pragma unroll
  for (int j = 0; j < 4; ++j) ov[j] = f2b(av[j] * r[j] * inv);
  *(u16x4*)(out + (size_t)bs * TD + d0) = ov;
}

// ---------------- embedding * sqrt(D) + sinusoidal posenc (fallback) -------
__global__ __launch_bounds__(256) void embed_pe_k(const int* __restrict__ tok,
                                                  const float* __restrict__ emb,
                                                  float* __restrict__ x) {
  const int bs = blockIdx.x;
  const int s  = bs & (TS - 1);
  const int t  = tok[bs];
  const int d0 = threadIdx.x << 2;
  f32x4 e = *(const f32x4*)(emb + (size_t)t * TD + d0);
  f32x4 r;
#pragma unroll
  for (int j = 0; j < 4; ++j) {
    int d = d0 + j;
    int i2 = d >> 1;
    float freq = __expf((float)(2 * i2) * (-9.210340371976184f / (float)TD));
    float arg = (float)s * freq;
    float pe = (d & 1) ? __cosf(arg) : __sinf(arg);
    r[j] = e[j] * 32.0f + pe;
  }
  *(f32x4*)(x + (size_t)bs * TD + d0) = r;
}

// ---------------- RMS norm -> bf16 ----------------
__global__ __launch_bounds__(256) void rms_k(const float* __restrict__ xin,
                                             const float* __restrict__ alpha,
                                             unsigned short* __restrict__ out) {
  const int row = blockIdx.x;
  const int tid = threadIdx.x;
  const int d0 = tid << 2;
  f32x4 xv = *(const f32x4*)(xin + (size_t)row * TD + d0);
  float ss = xv[0] * xv[0] + xv[1] * xv[1] + xv[2] * xv[2] + xv[3] * xv[3];
#pragma unroll
  for (int o = 32; o > 0; o >>= 1) ss += __shfl_down(ss, o);
  __shared__ float ps[4];
  __shared__ float invs;
  if ((tid & 63) == 0) ps[tid >> 6] = ss;
  __syncthreads();
  if (tid == 0) {
    float tot = ps[0] + ps[1] + ps[2] + ps[3];
    invs = 1.0f / (sqrtf(tot * (1.0f / (float)TD)) + 1e-8f);
  }
  __syncthreads();
  const float inv = invs;
  f32x4 av = *(const f32x4*)(alpha + d0);
  u16x4 ov;
#pragma unroll
  for (int j = 0; j < 4; ++j) ov[j] = f2b(av[j] * xv[j] * inv);
  *(u16x4*)(out + (size_t)row * TD + d0) = ov;
}

// ---------------- fused flash attention -----------------------------------
__global__ __launch_bounds__(512) void attn_k(
    const unsigned short* __restrict__ qkv, const unsigned short* __restrict__ vt,
    unsigned short* __restrict__ ob) {
  const int q0 = blockIdx.x << 7;
  const int bh = blockIdx.y;
  const int b = bh >> 4, h = bh & 15;
  const unsigned short* Qg = qkv + (size_t)(b * TS) * 3072 + h * 64;
  const unsigned short* Kg = Qg + 1024;
  const unsigned short* Vg = vt + (size_t)b * TD * TS + (size_t)(h * 64) * TS;

  __shared__ __attribute__((aligned(16))) unsigned short Qs[128 * 64];
  __shared__ __attribute__((aligned(16))) unsigned short Ks[128 * 64];
  __shared__ __attribute__((aligned(16))) unsigned short Vs[64 * 128];
  __shared__ __attribute__((aligned(16))) unsigned short Sb[128 * 128];
  __shared__ float mi[128], li[128], scl[128];

  const int tid = threadIdx.x, lane = tid & 63, wid = tid >> 6;
  const int lm = lane & 15, hi = lane >> 4;
  const int wm = wid >> 2, wn = wid & 3;

  if (tid < 128) { mi[tid] = -3.0e38f; li[tid] = 0.f; }

  {
    const int srow = lane >> 3, schk = lane & 7;
#pragma unroll
    for (int i = 0; i < 2; ++i) {
      const int row = wid * 16 + i * 8 + srow;
      const unsigned char* src =
          (const unsigned char*)(Qg + (size_t)(q0 + row) * 3072) +
          ((schk * 16) ^ ((srow & 7) << 4));
      glds16(src, (unsigned char*)Qs + (wid * 16 + i * 8) * 128);
    }
  }

  f32x4 acc_o[4] = {};
  const int nt = blockIdx.x + 1;

  for (int t = 0; t < nt; ++t) {
    const int kv0 = t << 7;
    {
      const int srow = lane >> 3, schk = lane & 7;
#pragma unroll
      for (int i = 0; i < 2; ++i) {
        const int row = wid * 16 + i * 8 + srow;
        const unsigned char* src =
            (const unsigned char*)(Kg + (size_t)(kv0 + row) * 3072) +
            ((schk * 16) ^ ((srow & 7) << 4));
        glds16(src, (unsigned char*)Ks + (wid * 16 + i * 8) * 128);
      }
      const int vrow4 = lane >> 4, vchk = lane & 15;
#pragma unroll
      for (int i = 0; i < 2; ++i) {
        const int row = wid * 8 + i * 4 + vrow4;
        const unsigned char* src =
            (const unsigned char*)(Vg + (size_t)row * TS + kv0) +
            ((vchk * 16) ^ ((row & 15) << 4));
        glds16(src, (unsigned char*)Vs + (wid * 8 + i * 4) * 256);
      }
    }
    asm volatile("s_waitcnt vmcnt(0)");
    __syncthreads();

    f32x4 acc_s[4][2] = {};
#pragma unroll
    for (int kk = 0; kk < 2; ++kk) {
      bf16x8 af[4], bf[2];
#pragma unroll
      for (int i = 0; i < 4; ++i) {
        const int row = wm * 64 + i * 16 + lm;
        af[i] = __builtin_bit_cast(
            bf16x8, *(const u16x8*)((const unsigned char*)Qs + row * 128 +
                                    (((kk * 4 + hi) ^ (row & 7)) << 4)));
      }
#pragma unroll
      for (int j = 0; j < 2; ++j) {
        const int row = wn * 32 + j * 16 + lm;
        bf[j] = __builtin_bit_cast(
            bf16x8, *(const u16x8*)((const unsigned char*)Ks + row * 128 +
                                    (((kk * 4 + hi) ^ (row & 7)) << 4)));
      }
#pragma unroll
      for (int i = 0; i < 4; ++i)
#pragma unroll
        for (int j = 0; j < 2; ++j)
          acc_s[i][j] = __builtin_amdgcn_mfma_f32_16x16x32_bf16(af[i], bf[j],
                                                                acc_s[i][j], 0, 0, 0);
    }
#pragma unroll
    for (int i = 0; i < 4; ++i)
#pragma unroll
      for (int j = 0; j < 2; ++j)
#pragma unroll
        for (int e = 0; e < 4; ++e) {
          const int row = wm * 64 + i * 16 + hi * 4 + e;
          const int col = wn * 32 + j * 16 + lm;
          float v = acc_s[i][j][e] * 0.125f;
          if (kv0 + col > q0 + row) v = -1e30f;
          const int chunk = (col >> 3) ^ (row & 15);
          *(unsigned short*)((unsigned char*)Sb + row * 256 + chunk * 16 +
                             ((col & 7) << 1)) = f2b(v);
        }
    __syncthreads();

    {
      const int r = tid >> 2, qt = tid & 3;
      float v[32];
      float rmax = -3.0e38f;
#pragma unroll
      for (int cc = 0; cc < 4; ++cc) {
        const int c = qt * 4 + cc;
        u16x8 pk = *(const u16x8*)((const unsigned char*)Sb + r * 256 +
                                   ((c ^ (r & 15)) << 4));
#pragma unroll
        for (int j = 0; j < 8; ++j) {
          v[cc * 8 + j] = b2f(pk[j]);
          rmax = fmaxf(rmax, v[cc * 8 + j]);
        }
      }
      rmax = fmaxf(rmax, __shfl_xor(rmax, 1));
      rmax = fmaxf(rmax, __shfl_xor(rmax, 2));
      const float mold = mi[r];
      const float mnew = fmaxf(mold, rmax);
      float lsum = 0.f;
#pragma unroll
      for (int cc = 0; cc < 4; ++cc) {
        const int c = qt * 4 + cc;
        u16x8 pk;
#pragma unroll
        for (int j = 0; j < 8; ++j) {
          float p = __expf(v[cc * 8 + j] - mnew);
          lsum += p;
          pk[j] = f2b(p);
        }
        *(u16x8*)((unsigned char*)Sb + r * 256 + ((c ^ (r & 15)) << 4)) = pk;
      }
      lsum += __shfl_xor(lsum, 1);
      lsum += __shfl_xor(lsum, 2);
      if (qt == 0) {
        const float sc = __expf(mold - mnew);
        scl[r] = sc;
        li[r] = li[r] * sc + lsum;
        mi[r] = mnew;
      }
    }
    __syncthreads();

    {
      float sc[4];
#pragma unroll
      for (int e = 0; e < 4; ++e) sc[e] = scl[wid * 16 + hi * 4 + e];
#pragma unroll
      for (int j = 0; j < 4; ++j)
#pragma unroll
        for (int e = 0; e < 4; ++e) acc_o[j][e] *= sc[e];
#pragma unroll
      for (int ks = 0; ks < 4; ++ks) {
        const int arow = wid * 16 + lm;
        bf16x8 pa = __builtin_bit_cast(
            bf16x8, *(const u16x8*)((const unsigned char*)Sb + arow * 256 +
                                    (((ks * 4 + hi) ^ (arow & 15)) << 4)));
#pragma unroll
        for (int j = 0; j < 4; ++j) {
          const int drow = j * 16 + lm;
          bf16x8 vb = __builtin_bit_cast(
              bf16x8, *(const u16x8*)((const unsigned char*)Vs + drow * 256 +
                                      (((ks * 4 + hi) ^ (drow & 15)) << 4)));
          acc_o[j] = __builtin_amdgcn_mfma_f32_16x16x32_bf16(pa, vb, acc_o[j], 0, 0, 0);
        }
      }
    }
    __syncthreads();
  }

  float il[4];
#pragma unroll
  for (int e = 0; e < 4; ++e) il[e] = 1.0f / li[wid * 16 + hi * 4 + e];
#pragma unroll
  for (int j = 0; j < 4; ++j)
#pragma unroll
    for (int e = 0; e < 4; ++e) {
      const int row = q0 + wid * 16 + hi * 4 + e;
      const int col = h * 64 + j * 16 + lm;
      ob[(size_t)(b * TS + row) * TD + col] = f2b(acc_o[j][e] * il[e]);
    }
}

// ---------------- old f32->bf16 softmax (fallback path) ----------------
__global__ __launch_bounds__(256) void softmax_k(const float* __restrict__ Pf,
                                                 unsigned short* __restrict__ Pb) {
  const int r = blockIdx.x;
  const int valid = (r & (TS - 1)) + 1;
  const int tid = threadIdx.x;
  const float* row = Pf + (size_t)r * TS;
  unsigned short* orow = Pb + (size_t)r * TS;
  float vals[4];
  float lmax = -1e30f;
#pragma unroll
  for (int it = 0; it < 4; ++it) {
    int i = it * 256 + tid;
    float v = (i < valid) ? row[i] : -1e30f;
    vals[it] = v;
    lmax = fmaxf(lmax, v);
  }
#pragma unroll
  for (int o = 32; o > 0; o >>= 1) lmax = fmaxf(lmax, __shfl_down(lmax, o));
  __shared__ float ps[4];
  __shared__ float bcast;
  if ((tid & 63) == 0) ps[tid >> 6] = lmax;
  __syncthreads();
  if (tid == 0) bcast = fmaxf(fmaxf(ps[0], ps[1]), fmaxf(ps[2], ps[3]));
  __syncthreads();
  const float m = bcast;
  float lsum = 0.f;
#pragma unroll
  for (int it = 0; it < 4; ++it) {
    int i = it * 256 + tid;
    float e = (i < valid) ? __expf((vals[it] - m) * 0.125f) : 0.f;
    vals[it] = e;
    lsum += e;
  }
#pragma unroll
  for (int o = 32; o > 0; o >>= 1) lsum += __shfl_down(lsum, o);
  __syncthreads();
  if ((tid & 63) == 0) ps[tid >> 6] = lsum;
  __syncthreads();
  if (tid == 0) bcast = 1.0f / (ps[0] + ps[1] + ps[2] + ps[3]);
  __syncthreads();
  const float inv = bcast;
#pragma unroll
  for (int it = 0; it < 4; ++it) {
    int i = it * 256 + tid;
    orow[i] = f2b(vals[it] * inv);
  }
}

// ---------------- log_softmax over V, in place (fallback path) -------------
__global__ __launch_bounds__(256) void logsoftmax_k(float* __restrict__ logits) {
  const int r = blockIdx.x;
  float* row = logits + (size_t)r * TV;
  const int tid = threadIdx.x;
  float m = -1e30f, s = 0.f;
  for (int i = tid * 4; i < TV; i += 1024) {
    f32x4 v = *(const f32x4*)(row + i);
#pragma unroll
    for (int j = 0; j < 4; ++j) {
      float xv = v[j];
      if (xv > m) { s = s * __expf(m - xv) + 1.f; m = xv; }
      else s += __expf(xv - m);
    }
  }
#pragma unroll
  for (int o = 32; o > 0; o >>= 1) {
    float mo = __shfl_down(m, o);
    float so = __shfl_down(s, o);
    float M = fmaxf(m, mo);
    s = s * __expf(m - M) + so * __expf(mo - M);
    m = M;
  }
  __shared__ float pm[4], psv[4];
  __shared__ float blse;
  if ((tid & 63) == 0) { pm[tid >> 6] = m; psv[tid >> 6] = s; }
  __syncthreads();
  if (tid == 0) {
    float M = fmaxf(fmaxf(pm[0], pm[1]), fmaxf(pm[2], pm[3]));
    float S = psv[0] * __expf(pm[0] - M) + psv[1] * __expf(pm[1] - M) +
              psv[2] * __expf(pm[2] - M) + psv[3] * __expf(pm[3] - M);
    blse = M + logf(S);
  }
  __syncthreads();
  const float lse = blse;
  for (int i = tid * 4; i < TV; i += 1024) {
    f32x4 v = *(const f32x4*)(row + i);
    v[0] -= lse; v[1] -= lse; v[2] -= lse; v[3] -= lse;
    *(f32x4*)(row + i) = v;
  }
}

// ---------------- final: LSE from reg-buffered bf16 row; write f32 ---------
__global__ __launch_bounds__(1024) void lse_final_k(
    float* __restrict__ out, const unsigned short* __restrict__ lb) {
  const int r = blockIdx.x;
  const int tid = threadIdx.x;
  const unsigned short* row = lb + (size_t)r * 64000 + 32000;
  u16x4 buf[8];
#pragma unroll
  for (int i = 0; i < 8; ++i) {
    const int e = tid * 4 + i * 4096;
    if (e < TV) buf[i] = *(const u16x4*)(row + e);
  }
  float m = -1e30f;
#pragma unroll
  for (int i = 0; i < 8; ++i) {
    const int e = tid * 4 + i * 4096;
    if (e < TV) {
#pragma unroll
      for (int j = 0; j < 4; ++j) m = fmaxf(m, b2f(buf[i][j]));
    }
  }
  float s = 0.f;
#pragma unroll
  for (int i = 0; i < 8; ++i) {
    const int e = tid * 4 + i * 4096;
    if (e < TV) {
#pragma unroll
      for (int j = 0; j < 4; ++j) s += __expf(b2f(buf[i][j]) - m);
    }
  }
#pragma unroll
  for (int o = 32; o > 0; o >>= 1) {
    float mo = __shfl_xor(m, o);
    float so = __shfl_xor(s, o);
    float M = fmaxf(m, mo);
    s = s * __expf(m - M) + so * __expf(mo - M);
    m = M;
  }
  __shared__ float pm[16], psv[16];
  __shared__ float blse;
  if ((tid & 63) == 0) { pm[tid >> 6] = m; psv[tid >> 6] = s; }
  __syncthreads();
  if (tid == 0) {
    float M = pm[0];
#pragma unroll
    for (int w = 1; w < 16; ++w) M = fmaxf(M, pm[w]);
    float S = 0.f;
#pragma unroll
    for (int w = 0; w < 16; ++w) S += psv[w] * __expf(pm[w] - M);
    blse = M + logf(S);
  }
  __syncthreads();
  const float lse = blse;
  float* orow = out + (size_t)r * TV;
#pragma unroll
  for (int i = 0; i < 8; ++i) {
    const int e = tid * 4 + i * 4096;
    if (e < TV) {
      f32x4 v;
#pragma unroll
      for (int j = 0; j < 4; ++j) v[j] = b2f(buf[i][j]) - lse;
      *(f32x4*)(orow + e) = v;
    }
  }
}

// ---------------- weight transpose+convert: [K,N] f32 -> [N,K] bf16 --------
struct TEnt { const float* s; unsigned short* d; int K; int N; int t0; };
struct TTab { TEnt e[13]; };

__global__ __launch_bounds__(256) void transpose_all_k(TTab tab) {
  const int bid = blockIdx.x;
  int mi = 0;
#pragma unroll
  for (int i = 1; i < 13; ++i)
    if (bid >= tab.e[i].t0) mi = i;
  const TEnt E = tab.e[mi];
  const int lt = bid - E.t0;
  const int ntn = E.N >> 6;
  const int kt = lt / ntn, nt = lt - kt * ntn;
  const int k0 = kt << 6, n0 = nt << 6;
  __shared__ unsigned short t[64][68];
  const int tid = threadIdx.x;
  const int cr = tid >> 4, cc = (tid & 15) << 2;
#pragma unroll
  for (int it = 0; it < 4; ++it) {
    const int kl = it * 16 + cr;
    f32x4 v = *(const f32x4*)(E.s + (size_t)(k0 + kl) * E.N + n0 + cc);
    u16x4 o;
#pragma unroll
    for (int j = 0; j < 4; ++j) o[j] = f2b(v[j]);
    *(u16x4*)&t[kl][cc] = o;
  }
  __syncthreads();
  const int nl = tid & 63, kc = (tid >> 6) << 4;
  u16x8 r0, r1;
#pragma unroll
  for (int j = 0; j < 8; ++j) { r0[j] = t[kc + j][nl]; r1[j] = t[kc + 8 + j][nl]; }
  unsigned short* dp = E.d + (size_t)(n0 + nl) * E.K + k0 + kc;
  *(u16x8*)dp = r0;
  *(u16x8*)(dp + 8) = r1;
}

// ---------------- V slice transpose: qkv[:,2048+d] -> vt[b][d][s] ----------
__global__ __launch_bounds__(256) void vtrans_k(const unsigned short* __restrict__ qkv,
                                                unsigned short* __restrict__ vt) {
  const int d0 = blockIdx.x << 6, s0 = blockIdx.y << 6, b = blockIdx.z;
  __shared__ unsigned short t[64][68];
  const int tid = threadIdx.x;
  const int cr = tid >> 4, cc = (tid & 15) << 2;
#pragma unroll
  for (int it = 0; it < 4; ++it) {
    const int sl = it * 16 + cr;
    u16x4 v = *(const u16x4*)(qkv + (size_t)(b * TS + s0 + sl) * 3072 + 2048 + d0 + cc);
    *(u16x4*)&t[sl][cc] = v;
  }
  __syncthreads();
  const int dl = tid & 63, sc = (tid >> 6) << 4;
  u16x8 r0, r1;
#pragma unroll
  for (int j = 0; j < 8; ++j) { r0[j] = t[sc + j][dl]; r1[j] = t[sc + 8 + j][dl]; }
  unsigned short* dp = vt + (size_t)b * TD * TS + (size_t)(d0 + dl) * TS + s0 + sc;
  *(u16x8*)dp = r0;
  *(u16x8*)(dp + 8) = r1;
}

// ---------------- pipelined 256x256 GEMM (projection) ----------------------
// A:[M,K] bf16, B:[N,K] bf16, C:[M,N] bf16 (+bias). 512 thr = 8 waves (2Mx4N).
// LDS ring: 8 quarter-slots x 16KB; tile kt uses slots {0-3} or {4-7};
// staging targets the other half. Per K-tile (2 barriers):
//   stage(2q) ; VMW(4) [uniform — drains ALL own tile-kt glds; last tile 0]
//   BAR ; issue 24 ds_read (kk0+kk1) ; MFMA kk0 x32 (kk1 reads return under it)
//   stage(2q) ; MFMA kk1 x32 ; BAR.
// Safety: reads touch current half only; stages touch other half; the other
// half's prior readers drained via lgkm-before-MFMA(kk1) preceding trailing
// barrier of the prior tile.
__global__ __launch_bounds__(512, 2) void gemm8p_k(
    const unsigned short* __restrict__ A, int lda,
    const unsigned short* __restrict__ B, int ldb,
    unsigned short* __restrict__ C, long long ldc,
    const float* __restrict__ bias, int K) {
  extern __shared__ __attribute__((aligned(16))) char smem[];
  const int NT = K >> 6;
  int bx = blockIdx.x, by = blockIdx.y;
  {
    const int nwg = gridDim.x * gridDim.y;
    const int bid = by * gridDim.x + bx;
    const int q = nwg >> 3, rr = nwg & 7;
    const int xcd = bid & 7, idx = bid >> 3;
    const int nid = (xcd < rr ? xcd * (q + 1) : rr * (q + 1) + (xcd - rr) * q) + idx;
    bx = nid % gridDim.x;
    by = nid / gridDim.x;
  }
  const int m0 = bx * 256, n0 = by * 256;
  const int tid = threadIdx.x, lane = tid & 63, wid = tid >> 6;
  const int wm = wid >> 2, wn = wid & 3;
  const int lm = lane & 15, hi = lane >> 4;
  const int srow = lane >> 3, schk = lane & 7;
  const int axor = (lm & 7) << 4;
  const int swz = (schk * 16) ^ ((srow & 7) << 4);
  const int rb = (wn & 1) * 64;

  const char* srcA = (const char*)(A + (size_t)(m0 + wid * 8 + srow) * lda) + swz;
  const char* srcB = (const char*)(B + (size_t)(n0 + wid * 8 + srow) * ldb) + swz;
  char* dstW = smem + wid * 8 * 128;

  auto stage_q = [&](int q) {
    const int kt_t = q >> 2, jj = q & 3;
    char* d = dstW + (q & 7) * 16384;
    if (jj < 2) {
      const char* s = srcB + ((size_t)(jj * 128) * ldb + (size_t)kt_t * 64) * 2;
      glds16(s, d);
      glds16(s + (size_t)64 * ldb * 2, d + 64 * 128);
    } else {
      const char* s = srcA + ((size_t)((jj - 2) * 128) * lda + (size_t)kt_t * 64) * 2;
      glds16(s, d);
      glds16(s + (size_t)64 * lda * 2, d + 64 * 128);
    }
  };

  // prologue: tile 0's quarters
  stage_q(0); stage_q(1); stage_q(2); stage_q(3);

  f32x4 acc[8][4] = {};

  for (int kt = 0; kt < NT; ++kt) {
    const char* ta = smem + ((kt & 1) * 4 + 2 + wm) * 16384;
    const char* tb = smem + ((kt & 1) * 4 + (wn >> 1)) * 16384;
    const bool more = (kt + 1 < NT);
    bf16x8 b0[4], a0[8], b1[4], a1[8];

    if (more) { stage_q(4 * kt + 4); stage_q(4 * kt + 5); }
    if (more) { VMW(4); } else { VMW(0); }
    BARX;
    // all 24 reads issued up front; compiler's partial lgkm lets kk0 MFMAs
    // start while kk1 reads are still returning.
#pragma unroll
    for (int j = 0; j < 4; ++j)
      b0[j] = __builtin_bit_cast(
          bf16x8, *(const u16x8*)(tb + (rb + j * 16 + lm) * 128 + ((hi * 16) ^ axor)));
#pragma unroll
    for (int i = 0; i < 8; ++i)
      a0[i] = __builtin_bit_cast(
          bf16x8, *(const u16x8*)(ta + (i * 16 + lm) * 128 + ((hi * 16) ^ axor)));
#pragma unroll
    for (int j = 0; j < 4; ++j)
      b1[j] = __builtin_bit_cast(
          bf16x8,
          *(const u16x8*)(tb + (rb + j * 16 + lm) * 128 + ((64 + hi * 16) ^ axor)));
#pragma unroll
    for (int i = 0; i < 8; ++i)
      a1[i] = __builtin_bit_cast(
          bf16x8, *(const u16x8*)(ta + (i * 16 + lm) * 128 + ((64 + hi * 16) ^ axor)));
    __builtin_amdgcn_s_setprio(1);
#pragma unroll
    for (int i = 0; i < 8; ++i)
#pragma unroll
      for (int j = 0; j < 4; ++j)
        acc[i][j] = __builtin_amdgcn_mfma_f32_16x16x32_bf16(a0[i], b0[j],
                                                            acc[i][j], 0, 0, 0);
    __builtin_amdgcn_s_setprio(0);
    if (more) { stage_q(4 * kt + 6); stage_q(4 * kt + 7); }
    __builtin_amdgcn_s_setprio(1);
#pragma unroll
    for (int i = 0; i < 8; ++i)
#pragma unroll
      for (int j = 0; j < 4; ++j)
        acc[i][j] = __builtin_amdgcn_mfma_f32_16x16x32_bf16(a1[i], b1[j],
                                                            acc[i][j], 0, 0, 0);
    __builtin_amdgcn_s_setprio(0);
    BARX;
  }

  // ---- epilogue ----
#pragma unroll
  for (int mi = 0; mi < 8; ++mi)
#pragma unroll
    for (int j = 0; j < 4; ++j) {
      const int col = n0 + wn * 64 + j * 16 + lm;
      const float bv = bias[col];
#pragma unroll
      for (int e = 0; e < 4; ++e) {
        const long long row = m0 + wm * 128 + mi * 16 + hi * 4 + e;
        C[row * ldc + col] = f2b(acc[mi][j][e] + bv);
      }
    }
}

// ---------------- GEMM: A,B bf16 [*,K]; global_load_lds; opt. XCD swizzle --
template <int BM_, int BN, typename OT, bool HB, bool HS, bool HR, bool CSKIP,
          bool CAUSA, bool GSWAP, bool XSWZ, bool DBUF>
__global__ __launch_bounds__(256) void gemm2_k(
    const unsigned short* __restrict__ A, int lda, long long sAo, long long sAi, int iA,
    const unsigned short* __restrict__ B, int ldb, long long sBo, long long sBi, int iB,
    OT* __restrict__ C, int ldc, long long sCo, long long sCi, int iC,
    const float* __restrict__ bias, const float* __restrict__ res, int K) {
  constexpr int WN = BN / 2;
  constexpr int FN = WN / 16;
  constexpr int FM = BM_ / 32;
  constexpr int NB = DBUF ? 2 : 1;
  int bx = blockIdx.x, by = blockIdx.y;
  if constexpr (XSWZ) {
    const int nwg = gridDim.x * gridDim.y;
    const int bid = by * gridDim.x + bx;
    const int q = nwg >> 3, rr = nwg & 7;
    const int xcd = bid & 7, idx = bid >> 3;
    const int nid = (xcd < rr ? xcd * (q + 1) : rr * (q + 1) + (xcd - rr) * q) + idx;
    bx = nid % gridDim.x;
    by = nid / gridDim.x;
  }
  const int m0 = (GSWAP ? bx : by) * BM_;
  const int n0 = (GSWAP ? by : bx) * BN;
  if (CSKIP && n0 > m0 + BM_ - 1) return;
  const int bz = blockIdx.z;
  A += (long long)(bz / iA) * sAo + (long long)(bz % iA) * sAi;
  B += (long long)(bz / iB) * sBo + (long long)(bz % iB) * sBi;
  C += (long long)(bz / iC) * sCo + (long long)(bz % iC) * sCi;

  __shared__ __attribute__((aligned(16))) unsigned short As[NB][BM_ * 64];
  __shared__ __attribute__((aligned(16))) unsigned short Bs[NB][BN * 64];

  const int tid = threadIdx.x, lane = tid & 63, wid = tid >> 6;
  const int wm = wid >> 1, wn = wid & 1;
  const int lm = lane & 15, hi = lane >> 4;

  const int srow = lane >> 3, schk = lane & 7;
  const int sxor = (srow & 7) << 4;
  const unsigned char* AgB =
      (const unsigned char*)(A + (size_t)(m0 + wid * (BM_ / 4) + srow) * lda) +
      ((schk * 16) ^ sxor);
  const unsigned char* BgB =
      (const unsigned char*)(B + (size_t)(n0 + wid * (BN / 4) + srow) * ldb) +
      ((schk * 16) ^ sxor);
  const size_t ldab = (size_t)lda * 2, ldbb = (size_t)ldb * 2;

  auto stage = [&](int kb, int bi) {
#pragma unroll
    for (int i = 0; i < BM_ / 32; ++i)
      glds16(AgB + kb + (size_t)i * 8 * ldab,
             (unsigned char*)As[bi] + wid * (BM_ / 4) * 128 + i * 1024);
#pragma unroll
    for (int i = 0; i < BN / 32; ++i)
      glds16(BgB + kb + (size_t)i * 8 * ldbb,
             (unsigned char*)Bs[bi] + wid * (BN / 4) * 128 + i * 1024);
  };

  f32x4 acc[FM][FN] = {};
  const int kend = CAUSA ? ((K < m0 + BM_) ? K : m0 + BM_) : K;
  const int axor = (lm & 7) << 4;

  int cur = 0;
  if constexpr (DBUF) {
    stage(0, 0);
    __syncthreads();
  }
  for (int k0 = 0; k0 < kend; k0 += 64) {
    if constexpr (DBUF) {
      if (k0 + 64 < kend) stage((k0 + 64) * 2, cur ^ 1);
    } else {
      stage(k0 * 2, 0);
      __syncthreads();
    }
    const unsigned char* AsP = (const unsigned char*)As[DBUF ? cur : 0];
    const unsigned char* BsP = (const unsigned char*)Bs[DBUF ? cur : 0];
#pragma unroll
    for (int kk = 0; kk < 2; ++kk) {
      const int kb = (kk * 64 + hi * 16) ^ axor;
      bf16x8 af[FM], bfr[FN];
#pragma unroll
      for (int i = 0; i < FM; ++i)
        af[i] = __builtin_bit_cast(
            bf16x8, *(const u16x8*)(AsP + (wm * (BM_ / 2) + i * 16 + lm) * 128 + kb));
#pragma unroll
      for (int j = 0; j < FN; ++j)
        bfr[j] = __builtin_bit_cast(
            bf16x8, *(const u16x8*)(BsP + (wn * WN + j * 16 + lm) * 128 + kb));
#pragma unroll
      for (int i = 0; i < FM; ++i)
#pragma unroll
        for (int j = 0; j < FN; ++j)
          acc[i][j] = __builtin_amdgcn_mfma_f32_16x16x32_bf16(af[i], bfr[j],
                                                              acc[i][j], 0, 0, 0);
    }
    __syncthreads();
    cur ^= 1;
  }

#pragma unroll
  for (int i = 0; i < FM; ++i) {
    const int rbase = m0 + wm * (BM_ / 2) + i * 16 + (hi << 2);
#pragma unroll
    for (int j = 0; j < FN; ++j) {
      const int c = n0 + wn * WN + j * 16 + lm;
      const float bval = HB ? bias[c] : 0.f;
#pragma unroll
      for (int e = 0; e < 4; ++e) {
        float v = acc[i][j][e];
        if (HB) v += bval;
        if (HS) v = v / (1.f + __expf(-v));
        const long long off = (long long)(rbase + e) * ldc + c;
        if (HR) v += res[off];
        if constexpr (std::is_same_v<OT, float>) C[off] = v;
        else C[off] = f2b(v);
      }
    }
  }
}

// ---------------- old GEMM (round-1, fallback path) ----------------
template <int BN, typename BT, bool BNK, typename OT, bool HB, bool HS, bool HR,
          bool CSKIP, bool CAUSA>
__global__ __launch_bounds__(256) void gemm_k(
    const unsigned short* __restrict__ A, int lda, long long sAo, long long sAi, int iA,
    const BT* __restrict__ Bg, int ldb, long long sBo, long long sBi, int iB,
    OT* __restrict__ Cg, int ldc, long long sCo, long long sCi, int iC,
    const float* __restrict__ bias, const float* __restrict__ res, int K) {
  constexpr int WN = BN / 2;
  constexpr int FN = WN / 16;
  constexpr int FM = 4;
  const int m0 = blockIdx.y * BM;
  const int n0 = blockIdx.x * BN;
  if (CSKIP && n0 > m0 + BM - 1) return;
  const int bz = blockIdx.z;
  A  += (long long)(bz / iA) * sAo + (long long)(bz % iA) * sAi;
  Bg += (long long)(bz / iB) * sBo + (long long)(bz % iB) * sBi;
  Cg += (long long)(bz / iC) * sCo + (long long)(bz % iC) * sCi;

  __shared__ __attribute__((aligned(16))) unsigned short As[BM * BKP];
  __shared__ __attribute__((aligned(16))) unsigned short Bs[BN * BKP];

  const int tid = threadIdx.x;
  const int lane = tid & 63;
  const int wid = tid >> 6;
  const int wm = wid >> 1, wn = wid & 1;
  const int lm = lane & 15;
  const int lk = (lane >> 4) << 3;

  f32x4 acc[FM][FN] = {};
  const int kend = CAUSA ? ((K < m0 + BM) ? K : m0 + BM) : K;

  for (int k0 = 0; k0 < kend; k0 += BK) {
#pragma unroll
    for (int it = 0; it < (BM * BK / 8) / 256; ++it) {
      int idx = it * 256 + tid;
      int rowa = idx >> 3;
      int kc = (idx & 7) << 3;
      u16x8 av = *(const u16x8*)(A + (size_t)(m0 + rowa) * lda + (k0 + kc));
      *(u16x8*)&As[rowa * BKP + kc] = av;
    }
    if constexpr (BNK) {
#pragma unroll
      for (int it = 0; it < (BN * BK / 8) / 256; ++it) {
        int idx = it * 256 + tid;
        int rowb = idx >> 3;
        int kc = (idx & 7) << 3;
        u16x8 bv = *(const u16x8*)((const unsigned short*)Bg +
                                   (size_t)(n0 + rowb) * ldb + (k0 + kc));
        *(u16x8*)&Bs[rowb * BKP + (kc ^ (((rowb >> 3) & 7) << 3))] = bv;
      }
    } else {
      constexpr int NCH = BN / 8;
#pragma unroll
      for (int it = 0; it < (BK * NCH) / 256; ++it) {
        int idx = it * 256 + tid;
        int nc = (idx & (NCH - 1)) << 3;
        int kr = idx / NCH;
        unsigned short ub[8];
        if constexpr (std::is_same_v<BT, float>) {
          const float* bp = Bg + (size_t)(k0 + kr) * ldb + (n0 + nc);
          f32x4 b0 = *(const f32x4*)bp;
          f32x4 b1 = *(const f32x4*)(bp + 4);
#pragma unroll
          for (int j = 0; j < 4; ++j) { ub[j] = f2b(b0[j]); ub[4 + j] = f2b(b1[j]); }
        } else {
          const unsigned short* bp =
              (const unsigned short*)Bg + (size_t)(k0 + kr) * ldb + (n0 + nc);
          u16x8 raw = *(const u16x8*)bp;
#pragma unroll
          for (int j = 0; j < 8; ++j) ub[j] = raw[j];
        }
        const int sw = ((nc >> 3) & 7) << 3;
#pragma unroll
        for (int j = 0; j < 8; ++j) Bs[(nc + j) * BKP + (kr ^ sw)] = ub[j];
      }
    }
    __syncthreads();
#pragma unroll
    for (int kk = 0; kk < 2; ++kk) {
      bf16x8 af[FM];
      bf16x8 bfr[FN];
#pragma unroll
      for (int i = 0; i < FM; ++i)
        af[i] = __builtin_bit_cast(
            bf16x8, *(const u16x8*)&As[(wm * 64 + i * 16 + lm) * BKP + (kk * 32 + lk)]);
#pragma unroll
      for (int j = 0; j < FN; ++j) {
        const int nr = wn * WN + j * 16 + lm;
        bfr[j] = __builtin_bit_cast(
            bf16x8,
            *(const u16x8*)&Bs[nr * BKP + ((kk * 32 + lk) ^ (((nr >> 3) & 7) << 3))]);
      }
#pragma unroll
      for (int i = 0; i < FM; ++i)
#pragma unroll
        for (int j = 0; j < FN; ++j)
          acc[i][j] = __builtin_amdgcn_mfma_f32_16x16x32_bf16(af[i], bfr[j],
                                                              acc[i][j], 0, 0, 0);
    }
    __syncthreads();
  }

#pragma unroll
  for (int i = 0; i < FM; ++i) {
    const int rbase = m0 + wm * 64 + i * 16 + ((lane >> 4) << 2);
#pragma unroll
    for (int j = 0; j < FN; ++j) {
      const int c = n0 + wn * WN + j * 16 + lm;
      const float bval = HB ? bias[c] : 0.f;
#pragma unroll
      for (int e = 0; e < 4; ++e) {
        float v = acc[i][j][e];
        if (HB) v += bval;
        if (HS) v = v / (1.f + __expf(-v));
        const long long off = (long long)(rbase + e) * ldc + c;
        if (HR) v += res[off];
        if constexpr (std::is_same_v<OT, float>) Cg[off] = v;
        else Cg[off] = f2b(v);
      }
    }
  }
}

// ---------------------------------------------------------------------------
extern "C" void kernel_launch(void* const* d_in, const int* in_sizes, int n_in,
                              void* d_out, int out_size, void* d_ws, size_t ws_size,
                              hipStream_t stream) {
  const int*   tok = (const int*)d_in[0];
  const float* emb = (const float*)d_in[2];
  const float* Wq  = (const float*)d_in[3];
  const float* Wk  = (const float*)d_in[4];
  const float* Wv  = (const float*)d_in[5];
  const float* Wo  = (const float*)d_in[6];
  const float* al1 = (const float*)d_in[7];
  const float* al3 = (const float*)d_in[8];
  const float* W1  = (const float*)d_in[9];
  const float* b1  = (const float*)d_in[10];
  const float* W2  = (const float*)d_in[11];
  const float* b2  = (const float*)d_in[12];
  const float* alf = (const float*)d_in[13];
  const float* Wp  = (const float*)d_in[14];
  const float* bp  = (const float*)d_in[15];

  char* ws = (char*)d_ws;
  dim3 blk(256);

  const size_t NEED = 166199296ULL;
  if (ws_size >= NEED) {
    // ---------------- new path ----------------
    float* x           = (float*)(ws);                        // 8 MB
    unsigned short* nb = (unsigned short*)(ws + 8388608);     // 4 MB
    unsigned short* qkv= (unsigned short*)(ws + 12582912);    // 12 MB [2048,3072]
    unsigned short* vt = (unsigned short*)(ws + 25165824);    // 4 MB  [B][D][S]
    unsigned short* ob = (unsigned short*)(ws + 29360128);    // 4 MB
    unsigned short* f1b= (unsigned short*)(ws + 33554432);    // 16 MB [2048,4096]
    unsigned short* wqkvT = (unsigned short*)(ws + 50331648); // 12 MB
    unsigned short* woT   = (unsigned short*)(ws + 62914560); // 4 MB
    unsigned short* w1T   = (unsigned short*)(ws + 67108864); // 16 MB
    unsigned short* w2T   = (unsigned short*)(ws + 83886080); // 16 MB
    unsigned short* wpT   = (unsigned short*)(ws + 100663296);// 62.5 MB
    // bf16 logits: second half of each f32 row slot in d_out
    unsigned short* lgb = (unsigned short*)d_out + 32000;     // ldc=64000

    hipFuncSetAttribute((const void*)gemm8p_k,
                        hipFuncAttributeMaxDynamicSharedMemorySize, 131072);

    TTab tab;
    const int M1 = 1048576;
    tab.e[0]  = {Wq,           wqkvT,               1024, 1024, 0};
    tab.e[1]  = {Wk,           wqkvT + M1,          1024, 1024, 256};
    tab.e[2]  = {Wv,           wqkvT + 2 * M1,      1024, 1024, 512};
    tab.e[3]  = {Wq + M1,      wqkvT + 3 * M1,      1024, 1024, 768};
    tab.e[4]  = {Wk + M1,      wqkvT + 4 * M1,      1024, 1024, 1024};
    tab.e[5]  = {Wv + M1,      wqkvT + 5 * M1,      1024, 1024, 1280};
    tab.e[6]  = {Wo,           woT,                 1024, 1024, 1536};
    tab.e[7]  = {Wo + M1,      woT + M1,            1024, 1024, 1792};
    tab.e[8]  = {W1,           w1T,                 1024, 4096, 2048};
    tab.e[9]  = {W1 + 4 * M1,  w1T + 4 * M1,        1024, 4096, 3072};
    tab.e[10] = {W2,           w2T,                 4096, 1024, 4096};
    tab.e[11] = {W2 + 4 * M1,  w2T + 4 * M1,        4096, 1024, 5120};
    tab.e[12] = {Wp,           wpT,                 1024, 32000, 6144};
    transpose_all_k<<<14144, blk, 0, stream>>>(tab);

    // fused embedding + posenc + layer-0 RMS
    embed_rms_k<<<TB * TS, blk, 0, stream>>>(tok, emb, al1, x, nb);

    for (int l = 0; l < TL; ++l) {
      if (l > 0) rms_k<<<TB * TS, blk, 0, stream>>>(x, al1 + (size_t)l * TD, nb);

      // fused QKV: [2048,1024] x [3072,1024]^T -> qkv [2048,3072] (BM=64)
      gemm2_k<64, 128, unsigned short, false, false, false, false, false, false, true, false>
          <<<dim3(24, 32, 1), blk, 0, stream>>>(
              nb, TD, 0, 0, 1, wqkvT + (size_t)l * 3 * M1, TD, 0, 0, 1,
              qkv, 3072, 0, 0, 1, nullptr, nullptr, TD);

      vtrans_k<<<dim3(16, 16, TB), blk, 0, stream>>>(qkv, vt);

      // fused flash attention: QK^T + online softmax + PV
      attn_k<<<dim3(8, TB * TH), dim3(512), 0, stream>>>(qkv, vt, ob);

      // x += O @ Wo  (64x64, 512 blk, 2-phase dbuf)
      gemm2_k<64, 64, float, false, false, true, false, false, false, true, true>
          <<<dim3(16, 32, 1), blk, 0, stream>>>(
              ob, TD, 0, 0, 1, woT + (size_t)l * M1, TD, 0, 0, 1,
              x, TD, 0, 0, 1, nullptr, x, TD);

      rms_k<<<TB * TS, blk, 0, stream>>>(x, al3 + (size_t)l * TD, nb);

      // f1 = silu(n @ W1 + b1)  (64x128, 1024 blk)
      gemm2_k<64, 128, unsigned short, true, true, false, false, false, false, true, false>
          <<<dim3(32, 32, 1), blk, 0, stream>>>(
              nb, TD, 0, 0, 1, w1T + (size_t)l * 4 * M1, TD, 0, 0, 1,
              f1b, TDFF, 0, 0, 1, b1 + (size_t)l * TDFF, nullptr, TD);

      // x += f1 @ W2 + b2  (64x64, 512 blk, 2-phase dbuf)
      gemm2_k<64, 64, float, true, false, true, false, false, false, true, true>
          <<<dim3(16, 32, 1), blk, 0, stream>>>(
              f1b, TDFF, 0, 0, 1, w2T + (size_t)l * 4 * M1, TDFF, 0, 0, 1,
              x, TD, 0, 0, 1, b2 + (size_t)l * TD, x, TDFF);
    }

    rms_k<<<TB * TS, blk, 0, stream>>>(x, alf, nb);

    // logits (bf16, colocated) = n @ Wp + bp : pipelined 256x256 kernel
    gemm8p_k<<<dim3(8, 125, 1), dim3(512), 131072, stream>>>(
        nb, TD, wpT, TD, lgb, 64000, bp, TD);

    lse_final_k<<<TB * TS, dim3(1024), 0, stream>>>(
        (float*)d_out, (const unsigned short*)d_out);
    return;
  }

  // ---------------- fallback: round-1 path ----------------
  {
    float* x            = (float*)(ws);
    unsigned short* nb  = (unsigned short*)(ws + 8388608);
    unsigned short* qb  = (unsigned short*)(ws + 12582912);
    unsigned short* kb  = (unsigned short*)(ws + 16777216);
    unsigned short* vb  = (unsigned short*)(ws + 20971520);
    unsigned short* ob  = (unsigned short*)(ws + 25165824);
    unsigned short* f1b = (unsigned short*)(ws + 29360128);
    float* Pf = (float*)d_out;
    unsigned short* Pb = (unsigned short*)d_out + 67108864LL;

    embed_pe_k<<<TB * TS, blk, 0, stream>>>(tok, emb, x);
    for (int l = 0; l < TL; ++l) {
      const float* Wq_l = Wq + (size_t)l * TD * TD;
      const float* Wk_l = Wk + (size_t)l * TD * TD;
      const float* Wv_l = Wv + (size_t)l * TD * TD;
      const float* Wo_l = Wo + (size_t)l * TD * TD;
      const float* W1_l = W1 + (size_t)l * TD * TDFF;
      const float* W2_l = W2 + (size_t)l * TDFF * TD;

      rms_k<<<TB * TS, blk, 0, stream>>>(x, al1 + (size_t)l * TD, nb);
      gemm_k<128, float, false, unsigned short, false, false, false, false, false>
          <<<dim3(TD / 128, (TB * TS) / BM, 1), blk, 0, stream>>>(
              nb, TD, 0, 0, 1, Wq_l, TD, 0, 0, 1, qb, TD, 0, 0, 1, nullptr, nullptr, TD);
      gemm_k<128, float, false, unsigned short, false, false, false, false, false>
          <<<dim3(TD / 128, (TB * TS) / BM, 1), blk, 0, stream>>>(
              nb, TD, 0, 0, 1, Wk_l, TD, 0, 0, 1, kb, TD, 0, 0, 1, nullptr, nullptr, TD);
      gemm_k<128, float, false, unsigned short, false, false, false, false, false>
          <<<dim3(TD / 128, (TB * TS) / BM, 1), blk, 0, stream>>>(
              nb, TD, 0, 0, 1, Wv_l, TD, 0, 0, 1, vb, TD, 0, 0, 1, nullptr, nullptr, TD);
      gemm_k<128, unsigned short, true, float, false, false, false, true, false>
          <<<dim3(TS / 128, TS / 128, TB * TH), blk, 0, stream>>>(
              qb, TD, (long long)TS * TD, THD, TH,
              kb, TD, (long long)TS * TD, THD, TH,
              Pf, TS, (long long)TS * TS, 0, 1, nullptr, nullptr, THD);
      softmax_k<<<TB * TH * TS, blk, 0, stream>>>(Pf, Pb);
      gemm_k<64, unsigned short, false, unsigned short, false, false, false, false, true>
          <<<dim3(1, TS / 128, TB * TH), blk, 0, stream>>>(
              Pb, TS, (long long)TS * TS, 0, 1,
              vb, TD, (long long)TS * TD, THD, TH,
              ob, TD, (long long)TS * TD, THD, TH, nullptr, nullptr, TS);
      gemm_k<128, float, false, float, false, false, true, false, false>
          <<<dim3(TD / 128, (TB * TS) / BM, 1), blk, 0, stream>>>(
              ob, TD, 0, 0, 1, Wo_l, TD, 0, 0, 1, x, TD, 0, 0, 1, nullptr, x, TD);
      rms_k<<<TB * TS, blk, 0, stream>>>(x, al3 + (size_t)l * TD, nb);
      gemm_k<128, float, false, unsigned short, true, true, false, false, false>
          <<<dim3(TDFF / 128, (TB * TS) / BM, 1), blk, 0, stream>>>(
              nb, TD, 0, 0, 1, W1_l, TDFF, 0, 0, 1, f1b, TDFF, 0, 0, 1,
              b1 + (size_t)l * TDFF, nullptr, TD);
      gemm_k<128, float, false, float, true, false, true, false, false>
          <<<dim3(TD / 128, (TB * TS) / BM, 1), blk, 0, stream>>>(
              f1b, TDFF, 0, 0, 1, W2_l, TD, 0, 0, 1, x, TD, 0, 0, 1,
              b2 + (size_t)l * TD, x, TDFF);
    }
    rms_k<<<TB * TS, blk, 0, stream>>>(x, alf, nb);
    gemm_k<128, float, false, float, true, false, false, false, false>
        <<<dim3(TV / 128, (TB * TS) / BM, 1), blk, 0, stream>>>(
            nb, TD, 0, 0, 1, Wp, TV, 0, 0, 1, (float*)d_out, TV, 0, 0, 1,
            bp, nullptr, TD);
    logsoftmax_k<<<TB * TS, blk, 0, stream>>>((float*)d_out);
  }
}